// Round 14
// baseline (332.144 us; speedup 1.0000x reference)
//
#include <hip/hip_runtime.h>
#include <hip/hip_bf16.h>

#define DD 1024
#define NB 4
#define TT 1024
#define NH 16
#define NS 4
#define LKV 1028   // NS + TT
#define NCH 4
#define CHS 257    // keys per chunk (4*257 = 1028)

typedef __hip_bfloat16 bf16;
typedef __attribute__((ext_vector_type(8))) short short8;
typedef __attribute__((ext_vector_type(4))) float f32x4;

#define GLD16(gp, lp) __builtin_amdgcn_global_load_lds( \
    (const __attribute__((address_space(1))) unsigned int*)(const void*)(gp), \
    (__attribute__((address_space(3))) unsigned int*)(void*)(lp), 16, 0, 0)

__device__ __forceinline__ float warp_sum(float v) {
#pragma unroll
    for (int o = 32; o > 0; o >>= 1) v += __shfl_xor(v, o);
    return v;
}

__device__ __forceinline__ float b2f(unsigned short u) {
    union { unsigned int i; float f; } x; x.i = ((unsigned)u) << 16; return x.f;
}

// ================= prep: cvt x + 2 embed weights, PE table, state copy ========
struct PrepArgs {
    const float* x;
    const float* seW;
    const float* oeW;
    bf16 *xb, *seWb, *oeWb;
    const float* state0;
    float* cat;
    float* pe;
};

__global__ __launch_bounds__(256) void prep_kernel(PrepArgs a) {
    int bid = blockIdx.x;
    int tid = threadIdx.x;
    if (bid < 6144) {
        const float* in; bf16* out; size_t off;
        if (bid < 4096)      { in = a.x;   out = a.xb;   off = (size_t)bid * 1024; }
        else if (bid < 5120) { in = a.seW; out = a.seWb; off = (size_t)(bid - 4096) * 1024; }
        else                 { in = a.oeW; out = a.oeWb; off = (size_t)(bid - 5120) * 1024; }
        size_t i = off + tid * 4;
        float4 v = *(const float4*)(in + i);
        out[i + 0] = __float2bfloat16(v.x);
        out[i + 1] = __float2bfloat16(v.y);
        out[i + 2] = __float2bfloat16(v.z);
        out[i + 3] = __float2bfloat16(v.w);
    } else if (bid < 7168) {
        int t = bid - 6144;
#pragma unroll
        for (int i = 0; i < 2; ++i) {
            int j = i * 256 + tid;                       // 0..511
            float ang = (float)t * exp2f(-(float)j * (1.0f / 256.0f));
            a.pe[(size_t)t * DD + j]       = sinf(ang);
            a.pe[(size_t)t * DD + 512 + j] = cosf(ang);
        }
    } else {
        int r = bid - 7168;        // 0..15
        int b = r >> 2, s = r & 3;
#pragma unroll
        for (int i = 0; i < 4; ++i)
            a.cat[(size_t)(b * LKV + s) * DD + i * 256 + tid] =
                a.state0[(size_t)r * DD + i * 256 + tid];
    }
}

// ================= fused LayerNorm -> bf16 (state-kv rows + out token rows) ===
__global__ __launch_bounds__(256) void ln_fused_kernel(
    const float* __restrict__ cat, const float* __restrict__ cat2,
    bf16* __restrict__ lnbb, bf16* __restrict__ lnbb2,
    const float* __restrict__ sg, const float* __restrict__ sb,
    const float* __restrict__ og, const float* __restrict__ ob)
{
    int bid = blockIdx.x;
    int tid = threadIdx.x;
    const float* in; bf16* out; const float* g; const float* b;
    if (bid < 4112) {
        in = cat + (size_t)bid * DD; out = lnbb + (size_t)bid * DD; g = sg; b = sb;
    } else {
        int r = bid - 4112;
        int row = (r >> 10) * LKV + (r & 1023);
        in = cat2 + (size_t)row * DD; out = lnbb2 + (size_t)r * DD; g = og; b = ob;
    }
    float v[4];
    float s1 = 0.f, s2 = 0.f;
#pragma unroll
    for (int i = 0; i < 4; ++i) {
        v[i] = in[i * 256 + tid];
        s1 += v[i]; s2 += v[i] * v[i];
    }
    s1 = warp_sum(s1); s2 = warp_sum(s2);
    __shared__ float a1[4], a2[4];
    int w = tid >> 6;
    if ((tid & 63) == 0) { a1[w] = s1; a2[w] = s2; }
    __syncthreads();
    s1 = a1[0] + a1[1] + a1[2] + a1[3];
    s2 = a2[0] + a2[1] + a2[2] + a2[3];
    float mu  = s1 * (1.0f / DD);
    float var = s2 * (1.0f / DD) - mu * mu;
    var = var < 0.f ? 0.f : var;
    float rs = rsqrtf(var + 1e-5f);
#pragma unroll
    for (int i = 0; i < 4; ++i) {
        int c = i * 256 + tid;
        out[c] = __float2bfloat16((v[i] - mu) * rs * g[c] + b[c]);
    }
}

// ================= MFMA tile body (128x128, BK=32, 4 waves) ===================
__device__ __forceinline__ void mfma_tile(
    const bf16* __restrict__ A, const bf16* __restrict__ W,
    const float* __restrict__ bias,
    float* __restrict__ outf,
    int obs, int oro, const float* __restrict__ pe,
    bf16* As, bf16* Ws, int m0, int n0)
{
    int tid  = threadIdx.x;
    int lane = tid & 63;
    int wave = tid >> 6;
    int wm = (wave >> 1) << 6;
    int wn = (wave & 1) << 6;

    f32x4 acc[4][4] = {};

    int soff  = wave * 1024 + lane * 16;
    int srow  = soff >> 6;
    int scol  = (soff & 63) >> 1;
    char* lA0 = (char*)As + wave * 1024;
    char* lA1 = (char*)As + 4096 + wave * 1024;
    char* lW0 = (char*)Ws + wave * 1024;
    char* lW1 = (char*)Ws + 4096 + wave * 1024;

    int fRow = lane & 15;
    int kOff = (lane >> 4) << 3;

    for (int k0 = 0; k0 < DD; k0 += 32) {
        GLD16(A + (size_t)(m0 + srow) * DD + k0 + scol,      lA0);
        GLD16(A + (size_t)(m0 + 64 + srow) * DD + k0 + scol, lA1);
        GLD16(W + (size_t)(n0 + srow) * DD + k0 + scol,      lW0);
        GLD16(W + (size_t)(n0 + 64 + srow) * DD + k0 + scol, lW1);
        __syncthreads();
        short8 a[4], b[4];
#pragma unroll
        for (int mi = 0; mi < 4; ++mi)
            a[mi] = *(const short8*)(As + (wm + mi * 16 + fRow) * 32 + kOff);
#pragma unroll
        for (int ni = 0; ni < 4; ++ni)
            b[ni] = *(const short8*)(Ws + (wn + ni * 16 + fRow) * 32 + kOff);
#pragma unroll
        for (int mi = 0; mi < 4; ++mi)
#pragma unroll
            for (int ni = 0; ni < 4; ++ni)
                acc[mi][ni] = __builtin_amdgcn_mfma_f32_16x16x32_bf16(
                    a[mi], b[ni], acc[mi][ni], 0, 0, 0);
        __syncthreads();
    }

    int cCol  = lane & 15;
    int cRow4 = (lane >> 4) << 2;
#pragma unroll
    for (int mi = 0; mi < 4; ++mi) {
#pragma unroll
        for (int ni = 0; ni < 4; ++ni) {
#pragma unroll
            for (int r = 0; r < 4; ++r) {
                int row = m0 + wm + mi * 16 + cRow4 + r;
                int col = n0 + wn + ni * 16 + cCol;
                float v = acc[mi][ni][r] + bias[col] + pe[(size_t)(row & 1023) * DD + col];
                int orow = (row >> 10) * obs + oro + (row & 1023);
                outf[(size_t)orow * DD + col] = v;
            }
        }
    }
}

// ================= fused embeds, XCD-swizzled linear grid (512 blocks) ========
__global__ __launch_bounds__(256) void embed_fused_kernel(
    const bf16* __restrict__ xb,
    const bf16* __restrict__ seW, const bf16* __restrict__ oeW,
    const float* __restrict__ seb, const float* __restrict__ oeb,
    float* __restrict__ cat, float* __restrict__ cat2,
    const float* __restrict__ pe)
{
    __shared__ bf16 As[128 * 32];
    __shared__ bf16 Ws[128 * 32];
    int bid = blockIdx.x;
    int t = (bid & 7) * 64 + (bid >> 3);   // bijective XCD swizzle (512 = 8*64)
    int x = t & 7;
    int q = t >> 3;
    int z = q & 1;
    int y = q >> 1;
    const bf16* W = z ? oeW : seW;
    const float* bias = z ? oeb : seb;
    float* outf = z ? cat2 : cat;
    int oro = z ? 0 : NS;
    mfma_tile(xb, W, bias, outf, LKV, oro, pe, As, Ws, y * 128, x * 128);
}

// ================= copy lo[:, -1] =============================================
__global__ __launch_bounds__(256) void copy_lolast_kernel(
    const float* __restrict__ cat2, float* __restrict__ dst)
{
    int b = blockIdx.x;
    int tid = threadIdx.x;
#pragma unroll
    for (int i = 0; i < 4; ++i)
        dst[(size_t)b * DD + i * 256 + tid] =
            cat2[(size_t)(b * LKV + (TT - 1)) * DD + i * 256 + tid];
}

// ================= small GEMM (M<=16), f32 LDS staging (round-7 proven) =======
template<int M>
__global__ __launch_bounds__(256) void small_gemm_kernel(
    const float* __restrict__ A, const float* __restrict__ W,
    const float* __restrict__ bias, float* __restrict__ out,
    const float* __restrict__ res, int gelu)
{
    __shared__ float As[M * DD];
    int tid = threadIdx.x;
#pragma unroll
    for (int i = 0; i < M; ++i) {
        int idx = (i * 256 + tid) * 4;
        *(float4*)(As + idx) = *(const float4*)(A + idx);
    }
    __syncthreads();
    int lane = tid & 63;
    int w = tid >> 6;
    int n = blockIdx.x * 4 + w;
    const float* Wr = W + (size_t)n * DD;
    float acc[M] = {};
#pragma unroll
    for (int j = 0; j < 4; ++j) {
        float4 wv = *(const float4*)(Wr + j * 256 + lane * 4);
#pragma unroll
        for (int m = 0; m < M; ++m) {
            float4 av = *(const float4*)(As + m * DD + j * 256 + lane * 4);
            acc[m] += av.x * wv.x + av.y * wv.y + av.z * wv.z + av.w * wv.w;
        }
    }
#pragma unroll
    for (int m = 0; m < M; ++m) acc[m] = warp_sum(acc[m]);
    if (lane == 0) {
#pragma unroll
        for (int m = 0; m < M; ++m) {
            float v = acc[m] + bias[n];
            if (gelu) v = 0.5f * v * (1.0f + erff(v * 0.70710678118654752f));
            if (res)  v += res[(size_t)m * DD + n];
            out[(size_t)m * DD + n] = v;
        }
    }
}

// ============ small GEMM with fused input LayerNorm (round-7 proven) ==========
template<int M>
__global__ __launch_bounds__(256) void small_ln_gemm_kernel(
    const float* __restrict__ A, int row0, int rstride,
    const float* __restrict__ lng, const float* __restrict__ lnb,
    const float* __restrict__ W, const float* __restrict__ bias,
    float* __restrict__ outf, int gelu)
{
    __shared__ float As[M * DD];
    __shared__ float smu[M], srs[M];
    int tid = threadIdx.x;
    int lane = tid & 63;
    int w = tid >> 6;
#pragma unroll
    for (int i = 0; i < M; ++i) {
        int row = row0 + i * rstride;
        *(float4*)(As + i * DD + tid * 4) =
            *(const float4*)(A + (size_t)row * DD + tid * 4);
    }
    __syncthreads();
    constexpr int RPW = (M + 3) / 4;
#pragma unroll
    for (int i = 0; i < RPW; ++i) {
        int r = w * RPW + i;
        if (r < M) {
            float s1 = 0.f, s2 = 0.f;
#pragma unroll
            for (int j = 0; j < 4; ++j) {
                float4 v = *(const float4*)(As + r * DD + (j * 64 + lane) * 4);
                s1 += v.x + v.y + v.z + v.w;
                s2 += v.x*v.x + v.y*v.y + v.z*v.z + v.w*v.w;
            }
            s1 = warp_sum(s1); s2 = warp_sum(s2);
            if (lane == 0) {
                float mu = s1 * (1.0f / DD);
                float var = s2 * (1.0f / DD) - mu * mu;
                var = var < 0.f ? 0.f : var;
                smu[r] = mu; srs[r] = rsqrtf(var + 1e-5f);
            }
        }
    }
    __syncthreads();
    float4 gv = *(const float4*)(lng + tid * 4);
    float4 bv = *(const float4*)(lnb + tid * 4);
#pragma unroll
    for (int i = 0; i < M; ++i) {
        float mu = smu[i], rs = srs[i];
        float4 v = *(const float4*)(As + i * DD + tid * 4);
        v.x = (v.x - mu) * rs * gv.x + bv.x;
        v.y = (v.y - mu) * rs * gv.y + bv.y;
        v.z = (v.z - mu) * rs * gv.z + bv.z;
        v.w = (v.w - mu) * rs * gv.w + bv.w;
        *(float4*)(As + i * DD + tid * 4) = v;
    }
    __syncthreads();
    int n = blockIdx.x * 4 + w;
    const float* Wr = W + (size_t)n * DD;
    float acc[M] = {};
#pragma unroll
    for (int j = 0; j < 4; ++j) {
        float4 wv = *(const float4*)(Wr + j * 256 + lane * 4);
#pragma unroll
        for (int m = 0; m < M; ++m) {
            float4 av = *(const float4*)(As + m * DD + j * 256 + lane * 4);
            acc[m] += av.x * wv.x + av.y * wv.y + av.z * wv.z + av.w * wv.w;
        }
    }
#pragma unroll
    for (int m = 0; m < M; ++m) acc[m] = warp_sum(acc[m]);
    if (lane == 0) {
#pragma unroll
        for (int m = 0; m < M; ++m) {
            float v = acc[m] + bias[n];
            if (gelu) v = 0.5f * v * (1.0f + erff(v * 0.70710678118654752f));
            outf[(size_t)m * DD + n] = v;
        }
    }
}

// ============ qtil: project queries through Wk (low-rank attention trick) =====
// blk < 256: state (b,q,h) with blk = (b*4+q)*16+h, src qh_s, W=s_Wk -> qtil_s[blk]
// blk >= 256: out (b,h) with blk-256 = b*16+h, src q2h, W=o_Wk -> qtil_o[blk-256]
__global__ __launch_bounds__(256) void qtil_kernel(
    const float* __restrict__ qh_s, const float* __restrict__ q2h,
    const float* __restrict__ sWk, const float* __restrict__ oWk,
    float* __restrict__ qtil_s, float* __restrict__ qtil_o)
{
    int blk = blockIdx.x;
    int tid = threadIdx.x;
    const float* src; const float* W; float* dst; int h;
    if (blk < 256) {
        int bq = blk >> 4;          // b*4+q
        h = blk & 15;
        src = qh_s + (size_t)bq * DD;
        W = sWk; dst = qtil_s + (size_t)blk * DD;
    } else {
        int o = blk - 256;
        int b = o >> 4;
        h = o & 15;
        src = q2h + (size_t)b * DD;
        W = oWk; dst = qtil_o + (size_t)o * DD;
    }
    __shared__ float qv[64];
    if (tid < 64) qv[tid] = src[h * 64 + tid];
    __syncthreads();
    int i = tid * 4;
    float4 acc = {0.f, 0.f, 0.f, 0.f};
#pragma unroll 4
    for (int o = 0; o < 64; ++o) {
        float4 wr = *(const float4*)(W + (size_t)(h * 64 + o) * DD + i);
        float s = qv[o];
        acc.x += s * wr.x; acc.y += s * wr.y; acc.z += s * wr.z; acc.w += s * wr.w;
    }
    acc.x *= 0.125f; acc.y *= 0.125f; acc.z *= 0.125f; acc.w *= 0.125f;
    *(float4*)(dst + i) = acc;
}

// ============ sc_ctx: scores + softmax-partial + ctx accumulation =============
// grid 64*NCH; blk -> c = blk&3, bh = blk>>2, b = bh>>4, h = bh&15.
// keys: row t -> keyM + (b*mainB + t)*DD if t < split else keyA + (b*NS + t-split)*DD
template<int LQ>
__global__ __launch_bounds__(256) void sc_ctx_kernel(
    const float* __restrict__ qtil,
    const bf16* __restrict__ keyM, const bf16* __restrict__ keyA,
    int mainB, int split,
    float* __restrict__ pm, float* __restrict__ pl, float* __restrict__ pctx)
{
    __shared__ float qt[LQ * DD];
    __shared__ float sc[LQ * CHS];
    __shared__ float redm[4 * LQ];
    __shared__ float redl[4 * LQ];
    int blk = blockIdx.x;
    int c  = blk & (NCH - 1);
    int bh = blk >> 2;
    int b = bh >> 4, h = bh & 15;
    int tid = threadIdx.x;
    int lane = tid & 63, w = tid >> 6;

    for (int x = tid; x < LQ * DD; x += 256) {
        int q = x >> 10;
        qt[x] = qtil[(size_t)((b * LQ + q) * 16 + h) * DD + (x & 1023)];
    }
    __syncthreads();

    int kbeg = c * CHS;
    // pass 1: thread-per-key scores (qt reads are wave-broadcast)
    for (int t = tid; t < CHS; t += 256) {
        int key = kbeg + t;
        const unsigned short* row = (const unsigned short*)(
            (key < split) ? (const void*)(keyM + (size_t)(b * mainB + key) * DD)
                          : (const void*)(keyA + (size_t)(b * NS + key - split) * DD));
        float acc[LQ] = {};
        for (int i = 0; i < DD; i += 8) {
            short8 v = *(const short8*)(row + i);
            float f0 = b2f((unsigned short)v[0]), f1 = b2f((unsigned short)v[1]);
            float f2 = b2f((unsigned short)v[2]), f3 = b2f((unsigned short)v[3]);
            float f4 = b2f((unsigned short)v[4]), f5 = b2f((unsigned short)v[5]);
            float f6 = b2f((unsigned short)v[6]), f7 = b2f((unsigned short)v[7]);
#pragma unroll
            for (int q = 0; q < LQ; ++q) {
                const float* qq = qt + q * DD + i;
                acc[q] += f0*qq[0] + f1*qq[1] + f2*qq[2] + f3*qq[3]
                        + f4*qq[4] + f5*qq[5] + f6*qq[6] + f7*qq[7];
            }
        }
#pragma unroll
        for (int q = 0; q < LQ; ++q) sc[q * CHS + t] = acc[q];
    }
    __syncthreads();

    // chunk-local max
    float M[LQ], L[LQ];
#pragma unroll
    for (int q = 0; q < LQ; ++q) {
        float lm = -1e30f;
        for (int t = tid; t < CHS; t += 256) lm = fmaxf(lm, sc[q * CHS + t]);
#pragma unroll
        for (int o = 32; o > 0; o >>= 1) lm = fmaxf(lm, __shfl_xor(lm, o));
        if (lane == 0) redm[w * LQ + q] = lm;
    }
    __syncthreads();
#pragma unroll
    for (int q = 0; q < LQ; ++q)
        M[q] = fmaxf(fmaxf(redm[q], redm[LQ + q]),
                     fmaxf(redm[2 * LQ + q], redm[3 * LQ + q]));
    // exp + sum
#pragma unroll
    for (int q = 0; q < LQ; ++q) {
        float ls = 0.f;
        for (int t = tid; t < CHS; t += 256) {
            float e = expf(sc[q * CHS + t] - M[q]);
            sc[q * CHS + t] = e;
            ls += e;
        }
        ls = warp_sum(ls);
        if (lane == 0) redl[w * LQ + q] = ls;
    }
    __syncthreads();
#pragma unroll
    for (int q = 0; q < LQ; ++q)
        L[q] = redl[q] + redl[LQ + q] + redl[2 * LQ + q] + redl[3 * LQ + q];

    // pass 2: thread-per-dim ctx accumulation (coalesced key reads)
    int i4 = tid * 4;
    float cx[LQ][4];
#pragma unroll
    for (int q = 0; q < LQ; ++q) { cx[q][0]=0; cx[q][1]=0; cx[q][2]=0; cx[q][3]=0; }
    for (int t = 0; t < CHS; ++t) {
        int key = kbeg + t;
        const unsigned short* row = (const unsigned short*)(
            (key < split) ? (const void*)(keyM + (size_t)(b * mainB + key) * DD)
                          : (const void*)(keyA + (size_t)(b * NS + key - split) * DD));
        ushort4 v = *(const ushort4*)(row + i4);
        float f0 = b2f(v.x), f1 = b2f(v.y), f2 = b2f(v.z), f3 = b2f(v.w);
#pragma unroll
        for (int q = 0; q < LQ; ++q) {
            float p = sc[q * CHS + t];
            cx[q][0] += p * f0; cx[q][1] += p * f1;
            cx[q][2] += p * f2; cx[q][3] += p * f3;
        }
    }
#pragma unroll
    for (int q = 0; q < LQ; ++q) {
        float4 o4 = {cx[q][0], cx[q][1], cx[q][2], cx[q][3]};
        *(float4*)(pctx + (size_t)((bh * NCH + c) * LQ + q) * DD + i4) = o4;
    }
    if (tid < LQ) {
        pm[(bh * LQ + tid) * NCH + c] = M[tid];
        pl[(bh * LQ + tid) * NCH + c] = L[tid];
    }
}

// ============ combproj: combine chunk ctx + project through Wv + bv ===========
// grid 64*LQ; blk = (b*LQ+q)*16+h. Output attn[(b*LQ+q)*DD + h*64 + o].
template<int LQ>
__global__ __launch_bounds__(256) void combproj_kernel(
    const float* __restrict__ pm, const float* __restrict__ pl,
    const float* __restrict__ pctx,
    const float* __restrict__ Wv, const float* __restrict__ bv,
    float* __restrict__ attn)
{
    __shared__ float ctxf[DD];
    int blk = blockIdx.x;
    int h = blk & 15;
    int bq = blk >> 4;               // b*LQ+q
    int b = bq / LQ, q = bq - b * LQ;
    int bh = b * 16 + h;
    int tid = threadIdx.x;
    int lane = tid & 63, w = tid >> 6;

    int base = (bh * LQ + q) * NCH;
    float m0 = pm[base], m1 = pm[base+1], m2 = pm[base+2], m3 = pm[base+3];
    float Mx = fmaxf(fmaxf(m0, m1), fmaxf(m2, m3));
    float w0 = expf(m0-Mx), w1 = expf(m1-Mx), w2 = expf(m2-Mx), w3 = expf(m3-Mx);
    float L = pl[base]*w0 + pl[base+1]*w1 + pl[base+2]*w2 + pl[base+3]*w3;
    float inv = 1.f / L;
    int i4 = tid * 4;
    float4 a0 = *(const float4*)(pctx + (size_t)((bh * NCH + 0) * LQ + q) * DD + i4);
    float4 a1 = *(const float4*)(pctx + (size_t)((bh * NCH + 1) * LQ + q) * DD + i4);
    float4 a2 = *(const float4*)(pctx + (size_t)((bh * NCH + 2) * LQ + q) * DD + i4);
    float4 a3 = *(const float4*)(pctx + (size_t)((bh * NCH + 3) * LQ + q) * DD + i4);
    ctxf[i4+0] = (a0.x*w0 + a1.x*w1 + a2.x*w2 + a3.x*w3) * inv;
    ctxf[i4+1] = (a0.y*w0 + a1.y*w1 + a2.y*w2 + a3.y*w3) * inv;
    ctxf[i4+2] = (a0.z*w0 + a1.z*w1 + a2.z*w2 + a3.z*w3) * inv;
    ctxf[i4+3] = (a0.w*w0 + a1.w*w1 + a2.w*w2 + a3.w*w3) * inv;
    __syncthreads();

    // project: wave w handles outs h*64 + w*16 + rr, rr=0..15
#pragma unroll 1
    for (int rr = 0; rr < 16; ++rr) {
        int o = h * 64 + w * 16 + rr;
        const float* Wr = Wv + (size_t)o * DD + lane * 16;
        const float* cf = ctxf + lane * 16;
        float s = 0.f;
#pragma unroll
        for (int j = 0; j < 4; ++j) {
            float4 wv4 = *(const float4*)(Wr + j * 4);
            s += wv4.x * cf[j*4+0] + wv4.y * cf[j*4+1]
               + wv4.z * cf[j*4+2] + wv4.w * cf[j*4+3];
        }
        s = warp_sum(s);
        if (lane == 0)
            attn[(size_t)bq * DD + o] = s + bv[o];
    }
}

// ================= LN of stateNew rows -> bf16 (out-branch keys) ==============
__global__ __launch_bounds__(256) void lnst_kernel(
    const float* __restrict__ stateNew, bf16* __restrict__ lnst,
    const float* __restrict__ g, const float* __restrict__ b)
{
    int r = blockIdx.x;
    int tid = threadIdx.x;
    size_t base = (size_t)r * DD;
    float v[4];
    float s1 = 0.f, s2 = 0.f;
#pragma unroll
    for (int i = 0; i < 4; ++i) {
        v[i] = stateNew[base + i * 256 + tid];
        s1 += v[i]; s2 += v[i] * v[i];
    }
    s1 = warp_sum(s1); s2 = warp_sum(s2);
    __shared__ float a1[4], a2[4];
    int w = tid >> 6;
    if ((tid & 63) == 0) { a1[w] = s1; a2[w] = s2; }
    __syncthreads();
    s1 = a1[0] + a1[1] + a1[2] + a1[3];
    s2 = a2[0] + a2[1] + a2[2] + a2[3];
    float mu  = s1 * (1.0f / DD);
    float var = s2 * (1.0f / DD) - mu * mu;
    var = var < 0.f ? 0.f : var;
    float rs = rsqrtf(var + 1e-5f);
#pragma unroll
    for (int i = 0; i < 4; ++i) {
        int c = i * 256 + tid;
        lnst[base + c] = __float2bfloat16((v[i] - mu) * rs * g[c] + b[c]);
    }
}

// ========== fused gate: LN(lat2) -> logits -> top2 -> state update ============
__global__ __launch_bounds__(256) void gate_fused_kernel(
    const float* __restrict__ lat2,
    const float* __restrict__ lng, const float* __restrict__ lnb,
    const float* __restrict__ ctx,
    const float* __restrict__ state_old, float* __restrict__ stateNew,
    float* __restrict__ dout)
{
    int b = blockIdx.x;
    int tid = threadIdx.x;
    int lane = tid & 63, w = tid >> 6;
    __shared__ float logit[NS];
    __shared__ float alpha[NS];

    {
        const float* row = lat2 + (size_t)(b * NS + w) * DD;
        float4 v[4];
        float s1 = 0.f, s2 = 0.f;
#pragma unroll
        for (int j = 0; j < 4; ++j) {
            v[j] = *(const float4*)(row + (j * 64 + lane) * 4);
            s1 += v[j].x + v[j].y + v[j].z + v[j].w;
            s2 += v[j].x*v[j].x + v[j].y*v[j].y + v[j].z*v[j].z + v[j].w*v[j].w;
        }
        s1 = warp_sum(s1); s2 = warp_sum(s2);
        float mu = s1 * (1.0f / DD);
        float var = s2 * (1.0f / DD) - mu * mu;
        var = var < 0.f ? 0.f : var;
        float rs = rsqrtf(var + 1e-5f);
        float dot = 0.f;
#pragma unroll
        for (int j = 0; j < 4; ++j) {
            int c = (j * 64 + lane) * 4;
            float4 gv = *(const float4*)(lng + c);
            float4 bv = *(const float4*)(lnb + c);
            float4 cv = *(const float4*)(ctx + c);
            dot += ((v[j].x - mu) * rs * gv.x + bv.x) * cv.x
                 + ((v[j].y - mu) * rs * gv.y + bv.y) * cv.y
                 + ((v[j].z - mu) * rs * gv.z + bv.z) * cv.z
                 + ((v[j].w - mu) * rs * gv.w + bv.w) * cv.w;
        }
        dot = warp_sum(dot);
        if (lane == 0) logit[w] = dot;
    }
    __syncthreads();
    if (tid == 0) {
        float l[NS];
        for (int s = 0; s < NS; ++s) l[s] = logit[s];
        int i0 = 0;
        for (int s = 1; s < NS; ++s) if (l[s] > l[i0]) i0 = s;
        int i1 = (i0 == 0) ? 1 : 0;
        for (int s = 0; s < NS; ++s) if (s != i0 && l[s] > l[i1]) i1 = s;
        float mx = fmaxf(l[i0], l[i1]);
        float e0 = expf(l[i0] - mx), e1 = expf(l[i1] - mx);
        float inv = 1.f / (e0 + e1);
        for (int s = 0; s < NS; ++s) alpha[s] = 0.f;
        alpha[i0] = e0 * inv;
        alpha[i1] += e1 * inv;
        dout[4096 + b * 2 + 0] = (float)i0;
        dout[4096 + b * 2 + 1] = (float)i1;
    }
    __syncthreads();
    for (int idx = tid; idx < NS * DD; idx += 256) {
        int s = idx >> 10;
        float so = state_old[(size_t)b * NS * DD + idx];
        float lt = lat2[(size_t)b * NS * DD + idx];
        float ns = 0.6f * so + 0.4f * alpha[s] * tanhf(lt);
        stateNew[(size_t)b * NS * DD + idx] = ns;
        dout[4104 + b * NS * DD + idx] = ns;
    }
}

extern "C" void kernel_launch(void* const* d_in, const int* in_sizes, int n_in,
                              void* d_out, int out_size, void* d_ws, size_t ws_size,
                              hipStream_t stream)
{
    const float* x        = (const float*)d_in[0];
    const float* state0   = (const float*)d_in[1];
    const float* se_W     = (const float*)d_in[2];
    const float* se_b     = (const float*)d_in[3];
    const float* s_Wq     = (const float*)d_in[4];
    const float* s_bq     = (const float*)d_in[5];
    const float* s_Wk     = (const float*)d_in[6];
    const float* s_bk     = (const float*)d_in[7];   (void)s_bk;  // drops out of softmax
    const float* s_Wv     = (const float*)d_in[8];
    const float* s_bv     = (const float*)d_in[9];
    const float* s_Wo     = (const float*)d_in[10];
    const float* s_bo     = (const float*)d_in[11];
    const float* s_lnq_g  = (const float*)d_in[12];
    const float* s_lnq_b  = (const float*)d_in[13];
    const float* s_lnkv_g = (const float*)d_in[14];
    const float* s_lnkv_b = (const float*)d_in[15];
    const float* s_fc1_W  = (const float*)d_in[16];
    const float* s_fc1_b  = (const float*)d_in[17];
    const float* s_fc2_W  = (const float*)d_in[18];
    const float* s_fc2_b  = (const float*)d_in[19];
    const float* s_lnffn_g= (const float*)d_in[20];
    const float* s_lnffn_b= (const float*)d_in[21];
    const float* s_lnslot_g=(const float*)d_in[22];
    const float* s_lnslot_b=(const float*)d_in[23];
    const float* slot_ctx = (const float*)d_in[24];
    const float* oe_W     = (const float*)d_in[25];
    const float* oe_b     = (const float*)d_in[26];
    const float* o_Wq     = (const float*)d_in[27];
    const float* o_bq     = (const float*)d_in[28];
    const float* o_Wk     = (const float*)d_in[29];
    const float* o_bk     = (const float*)d_in[30];  (void)o_bk;  // drops out of softmax
    const float* o_Wv     = (const float*)d_in[31];
    const float* o_bv     = (const float*)d_in[32];
    const float* o_Wo     = (const float*)d_in[33];
    const float* o_bo     = (const float*)d_in[34];
    const float* o_lnq_g  = (const float*)d_in[35];
    const float* o_lnq_b  = (const float*)d_in[36];
    const float* o_lnkv_g = (const float*)d_in[37];
    const float* o_lnkv_b = (const float*)d_in[38];
    const float* o_fc1_W  = (const float*)d_in[39];
    const float* o_fc1_b  = (const float*)d_in[40];
    const float* o_fc2_W  = (const float*)d_in[41];
    const float* o_fc2_b  = (const float*)d_in[42];
    const float* o_lnffn_g= (const float*)d_in[43];
    const float* o_lnffn_b= (const float*)d_in[44];
    const float* op_W     = (const float*)d_in[45];
    const float* op_b     = (const float*)d_in[46];

    float* ws = (float*)d_ws;
    float* pe    = ws;
    float* cat   = ws + 1048576;                 // consumed by ln_fused, then reused:
    float* qtil_s= ws + 1048576;                 //   256 x 1024
    float* qtil_o= ws + 1310720;                 //   64 x 1024
    float* pctx_s= ws + 1376256;                 //   64*4*4 x 1024
    float* pctx_o= ws + 2424832;                 //   64*4*1 x 1024
    float* pms   = ws + 2686976;                 //   1024
    float* pls   = ws + 2688000;                 //   1024
    float* pmo   = ws + 2689024;                 //   256
    float* plo   = ws + 2689280;                 //   256
    bf16*  lnbb  = (bf16*)(ws + 5259264);        // 4112 rows bf16
    float* cat2  = ws + 7421952;
    bf16*  xb    = (bf16*)(ws + 11632640);       // xb early, lnbb2 late (alias)
    bf16*  lnbb2 = (bf16*)(ws + 11632640);
    bf16*  seWb  = (bf16*)(ws + 13729792);
    bf16*  oeWb  = seWb + 1048576;
    float* sm    = ws + 16875520;
    float* qh_s    = sm + 16384;
    float* attn_s  = sm + 32768;
    float* lat1    = sm + 49152;
    float* g1      = sm + 81920;
    float* lat2    = sm + 98304;
    float* q2h     = sm + 135232;
    float* attn2   = sm + 139328;
    float* lo_last = sm + 143424;
    float* lo1     = sm + 147520;
    float* g2      = sm + 155712;
    float* lo2     = sm + 159808;
    float* stateNew= sm + 231488;
    bf16*  lnst    = (bf16*)(sm + 247872);       // 16 x 1024 bf16
    float* out = (float*)d_out;

    dim3 blk(256);

    // ---- phase 0: conversions (x, seW, oeW only) + PE + state-row copy ----
    PrepArgs pa;
    pa.x = x; pa.seW = se_W; pa.oeW = oe_W;
    pa.xb = xb; pa.seWb = seWb; pa.oeWb = oeWb;
    pa.state0 = state0; pa.cat = cat; pa.pe = pe;
    prep_kernel<<<7184, blk, 0, stream>>>(pa);

    // ---- phase 1: both embeds (MFMA), XCD-swizzled ----
    embed_fused_kernel<<<512, blk, 0, stream>>>(
        xb, seWb, oeWb, se_b, oe_b, cat, cat2, pe);

    // ---- phase 2: big LNs + q projections + lo_last ----
    ln_fused_kernel<<<8208, blk, 0, stream>>>(cat, cat2, lnbb, lnbb2,
        s_lnkv_g, s_lnkv_b, o_lnkv_g, o_lnkv_b);
    small_ln_gemm_kernel<16><<<256, blk, 0, stream>>>(state0, 0, 1,
        s_lnq_g, s_lnq_b, s_Wq, s_bq, qh_s, 0);
    small_ln_gemm_kernel<4><<<256, blk, 0, stream>>>(cat2, TT - 1, LKV,
        o_lnq_g, o_lnq_b, o_Wq, o_bq, q2h, 0);
    copy_lolast_kernel<<<NB, blk, 0, stream>>>(cat2, lo_last);

    // ---- phase 3: query-side Wk projection (replaces K GEMMs) ----
    qtil_kernel<<<320, blk, 0, stream>>>(qh_s, q2h, s_Wk, o_Wk, qtil_s, qtil_o);

    // ---- phase 4: state-branch attention (scores+ctx over lnbb) + slot MLP ----
    sc_ctx_kernel<4><<<256, blk, 0, stream>>>(qtil_s, lnbb, nullptr, LKV, 2000,
        pms, pls, pctx_s);
    combproj_kernel<4><<<256, blk, 0, stream>>>(pms, pls, pctx_s, s_Wv, s_bv, attn_s);
    small_gemm_kernel<16><<<256, blk, 0, stream>>>(attn_s, s_Wo, s_bo, lat1, state0, 0);
    small_ln_gemm_kernel<16><<<256, blk, 0, stream>>>(lat1, 0, 1,
        s_lnffn_g, s_lnffn_b, s_fc1_W, s_fc1_b, g1, 1);
    small_gemm_kernel<16><<<256, blk, 0, stream>>>(g1, s_fc2_W, s_fc2_b, lat2, lat1, 0);
    gate_fused_kernel<<<NB, blk, 0, stream>>>(lat2, s_lnslot_g, s_lnslot_b,
        slot_ctx, state0, stateNew, out);

    // ---- phase 5: out-branch attention (tokens from lnbb2 + 4 new-state rows) ----
    lnst_kernel<<<16, blk, 0, stream>>>(stateNew, lnst, o_lnkv_g, o_lnkv_b);
    sc_ctx_kernel<1><<<256, blk, 0, stream>>>(qtil_o, lnbb2, lnst, TT, TT,
        pmo, plo, pctx_o);
    combproj_kernel<1><<<64, blk, 0, stream>>>(pmo, plo, pctx_o, o_Wv, o_bv, attn2);
    small_gemm_kernel<4><<<256, blk, 0, stream>>>(attn2, o_Wo, o_bo, lo1, lo_last, 0);
    small_ln_gemm_kernel<4><<<256, blk, 0, stream>>>(lo1, 0, 1,
        o_lnffn_g, o_lnffn_b, o_fc1_W, o_fc1_b, g2, 1);
    small_gemm_kernel<4><<<256, blk, 0, stream>>>(g2, o_fc2_W, o_fc2_b, lo2, lo1, 0);
    small_gemm_kernel<4><<<256, blk, 0, stream>>>(lo2, op_W, op_b, out, nullptr, 0);
}

// Round 15
// 263.125 us; speedup vs baseline: 1.2623x; 1.2623x over previous
//
#include <hip/hip_runtime.h>
#include <hip/hip_bf16.h>

#define DD 1024
#define NB 4
#define TT 1024
#define NH 16
#define NS 4
#define LKV 1028   // NS + TT
#define NCH 16
#define CHS 65     // 16*65 = 1040 >= 1028
#define NKEY 1028

typedef __hip_bfloat16 bf16;
typedef __attribute__((ext_vector_type(8))) short short8;
typedef __attribute__((ext_vector_type(4))) float f32x4;

#define GLD16(gp, lp) __builtin_amdgcn_global_load_lds( \
    (const __attribute__((address_space(1))) unsigned int*)(const void*)(gp), \
    (__attribute__((address_space(3))) unsigned int*)(void*)(lp), 16, 0, 0)

__device__ __forceinline__ float warp_sum(float v) {
#pragma unroll
    for (int o = 32; o > 0; o >>= 1) v += __shfl_xor(v, o);
    return v;
}

__device__ __forceinline__ float b2f(unsigned short u) {
    union { unsigned int i; float f; } x; x.i = ((unsigned)u) << 16; return x.f;
}

// ================= prep: cvt x + 2 embed weights, PE table, state copy ========
struct PrepArgs {
    const float* x;
    const float* seW;
    const float* oeW;
    bf16 *xb, *seWb, *oeWb;
    const float* state0;
    float* cat;
    float* pe;
};

__global__ __launch_bounds__(256) void prep_kernel(PrepArgs a) {
    int bid = blockIdx.x;
    int tid = threadIdx.x;
    if (bid < 6144) {
        const float* in; bf16* out; size_t off;
        if (bid < 4096)      { in = a.x;   out = a.xb;   off = (size_t)bid * 1024; }
        else if (bid < 5120) { in = a.seW; out = a.seWb; off = (size_t)(bid - 4096) * 1024; }
        else                 { in = a.oeW; out = a.oeWb; off = (size_t)(bid - 5120) * 1024; }
        size_t i = off + tid * 4;
        float4 v = *(const float4*)(in + i);
        out[i + 0] = __float2bfloat16(v.x);
        out[i + 1] = __float2bfloat16(v.y);
        out[i + 2] = __float2bfloat16(v.z);
        out[i + 3] = __float2bfloat16(v.w);
    } else if (bid < 7168) {
        int t = bid - 6144;
#pragma unroll
        for (int i = 0; i < 2; ++i) {
            int j = i * 256 + tid;                       // 0..511
            float ang = (float)t * exp2f(-(float)j * (1.0f / 256.0f));
            a.pe[(size_t)t * DD + j]       = sinf(ang);
            a.pe[(size_t)t * DD + 512 + j] = cosf(ang);
        }
    } else {
        int r = bid - 7168;        // 0..15
        int b = r >> 2, s = r & 3;
#pragma unroll
        for (int i = 0; i < 4; ++i)
            a.cat[(size_t)(b * LKV + s) * DD + i * 256 + tid] =
                a.state0[(size_t)r * DD + i * 256 + tid];
    }
}

// ================= fused LayerNorm -> bf16 (state-kv rows + out token rows) ===
__global__ __launch_bounds__(256) void ln_fused_kernel(
    const float* __restrict__ cat, const float* __restrict__ cat2,
    bf16* __restrict__ lnbb, bf16* __restrict__ lnbb2,
    const float* __restrict__ sg, const float* __restrict__ sb,
    const float* __restrict__ og, const float* __restrict__ ob)
{
    int bid = blockIdx.x;
    int tid = threadIdx.x;
    const float* in; bf16* out; const float* g; const float* b;
    if (bid < 4112) {
        in = cat + (size_t)bid * DD; out = lnbb + (size_t)bid * DD; g = sg; b = sb;
    } else {
        int r = bid - 4112;
        int row = (r >> 10) * LKV + (r & 1023);
        in = cat2 + (size_t)row * DD; out = lnbb2 + (size_t)r * DD; g = og; b = ob;
    }
    float v[4];
    float s1 = 0.f, s2 = 0.f;
#pragma unroll
    for (int i = 0; i < 4; ++i) {
        v[i] = in[i * 256 + tid];
        s1 += v[i]; s2 += v[i] * v[i];
    }
    s1 = warp_sum(s1); s2 = warp_sum(s2);
    __shared__ float a1[4], a2[4];
    int w = tid >> 6;
    if ((tid & 63) == 0) { a1[w] = s1; a2[w] = s2; }
    __syncthreads();
    s1 = a1[0] + a1[1] + a1[2] + a1[3];
    s2 = a2[0] + a2[1] + a2[2] + a2[3];
    float mu  = s1 * (1.0f / DD);
    float var = s2 * (1.0f / DD) - mu * mu;
    var = var < 0.f ? 0.f : var;
    float rs = rsqrtf(var + 1e-5f);
#pragma unroll
    for (int i = 0; i < 4; ++i) {
        int c = i * 256 + tid;
        out[c] = __float2bfloat16((v[i] - mu) * rs * g[c] + b[c]);
    }
}

// ================= MFMA tile body (128x128, BK=32, 4 waves) ===================
__device__ __forceinline__ void mfma_tile(
    const bf16* __restrict__ A, const bf16* __restrict__ W,
    const float* __restrict__ bias,
    float* __restrict__ outf,
    int obs, int oro, const float* __restrict__ pe,
    bf16* As, bf16* Ws, int m0, int n0)
{
    int tid  = threadIdx.x;
    int lane = tid & 63;
    int wave = tid >> 6;
    int wm = (wave >> 1) << 6;
    int wn = (wave & 1) << 6;

    f32x4 acc[4][4] = {};

    int soff  = wave * 1024 + lane * 16;
    int srow  = soff >> 6;
    int scol  = (soff & 63) >> 1;
    char* lA0 = (char*)As + wave * 1024;
    char* lA1 = (char*)As + 4096 + wave * 1024;
    char* lW0 = (char*)Ws + wave * 1024;
    char* lW1 = (char*)Ws + 4096 + wave * 1024;

    int fRow = lane & 15;
    int kOff = (lane >> 4) << 3;

    for (int k0 = 0; k0 < DD; k0 += 32) {
        GLD16(A + (size_t)(m0 + srow) * DD + k0 + scol,      lA0);
        GLD16(A + (size_t)(m0 + 64 + srow) * DD + k0 + scol, lA1);
        GLD16(W + (size_t)(n0 + srow) * DD + k0 + scol,      lW0);
        GLD16(W + (size_t)(n0 + 64 + srow) * DD + k0 + scol, lW1);
        __syncthreads();
        short8 a[4], b[4];
#pragma unroll
        for (int mi = 0; mi < 4; ++mi)
            a[mi] = *(const short8*)(As + (wm + mi * 16 + fRow) * 32 + kOff);
#pragma unroll
        for (int ni = 0; ni < 4; ++ni)
            b[ni] = *(const short8*)(Ws + (wn + ni * 16 + fRow) * 32 + kOff);
#pragma unroll
        for (int mi = 0; mi < 4; ++mi)
#pragma unroll
            for (int ni = 0; ni < 4; ++ni)
                acc[mi][ni] = __builtin_amdgcn_mfma_f32_16x16x32_bf16(
                    a[mi], b[ni], acc[mi][ni], 0, 0, 0);
        __syncthreads();
    }

    int cCol  = lane & 15;
    int cRow4 = (lane >> 4) << 2;
#pragma unroll
    for (int mi = 0; mi < 4; ++mi) {
#pragma unroll
        for (int ni = 0; ni < 4; ++ni) {
#pragma unroll
            for (int r = 0; r < 4; ++r) {
                int row = m0 + wm + mi * 16 + cRow4 + r;
                int col = n0 + wn + ni * 16 + cCol;
                float v = acc[mi][ni][r] + bias[col] + pe[(size_t)(row & 1023) * DD + col];
                int orow = (row >> 10) * obs + oro + (row & 1023);
                outf[(size_t)orow * DD + col] = v;
            }
        }
    }
}

// ================= fused embeds, XCD-swizzled linear grid (512 blocks) ========
__global__ __launch_bounds__(256) void embed_fused_kernel(
    const bf16* __restrict__ xb,
    const bf16* __restrict__ seW, const bf16* __restrict__ oeW,
    const float* __restrict__ seb, const float* __restrict__ oeb,
    float* __restrict__ cat, float* __restrict__ cat2,
    const float* __restrict__ pe)
{
    __shared__ bf16 As[128 * 32];
    __shared__ bf16 Ws[128 * 32];
    int bid = blockIdx.x;
    int t = (bid & 7) * 64 + (bid >> 3);   // bijective XCD swizzle (512 = 8*64)
    int x = t & 7;
    int q = t >> 3;
    int z = q & 1;
    int y = q >> 1;
    const bf16* W = z ? oeW : seW;
    const float* bias = z ? oeb : seb;
    float* outf = z ? cat2 : cat;
    int oro = z ? 0 : NS;
    mfma_tile(xb, W, bias, outf, LKV, oro, pe, As, Ws, y * 128, x * 128);
}

// ================= copy lo[:, -1] =============================================
__global__ __launch_bounds__(256) void copy_lolast_kernel(
    const float* __restrict__ cat2, float* __restrict__ dst)
{
    int b = blockIdx.x;
    int tid = threadIdx.x;
#pragma unroll
    for (int i = 0; i < 4; ++i)
        dst[(size_t)b * DD + i * 256 + tid] =
            cat2[(size_t)(b * LKV + (TT - 1)) * DD + i * 256 + tid];
}

// ================= small GEMM (M<=16), f32 LDS staging =========================
template<int M>
__global__ __launch_bounds__(256) void small_gemm_kernel(
    const float* __restrict__ A, const float* __restrict__ W,
    const float* __restrict__ bias, float* __restrict__ out,
    const float* __restrict__ res, int gelu)
{
    __shared__ float As[M * DD];
    int tid = threadIdx.x;
#pragma unroll
    for (int i = 0; i < M; ++i) {
        int idx = (i * 256 + tid) * 4;
        *(float4*)(As + idx) = *(const float4*)(A + idx);
    }
    __syncthreads();
    int lane = tid & 63;
    int w = tid >> 6;
    int n = blockIdx.x * 4 + w;
    const float* Wr = W + (size_t)n * DD;
    float acc[M] = {};
#pragma unroll
    for (int j = 0; j < 4; ++j) {
        float4 wv = *(const float4*)(Wr + j * 256 + lane * 4);
#pragma unroll
        for (int m = 0; m < M; ++m) {
            float4 av = *(const float4*)(As + m * DD + j * 256 + lane * 4);
            acc[m] += av.x * wv.x + av.y * wv.y + av.z * wv.z + av.w * wv.w;
        }
    }
#pragma unroll
    for (int m = 0; m < M; ++m) acc[m] = warp_sum(acc[m]);
    if (lane == 0) {
#pragma unroll
        for (int m = 0; m < M; ++m) {
            float v = acc[m] + bias[n];
            if (gelu) v = 0.5f * v * (1.0f + erff(v * 0.70710678118654752f));
            if (res)  v += res[(size_t)m * DD + n];
            out[(size_t)m * DD + n] = v;
        }
    }
}

// ============ small GEMM with fused input LayerNorm ===========================
template<int M>
__global__ __launch_bounds__(256) void small_ln_gemm_kernel(
    const float* __restrict__ A, int row0, int rstride,
    const float* __restrict__ lng, const float* __restrict__ lnb,
    const float* __restrict__ W, const float* __restrict__ bias,
    float* __restrict__ outf, int gelu)
{
    __shared__ float As[M * DD];
    __shared__ float smu[M], srs[M];
    int tid = threadIdx.x;
    int lane = tid & 63;
    int w = tid >> 6;
#pragma unroll
    for (int i = 0; i < M; ++i) {
        int row = row0 + i * rstride;
        *(float4*)(As + i * DD + tid * 4) =
            *(const float4*)(A + (size_t)row * DD + tid * 4);
    }
    __syncthreads();
    constexpr int RPW = (M + 3) / 4;
#pragma unroll
    for (int i = 0; i < RPW; ++i) {
        int r = w * RPW + i;
        if (r < M) {
            float s1 = 0.f, s2 = 0.f;
#pragma unroll
            for (int j = 0; j < 4; ++j) {
                float4 v = *(const float4*)(As + r * DD + (j * 64 + lane) * 4);
                s1 += v.x + v.y + v.z + v.w;
                s2 += v.x*v.x + v.y*v.y + v.z*v.z + v.w*v.w;
            }
            s1 = warp_sum(s1); s2 = warp_sum(s2);
            if (lane == 0) {
                float mu = s1 * (1.0f / DD);
                float var = s2 * (1.0f / DD) - mu * mu;
                var = var < 0.f ? 0.f : var;
                smu[r] = mu; srs[r] = rsqrtf(var + 1e-5f);
            }
        }
    }
    __syncthreads();
    float4 gv = *(const float4*)(lng + tid * 4);
    float4 bv = *(const float4*)(lnb + tid * 4);
#pragma unroll
    for (int i = 0; i < M; ++i) {
        float mu = smu[i], rs = srs[i];
        float4 v = *(const float4*)(As + i * DD + tid * 4);
        v.x = (v.x - mu) * rs * gv.x + bv.x;
        v.y = (v.y - mu) * rs * gv.y + bv.y;
        v.z = (v.z - mu) * rs * gv.z + bv.z;
        v.w = (v.w - mu) * rs * gv.w + bv.w;
        *(float4*)(As + i * DD + tid * 4) = v;
    }
    __syncthreads();
    int n = blockIdx.x * 4 + w;
    const float* Wr = W + (size_t)n * DD;
    float acc[M] = {};
#pragma unroll
    for (int j = 0; j < 4; ++j) {
        float4 wv = *(const float4*)(Wr + j * 256 + lane * 4);
#pragma unroll
        for (int m = 0; m < M; ++m) {
            float4 av = *(const float4*)(As + m * DD + j * 256 + lane * 4);
            acc[m] += av.x * wv.x + av.y * wv.y + av.z * wv.z + av.w * wv.w;
        }
    }
#pragma unroll
    for (int m = 0; m < M; ++m) acc[m] = warp_sum(acc[m]);
    if (lane == 0) {
#pragma unroll
        for (int m = 0; m < M; ++m) {
            float v = acc[m] + bias[n];
            if (gelu) v = 0.5f * v * (1.0f + erff(v * 0.70710678118654752f));
            outf[(size_t)m * DD + n] = v;
        }
    }
}

// ============ qtil: project queries through Wk (low-rank attention trick) =====
__global__ __launch_bounds__(256) void qtil_kernel(
    const float* __restrict__ qh_s, const float* __restrict__ q2h,
    const float* __restrict__ sWk, const float* __restrict__ oWk,
    float* __restrict__ qtil_s, float* __restrict__ qtil_o)
{
    int blk = blockIdx.x;
    int tid = threadIdx.x;
    const float* src; const float* W; float* dst; int h;
    if (blk < 256) {
        int bq = blk >> 4;          // b*4+q
        h = blk & 15;
        src = qh_s + (size_t)bq * DD;
        W = sWk; dst = qtil_s + (size_t)blk * DD;
    } else {
        int o = blk - 256;
        int b = o >> 4;
        h = o & 15;
        src = q2h + (size_t)b * DD;
        W = oWk; dst = qtil_o + (size_t)o * DD;
    }
    __shared__ float qv[64];
    if (tid < 64) qv[tid] = src[h * 64 + tid];
    __syncthreads();
    int i = tid * 4;
    float4 acc = {0.f, 0.f, 0.f, 0.f};
#pragma unroll 4
    for (int o = 0; o < 64; ++o) {
        float4 wr = *(const float4*)(W + (size_t)(h * 64 + o) * DD + i);
        float s = qv[o];
        acc.x += s * wr.x; acc.y += s * wr.y; acc.z += s * wr.z; acc.w += s * wr.w;
    }
    acc.x *= 0.125f; acc.y *= 0.125f; acc.z *= 0.125f; acc.w *= 0.125f;
    *(float4*)(dst + i) = acc;
}

// ============ sc_ctx: scores + softmax-partial + ctx (16 chunks of 65 keys) ===
// grid 64*NCH; blk -> c = blk&15, bh = blk>>4, b = bh>>4, h = bh&15.
// keys: row t -> keyM + (b*mainB + t)*DD if t < split else keyA + (b*NS + t-split)*DD
template<int LQ>
__global__ __launch_bounds__(256) void sc_ctx_kernel(
    const float* __restrict__ qtil,
    const bf16* __restrict__ keyM, const bf16* __restrict__ keyA,
    int mainB, int split,
    float* __restrict__ pm, float* __restrict__ pl, float* __restrict__ pctx)
{
    __shared__ float qt[LQ * DD];
    __shared__ float sc[LQ * CHS];
    __shared__ float redm[4 * LQ];
    __shared__ float redl[4 * LQ];
    int blk = blockIdx.x;
    int c  = blk & (NCH - 1);
    int bh = blk >> 4;
    int b = bh >> 4, h = bh & 15;
    int tid = threadIdx.x;
    int lane = tid & 63, w = tid >> 6;

    for (int x = tid; x < LQ * DD; x += 256) {
        int q = x >> 10;
        qt[x] = qtil[(size_t)((b * LQ + q) * 16 + h) * DD + (x & 1023)];
    }
    __syncthreads();

    int kbeg = c * CHS;
    int kcnt = NKEY - kbeg; if (kcnt > CHS) kcnt = CHS;

    // pass 1: 4 threads per key (quarter-dims), shfl-reduce within lane quad
    {
        int slot = tid >> 2;
        int quarter = tid & 3;
        for (int base = 0; base < kcnt; base += 64) {
            int t = base + slot;
            float acc[LQ];
#pragma unroll
            for (int q = 0; q < LQ; ++q) acc[q] = 0.f;
            if (t < kcnt) {
                int key = kbeg + t;
                const unsigned short* row = (const unsigned short*)(
                    (key < split) ? (const void*)(keyM + (size_t)(b * mainB + key) * DD)
                                  : (const void*)(keyA + (size_t)(b * NS + key - split) * DD));
                row += quarter * 256;
                for (int i = 0; i < 256; i += 8) {
                    short8 v = *(const short8*)(row + i);
                    float f0 = b2f((unsigned short)v[0]), f1 = b2f((unsigned short)v[1]);
                    float f2 = b2f((unsigned short)v[2]), f3 = b2f((unsigned short)v[3]);
                    float f4 = b2f((unsigned short)v[4]), f5 = b2f((unsigned short)v[5]);
                    float f6 = b2f((unsigned short)v[6]), f7 = b2f((unsigned short)v[7]);
#pragma unroll
                    for (int q = 0; q < LQ; ++q) {
                        const float* qq = qt + q * DD + quarter * 256 + i;
                        acc[q] += f0*qq[0] + f1*qq[1] + f2*qq[2] + f3*qq[3]
                                + f4*qq[4] + f5*qq[5] + f6*qq[6] + f7*qq[7];
                    }
                }
            }
#pragma unroll
            for (int q = 0; q < LQ; ++q) {
                acc[q] += __shfl_xor(acc[q], 1);
                acc[q] += __shfl_xor(acc[q], 2);
            }
            if ((tid & 3) == 0 && t < kcnt) {
#pragma unroll
                for (int q = 0; q < LQ; ++q) sc[q * CHS + t] = acc[q];
            }
        }
    }
    __syncthreads();

    // chunk-local max
    float M[LQ], L[LQ];
#pragma unroll
    for (int q = 0; q < LQ; ++q) {
        float lm = -1e30f;
        for (int t = tid; t < kcnt; t += 256) lm = fmaxf(lm, sc[q * CHS + t]);
#pragma unroll
        for (int o = 32; o > 0; o >>= 1) lm = fmaxf(lm, __shfl_xor(lm, o));
        if (lane == 0) redm[w * LQ + q] = lm;
    }
    __syncthreads();
#pragma unroll
    for (int q = 0; q < LQ; ++q)
        M[q] = fmaxf(fmaxf(redm[q], redm[LQ + q]),
                     fmaxf(redm[2 * LQ + q], redm[3 * LQ + q]));
    // exp + sum
#pragma unroll
    for (int q = 0; q < LQ; ++q) {
        float ls = 0.f;
        for (int t = tid; t < kcnt; t += 256) {
            float e = expf(sc[q * CHS + t] - M[q]);
            sc[q * CHS + t] = e;
            ls += e;
        }
        ls = warp_sum(ls);
        if (lane == 0) redl[w * LQ + q] = ls;
    }
    __syncthreads();
#pragma unroll
    for (int q = 0; q < LQ; ++q)
        L[q] = redl[q] + redl[LQ + q] + redl[2 * LQ + q] + redl[3 * LQ + q];

    // pass 2: thread-per-dim ctx accumulation (coalesced key reads, <=65 iters)
    int i4 = tid * 4;
    float cx[LQ][4];
#pragma unroll
    for (int q = 0; q < LQ; ++q) { cx[q][0]=0; cx[q][1]=0; cx[q][2]=0; cx[q][3]=0; }
    for (int t = 0; t < kcnt; ++t) {
        int key = kbeg + t;
        const unsigned short* row = (const unsigned short*)(
            (key < split) ? (const void*)(keyM + (size_t)(b * mainB + key) * DD)
                          : (const void*)(keyA + (size_t)(b * NS + key - split) * DD));
        ushort4 v = *(const ushort4*)(row + i4);
        float f0 = b2f(v.x), f1 = b2f(v.y), f2 = b2f(v.z), f3 = b2f(v.w);
#pragma unroll
        for (int q = 0; q < LQ; ++q) {
            float p = sc[q * CHS + t];
            cx[q][0] += p * f0; cx[q][1] += p * f1;
            cx[q][2] += p * f2; cx[q][3] += p * f3;
        }
    }
#pragma unroll
    for (int q = 0; q < LQ; ++q) {
        float4 o4 = {cx[q][0], cx[q][1], cx[q][2], cx[q][3]};
        *(float4*)(pctx + (size_t)((bh * NCH + c) * LQ + q) * DD + i4) = o4;
    }
    if (tid < LQ) {
        pm[(bh * LQ + tid) * NCH + c] = M[tid];
        pl[(bh * LQ + tid) * NCH + c] = L[tid];
    }
}

// ============ combproj: combine 16 chunk ctx + project through Wv + bv ========
// grid 64*LQ; blk = (b*LQ+q)*16+h. Output attn[(b*LQ+q)*DD + h*64 + o].
template<int LQ>
__global__ __launch_bounds__(256) void combproj_kernel(
    const float* __restrict__ pm, const float* __restrict__ pl,
    const float* __restrict__ pctx,
    const float* __restrict__ Wv, const float* __restrict__ bv,
    float* __restrict__ attn)
{
    __shared__ float ctxf[DD];
    int blk = blockIdx.x;
    int h = blk & 15;
    int bq = blk >> 4;               // b*LQ+q
    int b = bq / LQ, q = bq - b * LQ;
    int bh = b * 16 + h;
    int tid = threadIdx.x;
    int lane = tid & 63, w = tid >> 6;

    int base = (bh * LQ + q) * NCH;
    float Mx = -1e30f;
#pragma unroll
    for (int c = 0; c < NCH; ++c) Mx = fmaxf(Mx, pm[base + c]);
    float wc[NCH];
    float L = 0.f;
#pragma unroll
    for (int c = 0; c < NCH; ++c) {
        wc[c] = expf(pm[base + c] - Mx);
        L += pl[base + c] * wc[c];
    }
    float inv = 1.f / L;
    int i4 = tid * 4;
    float4 s4 = {0.f, 0.f, 0.f, 0.f};
#pragma unroll
    for (int c = 0; c < NCH; ++c) {
        float4 a = *(const float4*)(pctx + (size_t)((bh * NCH + c) * LQ + q) * DD + i4);
        s4.x += a.x * wc[c]; s4.y += a.y * wc[c];
        s4.z += a.z * wc[c]; s4.w += a.w * wc[c];
    }
    ctxf[i4+0] = s4.x * inv;
    ctxf[i4+1] = s4.y * inv;
    ctxf[i4+2] = s4.z * inv;
    ctxf[i4+3] = s4.w * inv;
    __syncthreads();

    // project: wave w handles outs h*64 + w*16 + rr, rr=0..15
#pragma unroll 1
    for (int rr = 0; rr < 16; ++rr) {
        int o = h * 64 + w * 16 + rr;
        const float* Wr = Wv + (size_t)o * DD + lane * 16;
        const float* cf = ctxf + lane * 16;
        float s = 0.f;
#pragma unroll
        for (int j = 0; j < 4; ++j) {
            float4 wv4 = *(const float4*)(Wr + j * 4);
            s += wv4.x * cf[j*4+0] + wv4.y * cf[j*4+1]
               + wv4.z * cf[j*4+2] + wv4.w * cf[j*4+3];
        }
        s = warp_sum(s);
        if (lane == 0)
            attn[(size_t)bq * DD + o] = s + bv[o];
    }
}

// ================= LN of stateNew rows -> bf16 (out-branch keys) ==============
__global__ __launch_bounds__(256) void lnst_kernel(
    const float* __restrict__ stateNew, bf16* __restrict__ lnst,
    const float* __restrict__ g, const float* __restrict__ b)
{
    int r = blockIdx.x;
    int tid = threadIdx.x;
    size_t base = (size_t)r * DD;
    float v[4];
    float s1 = 0.f, s2 = 0.f;
#pragma unroll
    for (int i = 0; i < 4; ++i) {
        v[i] = stateNew[base + i * 256 + tid];
        s1 += v[i]; s2 += v[i] * v[i];
    }
    s1 = warp_sum(s1); s2 = warp_sum(s2);
    __shared__ float a1[4], a2[4];
    int w = tid >> 6;
    if ((tid & 63) == 0) { a1[w] = s1; a2[w] = s2; }
    __syncthreads();
    s1 = a1[0] + a1[1] + a1[2] + a1[3];
    s2 = a2[0] + a2[1] + a2[2] + a2[3];
    float mu  = s1 * (1.0f / DD);
    float var = s2 * (1.0f / DD) - mu * mu;
    var = var < 0.f ? 0.f : var;
    float rs = rsqrtf(var + 1e-5f);
#pragma unroll
    for (int i = 0; i < 4; ++i) {
        int c = i * 256 + tid;
        lnst[base + c] = __float2bfloat16((v[i] - mu) * rs * g[c] + b[c]);
    }
}

// ========== fused gate: LN(lat2) -> logits -> top2 -> state update ============
__global__ __launch_bounds__(256) void gate_fused_kernel(
    const float* __restrict__ lat2,
    const float* __restrict__ lng, const float* __restrict__ lnb,
    const float* __restrict__ ctx,
    const float* __restrict__ state_old, float* __restrict__ stateNew,
    float* __restrict__ dout)
{
    int b = blockIdx.x;
    int tid = threadIdx.x;
    int lane = tid & 63, w = tid >> 6;
    __shared__ float logit[NS];
    __shared__ float alpha[NS];

    {
        const float* row = lat2 + (size_t)(b * NS + w) * DD;
        float4 v[4];
        float s1 = 0.f, s2 = 0.f;
#pragma unroll
        for (int j = 0; j < 4; ++j) {
            v[j] = *(const float4*)(row + (j * 64 + lane) * 4);
            s1 += v[j].x + v[j].y + v[j].z + v[j].w;
            s2 += v[j].x*v[j].x + v[j].y*v[j].y + v[j].z*v[j].z + v[j].w*v[j].w;
        }
        s1 = warp_sum(s1); s2 = warp_sum(s2);
        float mu = s1 * (1.0f / DD);
        float var = s2 * (1.0f / DD) - mu * mu;
        var = var < 0.f ? 0.f : var;
        float rs = rsqrtf(var + 1e-5f);
        float dot = 0.f;
#pragma unroll
        for (int j = 0; j < 4; ++j) {
            int c = (j * 64 + lane) * 4;
            float4 gv = *(const float4*)(lng + c);
            float4 bv = *(const float4*)(lnb + c);
            float4 cv = *(const float4*)(ctx + c);
            dot += ((v[j].x - mu) * rs * gv.x + bv.x) * cv.x
                 + ((v[j].y - mu) * rs * gv.y + bv.y) * cv.y
                 + ((v[j].z - mu) * rs * gv.z + bv.z) * cv.z
                 + ((v[j].w - mu) * rs * gv.w + bv.w) * cv.w;
        }
        dot = warp_sum(dot);
        if (lane == 0) logit[w] = dot;
    }
    __syncthreads();
    if (tid == 0) {
        float l[NS];
        for (int s = 0; s < NS; ++s) l[s] = logit[s];
        int i0 = 0;
        for (int s = 1; s < NS; ++s) if (l[s] > l[i0]) i0 = s;
        int i1 = (i0 == 0) ? 1 : 0;
        for (int s = 0; s < NS; ++s) if (s != i0 && l[s] > l[i1]) i1 = s;
        float mx = fmaxf(l[i0], l[i1]);
        float e0 = expf(l[i0] - mx), e1 = expf(l[i1] - mx);
        float inv = 1.f / (e0 + e1);
        for (int s = 0; s < NS; ++s) alpha[s] = 0.f;
        alpha[i0] = e0 * inv;
        alpha[i1] += e1 * inv;
        dout[4096 + b * 2 + 0] = (float)i0;
        dout[4096 + b * 2 + 1] = (float)i1;
    }
    __syncthreads();
    for (int idx = tid; idx < NS * DD; idx += 256) {
        int s = idx >> 10;
        float so = state_old[(size_t)b * NS * DD + idx];
        float lt = lat2[(size_t)b * NS * DD + idx];
        float ns = 0.6f * so + 0.4f * alpha[s] * tanhf(lt);
        stateNew[(size_t)b * NS * DD + idx] = ns;
        dout[4104 + b * NS * DD + idx] = ns;
    }
}

extern "C" void kernel_launch(void* const* d_in, const int* in_sizes, int n_in,
                              void* d_out, int out_size, void* d_ws, size_t ws_size,
                              hipStream_t stream)
{
    const float* x        = (const float*)d_in[0];
    const float* state0   = (const float*)d_in[1];
    const float* se_W     = (const float*)d_in[2];
    const float* se_b     = (const float*)d_in[3];
    const float* s_Wq     = (const float*)d_in[4];
    const float* s_bq     = (const float*)d_in[5];
    const float* s_Wk     = (const float*)d_in[6];
    const float* s_bk     = (const float*)d_in[7];   (void)s_bk;  // drops out of softmax
    const float* s_Wv     = (const float*)d_in[8];
    const float* s_bv     = (const float*)d_in[9];
    const float* s_Wo     = (const float*)d_in[10];
    const float* s_bo     = (const float*)d_in[11];
    const float* s_lnq_g  = (const float*)d_in[12];
    const float* s_lnq_b  = (const float*)d_in[13];
    const float* s_lnkv_g = (const float*)d_in[14];
    const float* s_lnkv_b = (const float*)d_in[15];
    const float* s_fc1_W  = (const float*)d_in[16];
    const float* s_fc1_b  = (const float*)d_in[17];
    const float* s_fc2_W  = (const float*)d_in[18];
    const float* s_fc2_b  = (const float*)d_in[19];
    const float* s_lnffn_g= (const float*)d_in[20];
    const float* s_lnffn_b= (const float*)d_in[21];
    const float* s_lnslot_g=(const float*)d_in[22];
    const float* s_lnslot_b=(const float*)d_in[23];
    const float* slot_ctx = (const float*)d_in[24];
    const float* oe_W     = (const float*)d_in[25];
    const float* oe_b     = (const float*)d_in[26];
    const float* o_Wq     = (const float*)d_in[27];
    const float* o_bq     = (const float*)d_in[28];
    const float* o_Wk     = (const float*)d_in[29];
    const float* o_bk     = (const float*)d_in[30];  (void)o_bk;  // drops out of softmax
    const float* o_Wv     = (const float*)d_in[31];
    const float* o_bv     = (const float*)d_in[32];
    const float* o_Wo     = (const float*)d_in[33];
    const float* o_bo     = (const float*)d_in[34];
    const float* o_lnq_g  = (const float*)d_in[35];
    const float* o_lnq_b  = (const float*)d_in[36];
    const float* o_lnkv_g = (const float*)d_in[37];
    const float* o_lnkv_b = (const float*)d_in[38];
    const float* o_fc1_W  = (const float*)d_in[39];
    const float* o_fc1_b  = (const float*)d_in[40];
    const float* o_fc2_W  = (const float*)d_in[41];
    const float* o_fc2_b  = (const float*)d_in[42];
    const float* o_lnffn_g= (const float*)d_in[43];
    const float* o_lnffn_b= (const float*)d_in[44];
    const float* op_W     = (const float*)d_in[45];
    const float* op_b     = (const float*)d_in[46];

    float* ws = (float*)d_ws;
    float* pe    = ws;
    float* cat   = ws + 1048576;                 // consumed by ln_fused, then reused:
    float* qtil_s= ws + 1048576;                 //   256 x 1024
    float* qtil_o= ws + 1310720;                 //   64 x 1024
    float* pctx_o= ws + 1376256;                 //   64*16*1 x 1024 = 1,048,576
    float* pms   = ws + 2424832;                 //   64*4*16 = 4096
    float* pls   = ws + 2428928;                 //   4096
    float* pmo   = ws + 2433024;                 //   64*1*16 = 1024
    float* plo   = ws + 2434048;                 //   1024
    bf16*  lnbb  = (bf16*)(ws + 5259264);        // 4112 rows bf16
    float* cat2  = ws + 7421952;                 // consumed in phase 2, then:
    float* pctx_s= ws + 7421952;                 //   64*16*4 x 1024 = 4,194,304
    bf16*  xb    = (bf16*)(ws + 11632640);       // xb early, lnbb2 late (alias)
    bf16*  lnbb2 = (bf16*)(ws + 11632640);
    bf16*  seWb  = (bf16*)(ws + 13729792);
    bf16*  oeWb  = seWb + 1048576;
    float* sm    = ws + 16875520;
    float* qh_s    = sm + 16384;
    float* attn_s  = sm + 32768;
    float* lat1    = sm + 49152;
    float* g1      = sm + 81920;
    float* lat2    = sm + 98304;
    float* q2h     = sm + 135232;
    float* attn2   = sm + 139328;
    float* lo_last = sm + 143424;
    float* lo1     = sm + 147520;
    float* g2      = sm + 155712;
    float* lo2     = sm + 159808;
    float* stateNew= sm + 231488;
    bf16*  lnst    = (bf16*)(sm + 247872);       // 16 x 1024 bf16
    float* out = (float*)d_out;

    dim3 blk(256);

    // ---- phase 0: conversions (x, seW, oeW only) + PE + state-row copy ----
    PrepArgs pa;
    pa.x = x; pa.seW = se_W; pa.oeW = oe_W;
    pa.xb = xb; pa.seWb = seWb; pa.oeWb = oeWb;
    pa.state0 = state0; pa.cat = cat; pa.pe = pe;
    prep_kernel<<<7184, blk, 0, stream>>>(pa);

    // ---- phase 1: both embeds (MFMA), XCD-swizzled ----
    embed_fused_kernel<<<512, blk, 0, stream>>>(
        xb, seWb, oeWb, se_b, oe_b, cat, cat2, pe);

    // ---- phase 2: big LNs + q projections + lo_last ----
    ln_fused_kernel<<<8208, blk, 0, stream>>>(cat, cat2, lnbb, lnbb2,
        s_lnkv_g, s_lnkv_b, o_lnkv_g, o_lnkv_b);
    small_ln_gemm_kernel<16><<<256, blk, 0, stream>>>(state0, 0, 1,
        s_lnq_g, s_lnq_b, s_Wq, s_bq, qh_s, 0);
    small_ln_gemm_kernel<4><<<256, blk, 0, stream>>>(cat2, TT - 1, LKV,
        o_lnq_g, o_lnq_b, o_Wq, o_bq, q2h, 0);
    copy_lolast_kernel<<<NB, blk, 0, stream>>>(cat2, lo_last);

    // ---- phase 3: query-side Wk projection (replaces K GEMMs) ----
    qtil_kernel<<<320, blk, 0, stream>>>(qh_s, q2h, s_Wk, o_Wk, qtil_s, qtil_o);

    // ---- phase 4: state-branch attention (16-chunk sc_ctx) + slot MLP ----
    sc_ctx_kernel<4><<<1024, blk, 0, stream>>>(qtil_s, lnbb, nullptr, LKV, 2000,
        pms, pls, pctx_s);
    combproj_kernel<4><<<256, blk, 0, stream>>>(pms, pls, pctx_s, s_Wv, s_bv, attn_s);
    small_gemm_kernel<16><<<256, blk, 0, stream>>>(attn_s, s_Wo, s_bo, lat1, state0, 0);
    small_ln_gemm_kernel<16><<<256, blk, 0, stream>>>(lat1, 0, 1,
        s_lnffn_g, s_lnffn_b, s_fc1_W, s_fc1_b, g1, 1);
    small_gemm_kernel<16><<<256, blk, 0, stream>>>(g1, s_fc2_W, s_fc2_b, lat2, lat1, 0);
    gate_fused_kernel<<<NB, blk, 0, stream>>>(lat2, s_lnslot_g, s_lnslot_b,
        slot_ctx, state0, stateNew, out);

    // ---- phase 5: out-branch attention (tokens from lnbb2 + 4 new-state rows) ----
    lnst_kernel<<<16, blk, 0, stream>>>(stateNew, lnst, o_lnkv_g, o_lnkv_b);
    sc_ctx_kernel<1><<<1024, blk, 0, stream>>>(qtil_o, lnbb2, lnst, TT, TT,
        pmo, plo, pctx_o);
    combproj_kernel<1><<<64, blk, 0, stream>>>(pmo, plo, pctx_o, o_Wv, o_bv, attn2);
    small_gemm_kernel<4><<<256, blk, 0, stream>>>(attn2, o_Wo, o_bo, lo1, lo_last, 0);
    small_ln_gemm_kernel<4><<<256, blk, 0, stream>>>(lo1, 0, 1,
        o_lnffn_g, o_lnffn_b, o_fc1_W, o_fc1_b, g2, 1);
    small_gemm_kernel<4><<<256, blk, 0, stream>>>(g2, o_fc2_W, o_fc2_b, lo2, lo1, 0);
    small_gemm_kernel<4><<<256, blk, 0, stream>>>(lo2, op_W, op_b, out, nullptr, 0);
}

// Round 16
// 214.614 us; speedup vs baseline: 1.5476x; 1.2260x over previous
//
#include <hip/hip_runtime.h>
#include <hip/hip_bf16.h>

#define DD 1024
#define NB 4
#define TT 1024
#define NH 16
#define NS 4
#define LKV 1028   // NS + TT
#define NCH 16
#define CHS 65     // 16*65 = 1040 >= 1028
#define NKEY 1028

typedef __hip_bfloat16 bf16;
typedef __attribute__((ext_vector_type(8))) short short8;
typedef __attribute__((ext_vector_type(4))) float f32x4;

#define GLD16(gp, lp) __builtin_amdgcn_global_load_lds( \
    (const __attribute__((address_space(1))) unsigned int*)(const void*)(gp), \
    (__attribute__((address_space(3))) unsigned int*)(void*)(lp), 16, 0, 0)

__device__ __forceinline__ float warp_sum(float v) {
#pragma unroll
    for (int o = 32; o > 0; o >>= 1) v += __shfl_xor(v, o);
    return v;
}

__device__ __forceinline__ float b2f(unsigned short u) {
    union { unsigned int i; float f; } x; x.i = ((unsigned)u) << 16; return x.f;
}

// ================= prep: cvt x + 2 embed weights, PE table, state copy ========
struct PrepArgs {
    const float* x;
    const float* seW;
    const float* oeW;
    bf16 *xb, *seWb, *oeWb;
    const float* state0;
    float* cat;
    float* pe;
};

__global__ __launch_bounds__(256) void prep_kernel(PrepArgs a) {
    int bid = blockIdx.x;
    int tid = threadIdx.x;
    if (bid < 6144) {
        const float* in; bf16* out; size_t off;
        if (bid < 4096)      { in = a.x;   out = a.xb;   off = (size_t)bid * 1024; }
        else if (bid < 5120) { in = a.seW; out = a.seWb; off = (size_t)(bid - 4096) * 1024; }
        else                 { in = a.oeW; out = a.oeWb; off = (size_t)(bid - 5120) * 1024; }
        size_t i = off + tid * 4;
        float4 v = *(const float4*)(in + i);
        out[i + 0] = __float2bfloat16(v.x);
        out[i + 1] = __float2bfloat16(v.y);
        out[i + 2] = __float2bfloat16(v.z);
        out[i + 3] = __float2bfloat16(v.w);
    } else if (bid < 7168) {
        int t = bid - 6144;
#pragma unroll
        for (int i = 0; i < 2; ++i) {
            int j = i * 256 + tid;                       // 0..511
            float ang = (float)t * exp2f(-(float)j * (1.0f / 256.0f));
            a.pe[(size_t)t * DD + j]       = sinf(ang);
            a.pe[(size_t)t * DD + 512 + j] = cosf(ang);
        }
    } else {
        int r = bid - 7168;        // 0..15
        int b = r >> 2, s = r & 3;
#pragma unroll
        for (int i = 0; i < 4; ++i)
            a.cat[(size_t)(b * LKV + s) * DD + i * 256 + tid] =
                a.state0[(size_t)r * DD + i * 256 + tid];
    }
}

// ================= fused LayerNorm -> bf16 (state-kv rows + out token rows) ===
__global__ __launch_bounds__(256) void ln_fused_kernel(
    const float* __restrict__ cat, const float* __restrict__ cat2,
    bf16* __restrict__ lnbb, bf16* __restrict__ lnbb2,
    const float* __restrict__ sg, const float* __restrict__ sb,
    const float* __restrict__ og, const float* __restrict__ ob)
{
    int bid = blockIdx.x;
    int tid = threadIdx.x;
    const float* in; bf16* out; const float* g; const float* b;
    if (bid < 4112) {
        in = cat + (size_t)bid * DD; out = lnbb + (size_t)bid * DD; g = sg; b = sb;
    } else {
        int r = bid - 4112;
        int row = (r >> 10) * LKV + (r & 1023);
        in = cat2 + (size_t)row * DD; out = lnbb2 + (size_t)r * DD; g = og; b = ob;
    }
    float v[4];
    float s1 = 0.f, s2 = 0.f;
#pragma unroll
    for (int i = 0; i < 4; ++i) {
        v[i] = in[i * 256 + tid];
        s1 += v[i]; s2 += v[i] * v[i];
    }
    s1 = warp_sum(s1); s2 = warp_sum(s2);
    __shared__ float a1[4], a2[4];
    int w = tid >> 6;
    if ((tid & 63) == 0) { a1[w] = s1; a2[w] = s2; }
    __syncthreads();
    s1 = a1[0] + a1[1] + a1[2] + a1[3];
    s2 = a2[0] + a2[1] + a2[2] + a2[3];
    float mu  = s1 * (1.0f / DD);
    float var = s2 * (1.0f / DD) - mu * mu;
    var = var < 0.f ? 0.f : var;
    float rs = rsqrtf(var + 1e-5f);
#pragma unroll
    for (int i = 0; i < 4; ++i) {
        int c = i * 256 + tid;
        out[c] = __float2bfloat16((v[i] - mu) * rs * g[c] + b[c]);
    }
}

// ================= MFMA tile body (128x128, BK=32, 4 waves) ===================
__device__ __forceinline__ void mfma_tile(
    const bf16* __restrict__ A, const bf16* __restrict__ W,
    const float* __restrict__ bias,
    float* __restrict__ outf,
    int obs, int oro, const float* __restrict__ pe,
    bf16* As, bf16* Ws, int m0, int n0)
{
    int tid  = threadIdx.x;
    int lane = tid & 63;
    int wave = tid >> 6;
    int wm = (wave >> 1) << 6;
    int wn = (wave & 1) << 6;

    f32x4 acc[4][4] = {};

    int soff  = wave * 1024 + lane * 16;
    int srow  = soff >> 6;
    int scol  = (soff & 63) >> 1;
    char* lA0 = (char*)As + wave * 1024;
    char* lA1 = (char*)As + 4096 + wave * 1024;
    char* lW0 = (char*)Ws + wave * 1024;
    char* lW1 = (char*)Ws + 4096 + wave * 1024;

    int fRow = lane & 15;
    int kOff = (lane >> 4) << 3;

    for (int k0 = 0; k0 < DD; k0 += 32) {
        GLD16(A + (size_t)(m0 + srow) * DD + k0 + scol,      lA0);
        GLD16(A + (size_t)(m0 + 64 + srow) * DD + k0 + scol, lA1);
        GLD16(W + (size_t)(n0 + srow) * DD + k0 + scol,      lW0);
        GLD16(W + (size_t)(n0 + 64 + srow) * DD + k0 + scol, lW1);
        __syncthreads();
        short8 a[4], b[4];
#pragma unroll
        for (int mi = 0; mi < 4; ++mi)
            a[mi] = *(const short8*)(As + (wm + mi * 16 + fRow) * 32 + kOff);
#pragma unroll
        for (int ni = 0; ni < 4; ++ni)
            b[ni] = *(const short8*)(Ws + (wn + ni * 16 + fRow) * 32 + kOff);
#pragma unroll
        for (int mi = 0; mi < 4; ++mi)
#pragma unroll
            for (int ni = 0; ni < 4; ++ni)
                acc[mi][ni] = __builtin_amdgcn_mfma_f32_16x16x32_bf16(
                    a[mi], b[ni], acc[mi][ni], 0, 0, 0);
        __syncthreads();
    }

    int cCol  = lane & 15;
    int cRow4 = (lane >> 4) << 2;
#pragma unroll
    for (int mi = 0; mi < 4; ++mi) {
#pragma unroll
        for (int ni = 0; ni < 4; ++ni) {
#pragma unroll
            for (int r = 0; r < 4; ++r) {
                int row = m0 + wm + mi * 16 + cRow4 + r;
                int col = n0 + wn + ni * 16 + cCol;
                float v = acc[mi][ni][r] + bias[col] + pe[(size_t)(row & 1023) * DD + col];
                int orow = (row >> 10) * obs + oro + (row & 1023);
                outf[(size_t)orow * DD + col] = v;
            }
        }
    }
}

// ================= fused embeds, XCD-swizzled linear grid (512 blocks) ========
__global__ __launch_bounds__(256) void embed_fused_kernel(
    const bf16* __restrict__ xb,
    const bf16* __restrict__ seW, const bf16* __restrict__ oeW,
    const float* __restrict__ seb, const float* __restrict__ oeb,
    float* __restrict__ cat, float* __restrict__ cat2,
    const float* __restrict__ pe)
{
    __shared__ bf16 As[128 * 32];
    __shared__ bf16 Ws[128 * 32];
    int bid = blockIdx.x;
    int t = (bid & 7) * 64 + (bid >> 3);   // bijective XCD swizzle (512 = 8*64)
    int x = t & 7;
    int q = t >> 3;
    int z = q & 1;
    int y = q >> 1;
    const bf16* W = z ? oeW : seW;
    const float* bias = z ? oeb : seb;
    float* outf = z ? cat2 : cat;
    int oro = z ? 0 : NS;
    mfma_tile(xb, W, bias, outf, LKV, oro, pe, As, Ws, y * 128, x * 128);
}

// ================= copy lo[:, -1] =============================================
__global__ __launch_bounds__(256) void copy_lolast_kernel(
    const float* __restrict__ cat2, float* __restrict__ dst)
{
    int b = blockIdx.x;
    int tid = threadIdx.x;
#pragma unroll
    for (int i = 0; i < 4; ++i)
        dst[(size_t)b * DD + i * 256 + tid] =
            cat2[(size_t)(b * LKV + (TT - 1)) * DD + i * 256 + tid];
}

// ================= small GEMM (M<=16), f32 LDS staging =========================
template<int M>
__global__ __launch_bounds__(256) void small_gemm_kernel(
    const float* __restrict__ A, const float* __restrict__ W,
    const float* __restrict__ bias, float* __restrict__ out,
    const float* __restrict__ res, int gelu)
{
    __shared__ float As[M * DD];
    int tid = threadIdx.x;
#pragma unroll
    for (int i = 0; i < M; ++i) {
        int idx = (i * 256 + tid) * 4;
        *(float4*)(As + idx) = *(const float4*)(A + idx);
    }
    __syncthreads();
    int lane = tid & 63;
    int w = tid >> 6;
    int n = blockIdx.x * 4 + w;
    const float* Wr = W + (size_t)n * DD;
    float acc[M] = {};
#pragma unroll
    for (int j = 0; j < 4; ++j) {
        float4 wv = *(const float4*)(Wr + j * 256 + lane * 4);
#pragma unroll
        for (int m = 0; m < M; ++m) {
            float4 av = *(const float4*)(As + m * DD + j * 256 + lane * 4);
            acc[m] += av.x * wv.x + av.y * wv.y + av.z * wv.z + av.w * wv.w;
        }
    }
#pragma unroll
    for (int m = 0; m < M; ++m) acc[m] = warp_sum(acc[m]);
    if (lane == 0) {
#pragma unroll
        for (int m = 0; m < M; ++m) {
            float v = acc[m] + bias[n];
            if (gelu) v = 0.5f * v * (1.0f + erff(v * 0.70710678118654752f));
            if (res)  v += res[(size_t)m * DD + n];
            out[(size_t)m * DD + n] = v;
        }
    }
}

// ============ small GEMM with fused input LayerNorm ===========================
template<int M>
__global__ __launch_bounds__(256) void small_ln_gemm_kernel(
    const float* __restrict__ A, int row0, int rstride,
    const float* __restrict__ lng, const float* __restrict__ lnb,
    const float* __restrict__ W, const float* __restrict__ bias,
    float* __restrict__ outf, int gelu)
{
    __shared__ float As[M * DD];
    __shared__ float smu[M], srs[M];
    int tid = threadIdx.x;
    int lane = tid & 63;
    int w = tid >> 6;
#pragma unroll
    for (int i = 0; i < M; ++i) {
        int row = row0 + i * rstride;
        *(float4*)(As + i * DD + tid * 4) =
            *(const float4*)(A + (size_t)row * DD + tid * 4);
    }
    __syncthreads();
    constexpr int RPW = (M + 3) / 4;
#pragma unroll
    for (int i = 0; i < RPW; ++i) {
        int r = w * RPW + i;
        if (r < M) {
            float s1 = 0.f, s2 = 0.f;
#pragma unroll
            for (int j = 0; j < 4; ++j) {
                float4 v = *(const float4*)(As + r * DD + (j * 64 + lane) * 4);
                s1 += v.x + v.y + v.z + v.w;
                s2 += v.x*v.x + v.y*v.y + v.z*v.z + v.w*v.w;
            }
            s1 = warp_sum(s1); s2 = warp_sum(s2);
            if (lane == 0) {
                float mu = s1 * (1.0f / DD);
                float var = s2 * (1.0f / DD) - mu * mu;
                var = var < 0.f ? 0.f : var;
                smu[r] = mu; srs[r] = rsqrtf(var + 1e-5f);
            }
        }
    }
    __syncthreads();
    float4 gv = *(const float4*)(lng + tid * 4);
    float4 bv = *(const float4*)(lnb + tid * 4);
#pragma unroll
    for (int i = 0; i < M; ++i) {
        float mu = smu[i], rs = srs[i];
        float4 v = *(const float4*)(As + i * DD + tid * 4);
        v.x = (v.x - mu) * rs * gv.x + bv.x;
        v.y = (v.y - mu) * rs * gv.y + bv.y;
        v.z = (v.z - mu) * rs * gv.z + bv.z;
        v.w = (v.w - mu) * rs * gv.w + bv.w;
        *(float4*)(As + i * DD + tid * 4) = v;
    }
    __syncthreads();
    int n = blockIdx.x * 4 + w;
    const float* Wr = W + (size_t)n * DD;
    float acc[M] = {};
#pragma unroll
    for (int j = 0; j < 4; ++j) {
        float4 wv = *(const float4*)(Wr + j * 256 + lane * 4);
#pragma unroll
        for (int m = 0; m < M; ++m) {
            float4 av = *(const float4*)(As + m * DD + j * 256 + lane * 4);
            acc[m] += av.x * wv.x + av.y * wv.y + av.z * wv.z + av.w * wv.w;
        }
    }
#pragma unroll
    for (int m = 0; m < M; ++m) acc[m] = warp_sum(acc[m]);
    if (lane == 0) {
#pragma unroll
        for (int m = 0; m < M; ++m) {
            float v = acc[m] + bias[n];
            if (gelu) v = 0.5f * v * (1.0f + erff(v * 0.70710678118654752f));
            outf[(size_t)m * DD + n] = v;
        }
    }
}

// ============ qtil: project queries through Wk (low-rank attention trick) =====
__global__ __launch_bounds__(256) void qtil_kernel(
    const float* __restrict__ qh_s, const float* __restrict__ q2h,
    const float* __restrict__ sWk, const float* __restrict__ oWk,
    float* __restrict__ qtil_s, float* __restrict__ qtil_o)
{
    int blk = blockIdx.x;
    int tid = threadIdx.x;
    const float* src; const float* W; float* dst; int h;
    if (blk < 256) {
        int bq = blk >> 4;          // b*4+q
        h = blk & 15;
        src = qh_s + (size_t)bq * DD;
        W = sWk; dst = qtil_s + (size_t)blk * DD;
    } else {
        int o = blk - 256;
        int b = o >> 4;
        h = o & 15;
        src = q2h + (size_t)b * DD;
        W = oWk; dst = qtil_o + (size_t)o * DD;
    }
    __shared__ float qv[64];
    if (tid < 64) qv[tid] = src[h * 64 + tid];
    __syncthreads();
    int i = tid * 4;
    float4 acc = {0.f, 0.f, 0.f, 0.f};
#pragma unroll 4
    for (int o = 0; o < 64; ++o) {
        float4 wr = *(const float4*)(W + (size_t)(h * 64 + o) * DD + i);
        float s = qv[o];
        acc.x += s * wr.x; acc.y += s * wr.y; acc.z += s * wr.z; acc.w += s * wr.w;
    }
    acc.x *= 0.125f; acc.y *= 0.125f; acc.z *= 0.125f; acc.w *= 0.125f;
    *(float4*)(dst + i) = acc;
}

// ============ sc_ctx: scores + softmax-partial + ctx (16 chunks of 65 keys) ===
// grid 64*NCH. Pass 1 is register/shuffle-only: lane holds q-dims [16l,16l+16)
// in VGPRs; wave-per-key coalesced reads; shfl reduce. No LDS on the dot path.
template<int LQ>
__global__ __launch_bounds__(256) void sc_ctx_kernel(
    const float* __restrict__ qtil,
    const bf16* __restrict__ keyM, const bf16* __restrict__ keyA,
    int mainB, int split,
    float* __restrict__ pm, float* __restrict__ pl, float* __restrict__ pctx)
{
    __shared__ float sc[LQ * CHS];
    __shared__ float redm[4 * LQ];
    __shared__ float redl[4 * LQ];
    int blk = blockIdx.x;
    int c  = blk & (NCH - 1);
    int bh = blk >> 4;
    int b = bh >> 4, h = bh & 15;
    int tid = threadIdx.x;
    int lane = tid & 63, w = tid >> 6;

    // q fragments in registers: lane holds dims [lane*16, lane*16+16)
    float qreg[LQ][16];
#pragma unroll
    for (int q = 0; q < LQ; ++q) {
        const float* qrow = qtil + (size_t)((b * LQ + q) * 16 + h) * DD + lane * 16;
#pragma unroll
        for (int j = 0; j < 4; ++j) {
            float4 v = *(const float4*)(qrow + j * 4);
            qreg[q][j*4+0] = v.x; qreg[q][j*4+1] = v.y;
            qreg[q][j*4+2] = v.z; qreg[q][j*4+3] = v.w;
        }
    }

    int kbeg = c * CHS;
    int kcnt = NKEY - kbeg; if (kcnt > CHS) kcnt = CHS;

    // pass 1: wave-per-key (stride 4), coalesced 32B/lane key reads, shfl reduce
    for (int t = w; t < kcnt; t += 4) {
        int key = kbeg + t;
        const unsigned short* row = (const unsigned short*)(
            (key < split) ? (const void*)(keyM + (size_t)(b * mainB + key) * DD)
                          : (const void*)(keyA + (size_t)(b * NS + key - split) * DD))
            + lane * 16;
        float kf[16];
#pragma unroll
        for (int j = 0; j < 4; ++j) {
            ushort4 v = *(const ushort4*)(row + j * 4);
            kf[j*4+0] = b2f(v.x); kf[j*4+1] = b2f(v.y);
            kf[j*4+2] = b2f(v.z); kf[j*4+3] = b2f(v.w);
        }
        float acc[LQ];
#pragma unroll
        for (int q = 0; q < LQ; ++q) acc[q] = 0.f;
#pragma unroll
        for (int j = 0; j < 16; ++j)
#pragma unroll
            for (int q = 0; q < LQ; ++q)
                acc[q] += kf[j] * qreg[q][j];
#pragma unroll
        for (int q = 0; q < LQ; ++q) acc[q] = warp_sum(acc[q]);
        if (lane == 0) {
#pragma unroll
            for (int q = 0; q < LQ; ++q) sc[q * CHS + t] = acc[q];
        }
    }
    __syncthreads();

    // chunk-local max
    float M[LQ], L[LQ];
#pragma unroll
    for (int q = 0; q < LQ; ++q) {
        float lm = -1e30f;
        for (int t = tid; t < kcnt; t += 256) lm = fmaxf(lm, sc[q * CHS + t]);
#pragma unroll
        for (int o = 32; o > 0; o >>= 1) lm = fmaxf(lm, __shfl_xor(lm, o));
        if (lane == 0) redm[w * LQ + q] = lm;
    }
    __syncthreads();
#pragma unroll
    for (int q = 0; q < LQ; ++q)
        M[q] = fmaxf(fmaxf(redm[q], redm[LQ + q]),
                     fmaxf(redm[2 * LQ + q], redm[3 * LQ + q]));
    // exp + sum
#pragma unroll
    for (int q = 0; q < LQ; ++q) {
        float ls = 0.f;
        for (int t = tid; t < kcnt; t += 256) {
            float e = expf(sc[q * CHS + t] - M[q]);
            sc[q * CHS + t] = e;
            ls += e;
        }
        ls = warp_sum(ls);
        if (lane == 0) redl[w * LQ + q] = ls;
    }
    __syncthreads();
#pragma unroll
    for (int q = 0; q < LQ; ++q)
        L[q] = redl[q] + redl[LQ + q] + redl[2 * LQ + q] + redl[3 * LQ + q];

    // pass 2: thread-per-dim ctx accumulation (coalesced key reads, <=65 iters)
    int i4 = tid * 4;
    float cx[LQ][4];
#pragma unroll
    for (int q = 0; q < LQ; ++q) { cx[q][0]=0; cx[q][1]=0; cx[q][2]=0; cx[q][3]=0; }
    for (int t = 0; t < kcnt; ++t) {
        int key = kbeg + t;
        const unsigned short* row = (const unsigned short*)(
            (key < split) ? (const void*)(keyM + (size_t)(b * mainB + key) * DD)
                          : (const void*)(keyA + (size_t)(b * NS + key - split) * DD));
        ushort4 v = *(const ushort4*)(row + i4);
        float f0 = b2f(v.x), f1 = b2f(v.y), f2 = b2f(v.z), f3 = b2f(v.w);
#pragma unroll
        for (int q = 0; q < LQ; ++q) {
            float p = sc[q * CHS + t];
            cx[q][0] += p * f0; cx[q][1] += p * f1;
            cx[q][2] += p * f2; cx[q][3] += p * f3;
        }
    }
#pragma unroll
    for (int q = 0; q < LQ; ++q) {
        float4 o4 = {cx[q][0], cx[q][1], cx[q][2], cx[q][3]};
        *(float4*)(pctx + (size_t)((bh * NCH + c) * LQ + q) * DD + i4) = o4;
    }
    if (tid < LQ) {
        pm[(bh * LQ + tid) * NCH + c] = M[tid];
        pl[(bh * LQ + tid) * NCH + c] = L[tid];
    }
}

// ============ combproj: combine 16 chunk ctx + project through Wv + bv ========
template<int LQ>
__global__ __launch_bounds__(256) void combproj_kernel(
    const float* __restrict__ pm, const float* __restrict__ pl,
    const float* __restrict__ pctx,
    const float* __restrict__ Wv, const float* __restrict__ bv,
    float* __restrict__ attn)
{
    __shared__ float ctxf[DD];
    int blk = blockIdx.x;
    int h = blk & 15;
    int bq = blk >> 4;               // b*LQ+q
    int b = bq / LQ, q = bq - b * LQ;
    int bh = b * 16 + h;
    int tid = threadIdx.x;
    int lane = tid & 63, w = tid >> 6;

    int base = (bh * LQ + q) * NCH;
    float Mx = -1e30f;
#pragma unroll
    for (int c = 0; c < NCH; ++c) Mx = fmaxf(Mx, pm[base + c]);
    float wc[NCH];
    float L = 0.f;
#pragma unroll
    for (int c = 0; c < NCH; ++c) {
        wc[c] = expf(pm[base + c] - Mx);
        L += pl[base + c] * wc[c];
    }
    float inv = 1.f / L;
    int i4 = tid * 4;
    float4 s4 = {0.f, 0.f, 0.f, 0.f};
#pragma unroll
    for (int c = 0; c < NCH; ++c) {
        float4 a = *(const float4*)(pctx + (size_t)((bh * NCH + c) * LQ + q) * DD + i4);
        s4.x += a.x * wc[c]; s4.y += a.y * wc[c];
        s4.z += a.z * wc[c]; s4.w += a.w * wc[c];
    }
    ctxf[i4+0] = s4.x * inv;
    ctxf[i4+1] = s4.y * inv;
    ctxf[i4+2] = s4.z * inv;
    ctxf[i4+3] = s4.w * inv;
    __syncthreads();

    // project: wave w handles outs h*64 + w*16 + rr, rr=0..15
#pragma unroll 1
    for (int rr = 0; rr < 16; ++rr) {
        int o = h * 64 + w * 16 + rr;
        const float* Wr = Wv + (size_t)o * DD + lane * 16;
        const float* cf = ctxf + lane * 16;
        float s = 0.f;
#pragma unroll
        for (int j = 0; j < 4; ++j) {
            float4 wv4 = *(const float4*)(Wr + j * 4);
            s += wv4.x * cf[j*4+0] + wv4.y * cf[j*4+1]
               + wv4.z * cf[j*4+2] + wv4.w * cf[j*4+3];
        }
        s = warp_sum(s);
        if (lane == 0)
            attn[(size_t)bq * DD + o] = s + bv[o];
    }
}

// ================= LN of stateNew rows -> bf16 (out-branch keys) ==============
__global__ __launch_bounds__(256) void lnst_kernel(
    const float* __restrict__ stateNew, bf16* __restrict__ lnst,
    const float* __restrict__ g, const float* __restrict__ b)
{
    int r = blockIdx.x;
    int tid = threadIdx.x;
    size_t base = (size_t)r * DD;
    float v[4];
    float s1 = 0.f, s2 = 0.f;
#pragma unroll
    for (int i = 0; i < 4; ++i) {
        v[i] = stateNew[base + i * 256 + tid];
        s1 += v[i]; s2 += v[i] * v[i];
    }
    s1 = warp_sum(s1); s2 = warp_sum(s2);
    __shared__ float a1[4], a2[4];
    int w = tid >> 6;
    if ((tid & 63) == 0) { a1[w] = s1; a2[w] = s2; }
    __syncthreads();
    s1 = a1[0] + a1[1] + a1[2] + a1[3];
    s2 = a2[0] + a2[1] + a2[2] + a2[3];
    float mu  = s1 * (1.0f / DD);
    float var = s2 * (1.0f / DD) - mu * mu;
    var = var < 0.f ? 0.f : var;
    float rs = rsqrtf(var + 1e-5f);
#pragma unroll
    for (int i = 0; i < 4; ++i) {
        int c = i * 256 + tid;
        lnst[base + c] = __float2bfloat16((v[i] - mu) * rs * g[c] + b[c]);
    }
}

// ========== fused gate: LN(lat2) -> logits -> top2 -> state update ============
__global__ __launch_bounds__(256) void gate_fused_kernel(
    const float* __restrict__ lat2,
    const float* __restrict__ lng, const float* __restrict__ lnb,
    const float* __restrict__ ctx,
    const float* __restrict__ state_old, float* __restrict__ stateNew,
    float* __restrict__ dout)
{
    int b = blockIdx.x;
    int tid = threadIdx.x;
    int lane = tid & 63, w = tid >> 6;
    __shared__ float logit[NS];
    __shared__ float alpha[NS];

    {
        const float* row = lat2 + (size_t)(b * NS + w) * DD;
        float4 v[4];
        float s1 = 0.f, s2 = 0.f;
#pragma unroll
        for (int j = 0; j < 4; ++j) {
            v[j] = *(const float4*)(row + (j * 64 + lane) * 4);
            s1 += v[j].x + v[j].y + v[j].z + v[j].w;
            s2 += v[j].x*v[j].x + v[j].y*v[j].y + v[j].z*v[j].z + v[j].w*v[j].w;
        }
        s1 = warp_sum(s1); s2 = warp_sum(s2);
        float mu = s1 * (1.0f / DD);
        float var = s2 * (1.0f / DD) - mu * mu;
        var = var < 0.f ? 0.f : var;
        float rs = rsqrtf(var + 1e-5f);
        float dot = 0.f;
#pragma unroll
        for (int j = 0; j < 4; ++j) {
            int c = (j * 64 + lane) * 4;
            float4 gv = *(const float4*)(lng + c);
            float4 bv = *(const float4*)(lnb + c);
            float4 cv = *(const float4*)(ctx + c);
            dot += ((v[j].x - mu) * rs * gv.x + bv.x) * cv.x
                 + ((v[j].y - mu) * rs * gv.y + bv.y) * cv.y
                 + ((v[j].z - mu) * rs * gv.z + bv.z) * cv.z
                 + ((v[j].w - mu) * rs * gv.w + bv.w) * cv.w;
        }
        dot = warp_sum(dot);
        if (lane == 0) logit[w] = dot;
    }
    __syncthreads();
    if (tid == 0) {
        float l[NS];
        for (int s = 0; s < NS; ++s) l[s] = logit[s];
        int i0 = 0;
        for (int s = 1; s < NS; ++s) if (l[s] > l[i0]) i0 = s;
        int i1 = (i0 == 0) ? 1 : 0;
        for (int s = 0; s < NS; ++s) if (s != i0 && l[s] > l[i1]) i1 = s;
        float mx = fmaxf(l[i0], l[i1]);
        float e0 = expf(l[i0] - mx), e1 = expf(l[i1] - mx);
        float inv = 1.f / (e0 + e1);
        for (int s = 0; s < NS; ++s) alpha[s] = 0.f;
        alpha[i0] = e0 * inv;
        alpha[i1] += e1 * inv;
        dout[4096 + b * 2 + 0] = (float)i0;
        dout[4096 + b * 2 + 1] = (float)i1;
    }
    __syncthreads();
    for (int idx = tid; idx < NS * DD; idx += 256) {
        int s = idx >> 10;
        float so = state_old[(size_t)b * NS * DD + idx];
        float lt = lat2[(size_t)b * NS * DD + idx];
        float ns = 0.6f * so + 0.4f * alpha[s] * tanhf(lt);
        stateNew[(size_t)b * NS * DD + idx] = ns;
        dout[4104 + b * NS * DD + idx] = ns;
    }
}

extern "C" void kernel_launch(void* const* d_in, const int* in_sizes, int n_in,
                              void* d_out, int out_size, void* d_ws, size_t ws_size,
                              hipStream_t stream)
{
    const float* x        = (const float*)d_in[0];
    const float* state0   = (const float*)d_in[1];
    const float* se_W     = (const float*)d_in[2];
    const float* se_b     = (const float*)d_in[3];
    const float* s_Wq     = (const float*)d_in[4];
    const float* s_bq     = (const float*)d_in[5];
    const float* s_Wk     = (const float*)d_in[6];
    const float* s_bk     = (const float*)d_in[7];   (void)s_bk;  // drops out of softmax
    const float* s_Wv     = (const float*)d_in[8];
    const float* s_bv     = (const float*)d_in[9];
    const float* s_Wo     = (const float*)d_in[10];
    const float* s_bo     = (const float*)d_in[11];
    const float* s_lnq_g  = (const float*)d_in[12];
    const float* s_lnq_b  = (const float*)d_in[13];
    const float* s_lnkv_g = (const float*)d_in[14];
    const float* s_lnkv_b = (const float*)d_in[15];
    const float* s_fc1_W  = (const float*)d_in[16];
    const float* s_fc1_b  = (const float*)d_in[17];
    const float* s_fc2_W  = (const float*)d_in[18];
    const float* s_fc2_b  = (const float*)d_in[19];
    const float* s_lnffn_g= (const float*)d_in[20];
    const float* s_lnffn_b= (const float*)d_in[21];
    const float* s_lnslot_g=(const float*)d_in[22];
    const float* s_lnslot_b=(const float*)d_in[23];
    const float* slot_ctx = (const float*)d_in[24];
    const float* oe_W     = (const float*)d_in[25];
    const float* oe_b     = (const float*)d_in[26];
    const float* o_Wq     = (const float*)d_in[27];
    const float* o_bq     = (const float*)d_in[28];
    const float* o_Wk     = (const float*)d_in[29];
    const float* o_bk     = (const float*)d_in[30];  (void)o_bk;  // drops out of softmax
    const float* o_Wv     = (const float*)d_in[31];
    const float* o_bv     = (const float*)d_in[32];
    const float* o_Wo     = (const float*)d_in[33];
    const float* o_bo     = (const float*)d_in[34];
    const float* o_lnq_g  = (const float*)d_in[35];
    const float* o_lnq_b  = (const float*)d_in[36];
    const float* o_lnkv_g = (const float*)d_in[37];
    const float* o_lnkv_b = (const float*)d_in[38];
    const float* o_fc1_W  = (const float*)d_in[39];
    const float* o_fc1_b  = (const float*)d_in[40];
    const float* o_fc2_W  = (const float*)d_in[41];
    const float* o_fc2_b  = (const float*)d_in[42];
    const float* o_lnffn_g= (const float*)d_in[43];
    const float* o_lnffn_b= (const float*)d_in[44];
    const float* op_W     = (const float*)d_in[45];
    const float* op_b     = (const float*)d_in[46];

    float* ws = (float*)d_ws;
    float* pe    = ws;
    float* cat   = ws + 1048576;                 // consumed by ln_fused, then reused:
    float* qtil_s= ws + 1048576;                 //   256 x 1024
    float* qtil_o= ws + 1310720;                 //   64 x 1024
    float* pctx_o= ws + 1376256;                 //   64*16*1 x 1024 = 1,048,576
    float* pms   = ws + 2424832;                 //   64*4*16 = 4096
    float* pls   = ws + 2428928;                 //   4096
    float* pmo   = ws + 2433024;                 //   64*1*16 = 1024
    float* plo   = ws + 2434048;                 //   1024
    bf16*  lnbb  = (bf16*)(ws + 5259264);        // 4112 rows bf16
    float* cat2  = ws + 7421952;                 // consumed in phase 2, then:
    float* pctx_s= ws + 7421952;                 //   64*16*4 x 1024 = 4,194,304
    bf16*  xb    = (bf16*)(ws + 11632640);       // xb early, lnbb2 late (alias)
    bf16*  lnbb2 = (bf16*)(ws + 11632640);
    bf16*  seWb  = (bf16*)(ws + 13729792);
    bf16*  oeWb  = seWb + 1048576;
    float* sm    = ws + 16875520;
    float* qh_s    = sm + 16384;
    float* attn_s  = sm + 32768;
    float* lat1    = sm + 49152;
    float* g1      = sm + 81920;
    float* lat2    = sm + 98304;
    float* q2h     = sm + 135232;
    float* attn2   = sm + 139328;
    float* lo_last = sm + 143424;
    float* lo1     = sm + 147520;
    float* g2      = sm + 155712;
    float* lo2     = sm + 159808;
    float* stateNew= sm + 231488;
    bf16*  lnst    = (bf16*)(sm + 247872);       // 16 x 1024 bf16
    float* out = (float*)d_out;

    dim3 blk(256);

    // ---- phase 0: conversions (x, seW, oeW only) + PE + state-row copy ----
    PrepArgs pa;
    pa.x = x; pa.seW = se_W; pa.oeW = oe_W;
    pa.xb = xb; pa.seWb = seWb; pa.oeWb = oeWb;
    pa.state0 = state0; pa.cat = cat; pa.pe = pe;
    prep_kernel<<<7184, blk, 0, stream>>>(pa);

    // ---- phase 1: both embeds (MFMA), XCD-swizzled ----
    embed_fused_kernel<<<512, blk, 0, stream>>>(
        xb, seWb, oeWb, se_b, oe_b, cat, cat2, pe);

    // ---- phase 2: big LNs + q projections + lo_last ----
    ln_fused_kernel<<<8208, blk, 0, stream>>>(cat, cat2, lnbb, lnbb2,
        s_lnkv_g, s_lnkv_b, o_lnkv_g, o_lnkv_b);
    small_ln_gemm_kernel<16><<<256, blk, 0, stream>>>(state0, 0, 1,
        s_lnq_g, s_lnq_b, s_Wq, s_bq, qh_s, 0);
    small_ln_gemm_kernel<4><<<256, blk, 0, stream>>>(cat2, TT - 1, LKV,
        o_lnq_g, o_lnq_b, o_Wq, o_bq, q2h, 0);
    copy_lolast_kernel<<<NB, blk, 0, stream>>>(cat2, lo_last);

    // ---- phase 3: query-side Wk projection (replaces K GEMMs) ----
    qtil_kernel<<<320, blk, 0, stream>>>(qh_s, q2h, s_Wk, o_Wk, qtil_s, qtil_o);

    // ---- phase 4: state-branch attention (16-chunk sc_ctx) + slot MLP ----
    sc_ctx_kernel<4><<<1024, blk, 0, stream>>>(qtil_s, lnbb, nullptr, LKV, 2000,
        pms, pls, pctx_s);
    combproj_kernel<4><<<256, blk, 0, stream>>>(pms, pls, pctx_s, s_Wv, s_bv, attn_s);
    small_gemm_kernel<16><<<256, blk, 0, stream>>>(attn_s, s_Wo, s_bo, lat1, state0, 0);
    small_ln_gemm_kernel<16><<<256, blk, 0, stream>>>(lat1, 0, 1,
        s_lnffn_g, s_lnffn_b, s_fc1_W, s_fc1_b, g1, 1);
    small_gemm_kernel<16><<<256, blk, 0, stream>>>(g1, s_fc2_W, s_fc2_b, lat2, lat1, 0);
    gate_fused_kernel<<<NB, blk, 0, stream>>>(lat2, s_lnslot_g, s_lnslot_b,
        slot_ctx, state0, stateNew, out);

    // ---- phase 5: out-branch attention (tokens from lnbb2 + 4 new-state rows) ----
    lnst_kernel<<<16, blk, 0, stream>>>(stateNew, lnst, o_lnkv_g, o_lnkv_b);
    sc_ctx_kernel<1><<<1024, blk, 0, stream>>>(qtil_o, lnbb2, lnst, TT, TT,
        pmo, plo, pctx_o);
    combproj_kernel<1><<<64, blk, 0, stream>>>(pmo, plo, pctx_o, o_Wv, o_bv, attn2);
    small_gemm_kernel<4><<<256, blk, 0, stream>>>(attn2, o_Wo, o_bo, lo1, lo_last, 0);
    small_ln_gemm_kernel<4><<<256, blk, 0, stream>>>(lo1, 0, 1,
        o_lnffn_g, o_lnffn_b, o_fc1_W, o_fc1_b, g2, 1);
    small_gemm_kernel<4><<<256, blk, 0, stream>>>(g2, o_fc2_W, o_fc2_b, lo2, lo1, 0);
    small_gemm_kernel<4><<<256, blk, 0, stream>>>(lo2, op_W, op_b, out, nullptr, 0);
}

// Round 17
// 206.904 us; speedup vs baseline: 1.6053x; 1.0373x over previous
//
#include <hip/hip_runtime.h>
#include <hip/hip_bf16.h>

#define DD 1024
#define NB 4
#define TT 1024
#define NH 16
#define NS 4
#define LKV 1028   // NS + TT

typedef __hip_bfloat16 bf16;
typedef __attribute__((ext_vector_type(8))) short short8;
typedef __attribute__((ext_vector_type(4))) float f32x4;

#define GLD16(gp, lp) __builtin_amdgcn_global_load_lds( \
    (const __attribute__((address_space(1))) unsigned int*)(const void*)(gp), \
    (__attribute__((address_space(3))) unsigned int*)(void*)(lp), 16, 0, 0)

__device__ __forceinline__ float warp_sum(float v) {
#pragma unroll
    for (int o = 32; o > 0; o >>= 1) v += __shfl_xor(v, o);
    return v;
}

__device__ __forceinline__ float b2f(unsigned short u) {
    union { unsigned int i; float f; } x; x.i = ((unsigned)u) << 16; return x.f;
}

// ================= prep: cvt x + 2 embed weights, PE table, state copy ========
struct PrepArgs {
    const float* x;
    const float* seW;
    const float* oeW;
    bf16 *xb, *seWb, *oeWb;
    const float* state0;
    float* cat;
    float* pe;
};

__global__ __launch_bounds__(256) void prep_kernel(PrepArgs a) {
    int bid = blockIdx.x;
    int tid = threadIdx.x;
    if (bid < 6144) {
        const float* in; bf16* out; size_t off;
        if (bid < 4096)      { in = a.x;   out = a.xb;   off = (size_t)bid * 1024; }
        else if (bid < 5120) { in = a.seW; out = a.seWb; off = (size_t)(bid - 4096) * 1024; }
        else                 { in = a.oeW; out = a.oeWb; off = (size_t)(bid - 5120) * 1024; }
        size_t i = off + tid * 4;
        float4 v = *(const float4*)(in + i);
        out[i + 0] = __float2bfloat16(v.x);
        out[i + 1] = __float2bfloat16(v.y);
        out[i + 2] = __float2bfloat16(v.z);
        out[i + 3] = __float2bfloat16(v.w);
    } else if (bid < 7168) {
        int t = bid - 6144;
#pragma unroll
        for (int i = 0; i < 2; ++i) {
            int j = i * 256 + tid;                       // 0..511
            float ang = (float)t * exp2f(-(float)j * (1.0f / 256.0f));
            a.pe[(size_t)t * DD + j]       = sinf(ang);
            a.pe[(size_t)t * DD + 512 + j] = cosf(ang);
        }
    } else {
        int r = bid - 7168;        // 0..15
        int b = r >> 2, s = r & 3;
#pragma unroll
        for (int i = 0; i < 4; ++i)
            a.cat[(size_t)(b * LKV + s) * DD + i * 256 + tid] =
                a.state0[(size_t)r * DD + i * 256 + tid];
    }
}

// ================= fused LayerNorm -> bf16 (state-kv rows + out token rows) ===
__global__ __launch_bounds__(256) void ln_fused_kernel(
    const float* __restrict__ cat, const float* __restrict__ cat2,
    bf16* __restrict__ lnbb, bf16* __restrict__ lnbb2,
    const float* __restrict__ sg, const float* __restrict__ sb,
    const float* __restrict__ og, const float* __restrict__ ob)
{
    int bid = blockIdx.x;
    int tid = threadIdx.x;
    const float* in; bf16* out; const float* g; const float* b;
    if (bid < 4112) {
        in = cat + (size_t)bid * DD; out = lnbb + (size_t)bid * DD; g = sg; b = sb;
    } else {
        int r = bid - 4112;
        int row = (r >> 10) * LKV + (r & 1023);
        in = cat2 + (size_t)row * DD; out = lnbb2 + (size_t)r * DD; g = og; b = ob;
    }
    float v[4];
    float s1 = 0.f, s2 = 0.f;
#pragma unroll
    for (int i = 0; i < 4; ++i) {
        v[i] = in[i * 256 + tid];
        s1 += v[i]; s2 += v[i] * v[i];
    }
    s1 = warp_sum(s1); s2 = warp_sum(s2);
    __shared__ float a1[4], a2[4];
    int w = tid >> 6;
    if ((tid & 63) == 0) { a1[w] = s1; a2[w] = s2; }
    __syncthreads();
    s1 = a1[0] + a1[1] + a1[2] + a1[3];
    s2 = a2[0] + a2[1] + a2[2] + a2[3];
    float mu  = s1 * (1.0f / DD);
    float var = s2 * (1.0f / DD) - mu * mu;
    var = var < 0.f ? 0.f : var;
    float rs = rsqrtf(var + 1e-5f);
#pragma unroll
    for (int i = 0; i < 4; ++i) {
        int c = i * 256 + tid;
        out[c] = __float2bfloat16((v[i] - mu) * rs * g[c] + b[c]);
    }
}

// ================= MFMA tile body (128x128, BK=32, 4 waves) ===================
__device__ __forceinline__ void mfma_tile(
    const bf16* __restrict__ A, const bf16* __restrict__ W,
    const float* __restrict__ bias,
    float* __restrict__ outf,
    int obs, int oro, const float* __restrict__ pe,
    bf16* As, bf16* Ws, int m0, int n0)
{
    int tid  = threadIdx.x;
    int lane = tid & 63;
    int wave = tid >> 6;
    int wm = (wave >> 1) << 6;
    int wn = (wave & 1) << 6;

    f32x4 acc[4][4] = {};

    int soff  = wave * 1024 + lane * 16;
    int srow  = soff >> 6;
    int scol  = (soff & 63) >> 1;
    char* lA0 = (char*)As + wave * 1024;
    char* lA1 = (char*)As + 4096 + wave * 1024;
    char* lW0 = (char*)Ws + wave * 1024;
    char* lW1 = (char*)Ws + 4096 + wave * 1024;

    int fRow = lane & 15;
    int kOff = (lane >> 4) << 3;

    for (int k0 = 0; k0 < DD; k0 += 32) {
        GLD16(A + (size_t)(m0 + srow) * DD + k0 + scol,      lA0);
        GLD16(A + (size_t)(m0 + 64 + srow) * DD + k0 + scol, lA1);
        GLD16(W + (size_t)(n0 + srow) * DD + k0 + scol,      lW0);
        GLD16(W + (size_t)(n0 + 64 + srow) * DD + k0 + scol, lW1);
        __syncthreads();
        short8 a[4], b[4];
#pragma unroll
        for (int mi = 0; mi < 4; ++mi)
            a[mi] = *(const short8*)(As + (wm + mi * 16 + fRow) * 32 + kOff);
#pragma unroll
        for (int ni = 0; ni < 4; ++ni)
            b[ni] = *(const short8*)(Ws + (wn + ni * 16 + fRow) * 32 + kOff);
#pragma unroll
        for (int mi = 0; mi < 4; ++mi)
#pragma unroll
            for (int ni = 0; ni < 4; ++ni)
                acc[mi][ni] = __builtin_amdgcn_mfma_f32_16x16x32_bf16(
                    a[mi], b[ni], acc[mi][ni], 0, 0, 0);
        __syncthreads();
    }

    int cCol  = lane & 15;
    int cRow4 = (lane >> 4) << 2;
#pragma unroll
    for (int mi = 0; mi < 4; ++mi) {
#pragma unroll
        for (int ni = 0; ni < 4; ++ni) {
#pragma unroll
            for (int r = 0; r < 4; ++r) {
                int row = m0 + wm + mi * 16 + cRow4 + r;
                int col = n0 + wn + ni * 16 + cCol;
                float v = acc[mi][ni][r] + bias[col] + pe[(size_t)(row & 1023) * DD + col];
                int orow = (row >> 10) * obs + oro + (row & 1023);
                outf[(size_t)orow * DD + col] = v;
            }
        }
    }
}

// ================= fused embeds, XCD-swizzled linear grid (512 blocks) ========
__global__ __launch_bounds__(256) void embed_fused_kernel(
    const bf16* __restrict__ xb,
    const bf16* __restrict__ seW, const bf16* __restrict__ oeW,
    const float* __restrict__ seb, const float* __restrict__ oeb,
    float* __restrict__ cat, float* __restrict__ cat2,
    const float* __restrict__ pe)
{
    __shared__ bf16 As[128 * 32];
    __shared__ bf16 Ws[128 * 32];
    int bid = blockIdx.x;
    int t = (bid & 7) * 64 + (bid >> 3);   // bijective XCD swizzle (512 = 8*64)
    int x = t & 7;
    int q = t >> 3;
    int z = q & 1;
    int y = q >> 1;
    const bf16* W = z ? oeW : seW;
    const float* bias = z ? oeb : seb;
    float* outf = z ? cat2 : cat;
    int oro = z ? 0 : NS;
    mfma_tile(xb, W, bias, outf, LKV, oro, pe, As, Ws, y * 128, x * 128);
}

// ================= copy lo[:, -1] =============================================
__global__ __launch_bounds__(256) void copy_lolast_kernel(
    const float* __restrict__ cat2, float* __restrict__ dst)
{
    int b = blockIdx.x;
    int tid = threadIdx.x;
#pragma unroll
    for (int i = 0; i < 4; ++i)
        dst[(size_t)b * DD + i * 256 + tid] =
            cat2[(size_t)(b * LKV + (TT - 1)) * DD + i * 256 + tid];
}

// ================= small GEMM (M<=16), f32 LDS staging =========================
template<int M>
__global__ __launch_bounds__(256) void small_gemm_kernel(
    const float* __restrict__ A, const float* __restrict__ W,
    const float* __restrict__ bias, float* __restrict__ out,
    const float* __restrict__ res, int gelu)
{
    __shared__ float As[M * DD];
    int tid = threadIdx.x;
#pragma unroll
    for (int i = 0; i < M; ++i) {
        int idx = (i * 256 + tid) * 4;
        *(float4*)(As + idx) = *(const float4*)(A + idx);
    }
    __syncthreads();
    int lane = tid & 63;
    int w = tid >> 6;
    int n = blockIdx.x * 4 + w;
    const float* Wr = W + (size_t)n * DD;
    float acc[M] = {};
#pragma unroll
    for (int j = 0; j < 4; ++j) {
        float4 wv = *(const float4*)(Wr + j * 256 + lane * 4);
#pragma unroll
        for (int m = 0; m < M; ++m) {
            float4 av = *(const float4*)(As + m * DD + j * 256 + lane * 4);
            acc[m] += av.x * wv.x + av.y * wv.y + av.z * wv.z + av.w * wv.w;
        }
    }
#pragma unroll
    for (int m = 0; m < M; ++m) acc[m] = warp_sum(acc[m]);
    if (lane == 0) {
#pragma unroll
        for (int m = 0; m < M; ++m) {
            float v = acc[m] + bias[n];
            if (gelu) v = 0.5f * v * (1.0f + erff(v * 0.70710678118654752f));
            if (res)  v += res[(size_t)m * DD + n];
            out[(size_t)m * DD + n] = v;
        }
    }
}

// ============ small GEMM with fused input LayerNorm ===========================
template<int M>
__global__ __launch_bounds__(256) void small_ln_gemm_kernel(
    const float* __restrict__ A, int row0, int rstride,
    const float* __restrict__ lng, const float* __restrict__ lnb,
    const float* __restrict__ W, const float* __restrict__ bias,
    float* __restrict__ outf, int gelu)
{
    __shared__ float As[M * DD];
    __shared__ float smu[M], srs[M];
    int tid = threadIdx.x;
    int lane = tid & 63;
    int w = tid >> 6;
#pragma unroll
    for (int i = 0; i < M; ++i) {
        int row = row0 + i * rstride;
        *(float4*)(As + i * DD + tid * 4) =
            *(const float4*)(A + (size_t)row * DD + tid * 4);
    }
    __syncthreads();
    constexpr int RPW = (M + 3) / 4;
#pragma unroll
    for (int i = 0; i < RPW; ++i) {
        int r = w * RPW + i;
        if (r < M) {
            float s1 = 0.f, s2 = 0.f;
#pragma unroll
            for (int j = 0; j < 4; ++j) {
                float4 v = *(const float4*)(As + r * DD + (j * 64 + lane) * 4);
                s1 += v.x + v.y + v.z + v.w;
                s2 += v.x*v.x + v.y*v.y + v.z*v.z + v.w*v.w;
            }
            s1 = warp_sum(s1); s2 = warp_sum(s2);
            if (lane == 0) {
                float mu = s1 * (1.0f / DD);
                float var = s2 * (1.0f / DD) - mu * mu;
                var = var < 0.f ? 0.f : var;
                smu[r] = mu; srs[r] = rsqrtf(var + 1e-5f);
            }
        }
    }
    __syncthreads();
    float4 gv = *(const float4*)(lng + tid * 4);
    float4 bv = *(const float4*)(lnb + tid * 4);
#pragma unroll
    for (int i = 0; i < M; ++i) {
        float mu = smu[i], rs = srs[i];
        float4 v = *(const float4*)(As + i * DD + tid * 4);
        v.x = (v.x - mu) * rs * gv.x + bv.x;
        v.y = (v.y - mu) * rs * gv.y + bv.y;
        v.z = (v.z - mu) * rs * gv.z + bv.z;
        v.w = (v.w - mu) * rs * gv.w + bv.w;
        *(float4*)(As + i * DD + tid * 4) = v;
    }
    __syncthreads();
    int n = blockIdx.x * 4 + w;
    const float* Wr = W + (size_t)n * DD;
    float acc[M] = {};
#pragma unroll
    for (int j = 0; j < 4; ++j) {
        float4 wv = *(const float4*)(Wr + j * 256 + lane * 4);
#pragma unroll
        for (int m = 0; m < M; ++m) {
            float4 av = *(const float4*)(As + m * DD + j * 256 + lane * 4);
            acc[m] += av.x * wv.x + av.y * wv.y + av.z * wv.z + av.w * wv.w;
        }
    }
#pragma unroll
    for (int m = 0; m < M; ++m) acc[m] = warp_sum(acc[m]);
    if (lane == 0) {
#pragma unroll
        for (int m = 0; m < M; ++m) {
            float v = acc[m] + bias[n];
            if (gelu) v = 0.5f * v * (1.0f + erff(v * 0.70710678118654752f));
            outf[(size_t)m * DD + n] = v;
        }
    }
}

// ============ qtil: project queries through Wk (low-rank attention trick) =====
__global__ __launch_bounds__(256) void qtil_kernel(
    const float* __restrict__ qh_s, const float* __restrict__ q2h,
    const float* __restrict__ sWk, const float* __restrict__ oWk,
    float* __restrict__ qtil_s, float* __restrict__ qtil_o)
{
    int blk = blockIdx.x;
    int tid = threadIdx.x;
    const float* src; const float* W; float* dst; int h;
    if (blk < 256) {
        int bq = blk >> 4;          // b*4+q
        h = blk & 15;
        src = qh_s + (size_t)bq * DD;
        W = sWk; dst = qtil_s + (size_t)blk * DD;
    } else {
        int o = blk - 256;
        int b = o >> 4;
        h = o & 15;
        src = q2h + (size_t)b * DD;
        W = oWk; dst = qtil_o + (size_t)o * DD;
    }
    __shared__ float qv[64];
    if (tid < 64) qv[tid] = src[h * 64 + tid];
    __syncthreads();
    int i = tid * 4;
    float4 acc = {0.f, 0.f, 0.f, 0.f};
#pragma unroll 4
    for (int o = 0; o < 64; ++o) {
        float4 wr = *(const float4*)(W + (size_t)(h * 64 + o) * DD + i);
        float s = qv[o];
        acc.x += s * wr.x; acc.y += s * wr.y; acc.z += s * wr.z; acc.w += s * wr.w;
    }
    acc.x *= 0.125f; acc.y *= 0.125f; acc.z *= 0.125f; acc.w *= 0.125f;
    *(float4*)(dst + i) = acc;
}

// ============ sc_ctx body: scores + softmax-partial + ctx for one chunk =======
// Register/shuffle pass 1; nchs = chunk-slot stride in pm/pl/pctx.
template<int LQ, int CHSv>
__device__ void sc_ctx_body(int c, int bh,
    const float* __restrict__ qtil, const bf16* __restrict__ keys,
    int keyStride, int nkey, int nchs,
    float* __restrict__ pm, float* __restrict__ pl, float* __restrict__ pctx,
    float* sc, float* redm, float* redl)
{
    int b = bh >> 4, h = bh & 15;
    int tid = threadIdx.x;
    int lane = tid & 63, w = tid >> 6;

    float qreg[LQ][16];
#pragma unroll
    for (int q = 0; q < LQ; ++q) {
        const float* qrow = qtil + (size_t)((b * LQ + q) * 16 + h) * DD + lane * 16;
#pragma unroll
        for (int j = 0; j < 4; ++j) {
            float4 v = *(const float4*)(qrow + j * 4);
            qreg[q][j*4+0] = v.x; qreg[q][j*4+1] = v.y;
            qreg[q][j*4+2] = v.z; qreg[q][j*4+3] = v.w;
        }
    }

    int kbeg = c * CHSv;
    int kcnt = nkey - kbeg; if (kcnt > CHSv) kcnt = CHSv;

    // pass 1: wave-per-key, coalesced 32B/lane key reads, shfl reduce
    for (int t = w; t < kcnt; t += 4) {
        const unsigned short* row = (const unsigned short*)keys
            + (size_t)(b * keyStride + kbeg + t) * DD + lane * 16;
        float kf[16];
#pragma unroll
        for (int j = 0; j < 4; ++j) {
            ushort4 v = *(const ushort4*)(row + j * 4);
            kf[j*4+0] = b2f(v.x); kf[j*4+1] = b2f(v.y);
            kf[j*4+2] = b2f(v.z); kf[j*4+3] = b2f(v.w);
        }
        float acc[LQ];
#pragma unroll
        for (int q = 0; q < LQ; ++q) acc[q] = 0.f;
#pragma unroll
        for (int j = 0; j < 16; ++j)
#pragma unroll
            for (int q = 0; q < LQ; ++q)
                acc[q] += kf[j] * qreg[q][j];
#pragma unroll
        for (int q = 0; q < LQ; ++q) acc[q] = warp_sum(acc[q]);
        if (lane == 0) {
#pragma unroll
            for (int q = 0; q < LQ; ++q) sc[q * CHSv + t] = acc[q];
        }
    }
    __syncthreads();

    float M[LQ], L[LQ];
#pragma unroll
    for (int q = 0; q < LQ; ++q) {
        float lm = -1e30f;
        for (int t = tid; t < kcnt; t += 256) lm = fmaxf(lm, sc[q * CHSv + t]);
#pragma unroll
        for (int o = 32; o > 0; o >>= 1) lm = fmaxf(lm, __shfl_xor(lm, o));
        if (lane == 0) redm[w * LQ + q] = lm;
    }
    __syncthreads();
#pragma unroll
    for (int q = 0; q < LQ; ++q)
        M[q] = fmaxf(fmaxf(redm[q], redm[LQ + q]),
                     fmaxf(redm[2 * LQ + q], redm[3 * LQ + q]));
#pragma unroll
    for (int q = 0; q < LQ; ++q) {
        float ls = 0.f;
        for (int t = tid; t < kcnt; t += 256) {
            float e = expf(sc[q * CHSv + t] - M[q]);
            sc[q * CHSv + t] = e;
            ls += e;
        }
        ls = warp_sum(ls);
        if (lane == 0) redl[w * LQ + q] = ls;
    }
    __syncthreads();
#pragma unroll
    for (int q = 0; q < LQ; ++q)
        L[q] = redl[q] + redl[LQ + q] + redl[2 * LQ + q] + redl[3 * LQ + q];

    // pass 2: thread-per-dim ctx accumulation (coalesced key reads)
    int i4 = tid * 4;
    float cx[LQ][4];
#pragma unroll
    for (int q = 0; q < LQ; ++q) { cx[q][0]=0; cx[q][1]=0; cx[q][2]=0; cx[q][3]=0; }
    for (int t = 0; t < kcnt; ++t) {
        const unsigned short* row = (const unsigned short*)keys
            + (size_t)(b * keyStride + kbeg + t) * DD;
        ushort4 v = *(const ushort4*)(row + i4);
        float f0 = b2f(v.x), f1 = b2f(v.y), f2 = b2f(v.z), f3 = b2f(v.w);
#pragma unroll
        for (int q = 0; q < LQ; ++q) {
            float p = sc[q * CHSv + t];
            cx[q][0] += p * f0; cx[q][1] += p * f1;
            cx[q][2] += p * f2; cx[q][3] += p * f3;
        }
    }
#pragma unroll
    for (int q = 0; q < LQ; ++q) {
        float4 o4 = {cx[q][0], cx[q][1], cx[q][2], cx[q][3]};
        *(float4*)(pctx + (size_t)((bh * nchs + c) * LQ + q) * DD + i4) = o4;
    }
    if (tid < LQ) {
        pm[(bh * LQ + tid) * nchs + c] = M[tid];
        pl[(bh * LQ + tid) * nchs + c] = L[tid];
    }
}

// ======= merged sc_ctx: blocks 0-1023 state branch; 1024-2047 out tokens ======
__global__ __launch_bounds__(256) void sc_ctx_main_kernel(
    const float* __restrict__ qtil_s, const float* __restrict__ qtil_o,
    const bf16* __restrict__ lnbb, const bf16* __restrict__ lnbb2,
    float* __restrict__ pms, float* __restrict__ pls, float* __restrict__ pctx_s,
    float* __restrict__ pmo, float* __restrict__ plo, float* __restrict__ pctx_o)
{
    __shared__ float sc[4 * 65];
    __shared__ float redm[16], redl[16];
    int bid = blockIdx.x;
    if (bid < 1024) {
        int c = bid & 15, bh = bid >> 4;
        sc_ctx_body<4, 65>(c, bh, qtil_s, lnbb, LKV, 1028, 16,
                           pms, pls, pctx_s, sc, redm, redl);
    } else {
        bid -= 1024;
        int c = bid & 15, bh = bid >> 4;
        sc_ctx_body<1, 64>(c, bh, qtil_o, lnbb2, TT, 1024, 17,
                           pmo, plo, pctx_o, sc, redm, redl);
    }
}

// ======= gate-dependent tail: 4 new-state keys as chunk 16 of out branch ======
__global__ __launch_bounds__(256) void sc_tail_kernel(
    const float* __restrict__ qtil_o, const bf16* __restrict__ lnst,
    float* __restrict__ pmo, float* __restrict__ plo, float* __restrict__ pctx_o)
{
    __shared__ float sc4[4];
    int bh = blockIdx.x;
    int b = bh >> 4, h = bh & 15;
    int tid = threadIdx.x;
    int lane = tid & 63, w = tid >> 6;

    {
        const unsigned short* row = (const unsigned short*)lnst
            + (size_t)(b * 4 + w) * DD + lane * 16;
        const float* qrow = qtil_o + (size_t)bh * DD + lane * 16;
        float s = 0.f;
#pragma unroll
        for (int j = 0; j < 4; ++j) {
            ushort4 v = *(const ushort4*)(row + j * 4);
            float4 qv = *(const float4*)(qrow + j * 4);
            s += b2f(v.x)*qv.x + b2f(v.y)*qv.y + b2f(v.z)*qv.z + b2f(v.w)*qv.w;
        }
        s = warp_sum(s);
        if (lane == 0) sc4[w] = s;
    }
    __syncthreads();
    float m = fmaxf(fmaxf(sc4[0], sc4[1]), fmaxf(sc4[2], sc4[3]));
    float e0 = expf(sc4[0] - m), e1 = expf(sc4[1] - m);
    float e2 = expf(sc4[2] - m), e3 = expf(sc4[3] - m);
    float l = e0 + e1 + e2 + e3;
    int i4 = tid * 4;
    const unsigned short* k0 = (const unsigned short*)lnst + (size_t)(b*4+0)*DD + i4;
    const unsigned short* k1 = (const unsigned short*)lnst + (size_t)(b*4+1)*DD + i4;
    const unsigned short* k2 = (const unsigned short*)lnst + (size_t)(b*4+2)*DD + i4;
    const unsigned short* k3 = (const unsigned short*)lnst + (size_t)(b*4+3)*DD + i4;
    ushort4 v0 = *(const ushort4*)k0, v1 = *(const ushort4*)k1;
    ushort4 v2 = *(const ushort4*)k2, v3 = *(const ushort4*)k3;
    float4 o4;
    o4.x = e0*b2f(v0.x) + e1*b2f(v1.x) + e2*b2f(v2.x) + e3*b2f(v3.x);
    o4.y = e0*b2f(v0.y) + e1*b2f(v1.y) + e2*b2f(v2.y) + e3*b2f(v3.y);
    o4.z = e0*b2f(v0.z) + e1*b2f(v1.z) + e2*b2f(v2.z) + e3*b2f(v3.z);
    o4.w = e0*b2f(v0.w) + e1*b2f(v1.w) + e2*b2f(v2.w) + e3*b2f(v3.w);
    *(float4*)(pctx_o + (size_t)(bh * 17 + 16) * DD + i4) = o4;
    if (tid == 0) {
        pmo[bh * 17 + 16] = m;
        plo[bh * 17 + 16] = l;
    }
}

// ============ combproj: combine NCHT chunk ctx + project through Wv + bv ======
template<int LQ, int NCHT>
__global__ __launch_bounds__(256) void combproj_kernel(
    const float* __restrict__ pm, const float* __restrict__ pl,
    const float* __restrict__ pctx,
    const float* __restrict__ Wv, const float* __restrict__ bv,
    float* __restrict__ attn)
{
    __shared__ float ctxf[DD];
    int blk = blockIdx.x;
    int h = blk & 15;
    int bq = blk >> 4;               // b*LQ+q
    int b = bq / LQ, q = bq - b * LQ;
    int bh = b * 16 + h;
    int tid = threadIdx.x;
    int lane = tid & 63, w = tid >> 6;

    int base = (bh * LQ + q) * NCHT;
    float Mx = -1e30f;
#pragma unroll
    for (int c = 0; c < NCHT; ++c) Mx = fmaxf(Mx, pm[base + c]);
    float wc[NCHT];
    float L = 0.f;
#pragma unroll
    for (int c = 0; c < NCHT; ++c) {
        wc[c] = expf(pm[base + c] - Mx);
        L += pl[base + c] * wc[c];
    }
    float inv = 1.f / L;
    int i4 = tid * 4;
    float4 s4 = {0.f, 0.f, 0.f, 0.f};
#pragma unroll
    for (int c = 0; c < NCHT; ++c) {
        float4 a = *(const float4*)(pctx + (size_t)((bh * NCHT + c) * LQ + q) * DD + i4);
        s4.x += a.x * wc[c]; s4.y += a.y * wc[c];
        s4.z += a.z * wc[c]; s4.w += a.w * wc[c];
    }
    ctxf[i4+0] = s4.x * inv;
    ctxf[i4+1] = s4.y * inv;
    ctxf[i4+2] = s4.z * inv;
    ctxf[i4+3] = s4.w * inv;
    __syncthreads();

#pragma unroll 1
    for (int rr = 0; rr < 16; ++rr) {
        int o = h * 64 + w * 16 + rr;
        const float* Wr = Wv + (size_t)o * DD + lane * 16;
        const float* cf = ctxf + lane * 16;
        float s = 0.f;
#pragma unroll
        for (int j = 0; j < 4; ++j) {
            float4 wv4 = *(const float4*)(Wr + j * 4);
            s += wv4.x * cf[j*4+0] + wv4.y * cf[j*4+1]
               + wv4.z * cf[j*4+2] + wv4.w * cf[j*4+3];
        }
        s = warp_sum(s);
        if (lane == 0)
            attn[(size_t)bq * DD + o] = s + bv[o];
    }
}

// ================= LN of stateNew rows -> bf16 (out-branch keys) ==============
__global__ __launch_bounds__(256) void lnst_kernel(
    const float* __restrict__ stateNew, bf16* __restrict__ lnst,
    const float* __restrict__ g, const float* __restrict__ b)
{
    int r = blockIdx.x;
    int tid = threadIdx.x;
    size_t base = (size_t)r * DD;
    float v[4];
    float s1 = 0.f, s2 = 0.f;
#pragma unroll
    for (int i = 0; i < 4; ++i) {
        v[i] = stateNew[base + i * 256 + tid];
        s1 += v[i]; s2 += v[i] * v[i];
    }
    s1 = warp_sum(s1); s2 = warp_sum(s2);
    __shared__ float a1[4], a2[4];
    int w = tid >> 6;
    if ((tid & 63) == 0) { a1[w] = s1; a2[w] = s2; }
    __syncthreads();
    s1 = a1[0] + a1[1] + a1[2] + a1[3];
    s2 = a2[0] + a2[1] + a2[2] + a2[3];
    float mu  = s1 * (1.0f / DD);
    float var = s2 * (1.0f / DD) - mu * mu;
    var = var < 0.f ? 0.f : var;
    float rs = rsqrtf(var + 1e-5f);
#pragma unroll
    for (int i = 0; i < 4; ++i) {
        int c = i * 256 + tid;
        lnst[base + c] = __float2bfloat16((v[i] - mu) * rs * g[c] + b[c]);
    }
}

// ========== fused gate: LN(lat2) -> logits -> top2 -> state update ============
__global__ __launch_bounds__(256) void gate_fused_kernel(
    const float* __restrict__ lat2,
    const float* __restrict__ lng, const float* __restrict__ lnb,
    const float* __restrict__ ctx,
    const float* __restrict__ state_old, float* __restrict__ stateNew,
    float* __restrict__ dout)
{
    int b = blockIdx.x;
    int tid = threadIdx.x;
    int lane = tid & 63, w = tid >> 6;
    __shared__ float logit[NS];
    __shared__ float alpha[NS];

    {
        const float* row = lat2 + (size_t)(b * NS + w) * DD;
        float4 v[4];
        float s1 = 0.f, s2 = 0.f;
#pragma unroll
        for (int j = 0; j < 4; ++j) {
            v[j] = *(const float4*)(row + (j * 64 + lane) * 4);
            s1 += v[j].x + v[j].y + v[j].z + v[j].w;
            s2 += v[j].x*v[j].x + v[j].y*v[j].y + v[j].z*v[j].z + v[j].w*v[j].w;
        }
        s1 = warp_sum(s1); s2 = warp_sum(s2);
        float mu = s1 * (1.0f / DD);
        float var = s2 * (1.0f / DD) - mu * mu;
        var = var < 0.f ? 0.f : var;
        float rs = rsqrtf(var + 1e-5f);
        float dot = 0.f;
#pragma unroll
        for (int j = 0; j < 4; ++j) {
            int c = (j * 64 + lane) * 4;
            float4 gv = *(const float4*)(lng + c);
            float4 bv = *(const float4*)(lnb + c);
            float4 cv = *(const float4*)(ctx + c);
            dot += ((v[j].x - mu) * rs * gv.x + bv.x) * cv.x
                 + ((v[j].y - mu) * rs * gv.y + bv.y) * cv.y
                 + ((v[j].z - mu) * rs * gv.z + bv.z) * cv.z
                 + ((v[j].w - mu) * rs * gv.w + bv.w) * cv.w;
        }
        dot = warp_sum(dot);
        if (lane == 0) logit[w] = dot;
    }
    __syncthreads();
    if (tid == 0) {
        float l[NS];
        for (int s = 0; s < NS; ++s) l[s] = logit[s];
        int i0 = 0;
        for (int s = 1; s < NS; ++s) if (l[s] > l[i0]) i0 = s;
        int i1 = (i0 == 0) ? 1 : 0;
        for (int s = 0; s < NS; ++s) if (s != i0 && l[s] > l[i1]) i1 = s;
        float mx = fmaxf(l[i0], l[i1]);
        float e0 = expf(l[i0] - mx), e1 = expf(l[i1] - mx);
        float inv = 1.f / (e0 + e1);
        for (int s = 0; s < NS; ++s) alpha[s] = 0.f;
        alpha[i0] = e0 * inv;
        alpha[i1] += e1 * inv;
        dout[4096 + b * 2 + 0] = (float)i0;
        dout[4096 + b * 2 + 1] = (float)i1;
    }
    __syncthreads();
    for (int idx = tid; idx < NS * DD; idx += 256) {
        int s = idx >> 10;
        float so = state_old[(size_t)b * NS * DD + idx];
        float lt = lat2[(size_t)b * NS * DD + idx];
        float ns = 0.6f * so + 0.4f * alpha[s] * tanhf(lt);
        stateNew[(size_t)b * NS * DD + idx] = ns;
        dout[4104 + b * NS * DD + idx] = ns;
    }
}

extern "C" void kernel_launch(void* const* d_in, const int* in_sizes, int n_in,
                              void* d_out, int out_size, void* d_ws, size_t ws_size,
                              hipStream_t stream)
{
    const float* x        = (const float*)d_in[0];
    const float* state0   = (const float*)d_in[1];
    const float* se_W     = (const float*)d_in[2];
    const float* se_b     = (const float*)d_in[3];
    const float* s_Wq     = (const float*)d_in[4];
    const float* s_bq     = (const float*)d_in[5];
    const float* s_Wk     = (const float*)d_in[6];
    const float* s_bk     = (const float*)d_in[7];   (void)s_bk;  // drops out of softmax
    const float* s_Wv     = (const float*)d_in[8];
    const float* s_bv     = (const float*)d_in[9];
    const float* s_Wo     = (const float*)d_in[10];
    const float* s_bo     = (const float*)d_in[11];
    const float* s_lnq_g  = (const float*)d_in[12];
    const float* s_lnq_b  = (const float*)d_in[13];
    const float* s_lnkv_g = (const float*)d_in[14];
    const float* s_lnkv_b = (const float*)d_in[15];
    const float* s_fc1_W  = (const float*)d_in[16];
    const float* s_fc1_b  = (const float*)d_in[17];
    const float* s_fc2_W  = (const float*)d_in[18];
    const float* s_fc2_b  = (const float*)d_in[19];
    const float* s_lnffn_g= (const float*)d_in[20];
    const float* s_lnffn_b= (const float*)d_in[21];
    const float* s_lnslot_g=(const float*)d_in[22];
    const float* s_lnslot_b=(const float*)d_in[23];
    const float* slot_ctx = (const float*)d_in[24];
    const float* oe_W     = (const float*)d_in[25];
    const float* oe_b     = (const float*)d_in[26];
    const float* o_Wq     = (const float*)d_in[27];
    const float* o_bq     = (const float*)d_in[28];
    const float* o_Wk     = (const float*)d_in[29];
    const float* o_bk     = (const float*)d_in[30];  (void)o_bk;  // drops out of softmax
    const float* o_Wv     = (const float*)d_in[31];
    const float* o_bv     = (const float*)d_in[32];
    const float* o_Wo     = (const float*)d_in[33];
    const float* o_bo     = (const float*)d_in[34];
    const float* o_lnq_g  = (const float*)d_in[35];
    const float* o_lnq_b  = (const float*)d_in[36];
    const float* o_lnkv_g = (const float*)d_in[37];
    const float* o_lnkv_b = (const float*)d_in[38];
    const float* o_fc1_W  = (const float*)d_in[39];
    const float* o_fc1_b  = (const float*)d_in[40];
    const float* o_fc2_W  = (const float*)d_in[41];
    const float* o_fc2_b  = (const float*)d_in[42];
    const float* o_lnffn_g= (const float*)d_in[43];
    const float* o_lnffn_b= (const float*)d_in[44];
    const float* op_W     = (const float*)d_in[45];
    const float* op_b     = (const float*)d_in[46];

    float* ws = (float*)d_ws;
    float* pe    = ws;
    float* cat   = ws + 1048576;                 // consumed by ln_fused, then reused:
    float* qtil_s= ws + 1048576;                 //   256 x 1024
    float* qtil_o= ws + 1310720;                 //   64 x 1024
    float* pctx_o= ws + 1376256;                 //   64*17 x 1024 = 1,114,112
    float* pms   = ws + 2490368;                 //   64*4*16 = 4096
    float* pls   = ws + 2494464;                 //   4096
    float* pmo   = ws + 2498560;                 //   64*17 = 1088 (pad 2048)
    float* plo   = ws + 2500608;                 //   1088
    bf16*  lnbb  = (bf16*)(ws + 5259264);        // 4112 rows bf16
    float* cat2  = ws + 7421952;                 // consumed in phase 2, then:
    float* pctx_s= ws + 7421952;                 //   64*16*4 x 1024 = 4,194,304
    bf16*  xb    = (bf16*)(ws + 11632640);       // xb early, lnbb2 late (alias)
    bf16*  lnbb2 = (bf16*)(ws + 11632640);
    bf16*  seWb  = (bf16*)(ws + 13729792);
    bf16*  oeWb  = seWb + 1048576;
    float* sm    = ws + 16875520;
    float* qh_s    = sm + 16384;
    float* attn_s  = sm + 32768;
    float* lat1    = sm + 49152;
    float* g1      = sm + 81920;
    float* lat2    = sm + 98304;
    float* q2h     = sm + 135232;
    float* attn2   = sm + 139328;
    float* lo_last = sm + 143424;
    float* lo1     = sm + 147520;
    float* g2      = sm + 155712;
    float* lo2     = sm + 159808;
    float* stateNew= sm + 231488;
    bf16*  lnst    = (bf16*)(sm + 247872);       // 16 x 1024 bf16
    float* out = (float*)d_out;

    dim3 blk(256);

    // ---- phase 0: conversions (x, seW, oeW only) + PE + state-row copy ----
    PrepArgs pa;
    pa.x = x; pa.seW = se_W; pa.oeW = oe_W;
    pa.xb = xb; pa.seWb = seWb; pa.oeWb = oeWb;
    pa.state0 = state0; pa.cat = cat; pa.pe = pe;
    prep_kernel<<<7184, blk, 0, stream>>>(pa);

    // ---- phase 1: both embeds (MFMA), XCD-swizzled ----
    embed_fused_kernel<<<512, blk, 0, stream>>>(
        xb, seWb, oeWb, se_b, oe_b, cat, cat2, pe);

    // ---- phase 2: big LNs + q projections + lo_last ----
    ln_fused_kernel<<<8208, blk, 0, stream>>>(cat, cat2, lnbb, lnbb2,
        s_lnkv_g, s_lnkv_b, o_lnkv_g, o_lnkv_b);
    small_ln_gemm_kernel<16><<<256, blk, 0, stream>>>(state0, 0, 1,
        s_lnq_g, s_lnq_b, s_Wq, s_bq, qh_s, 0);
    small_ln_gemm_kernel<4><<<256, blk, 0, stream>>>(cat2, TT - 1, LKV,
        o_lnq_g, o_lnq_b, o_Wq, o_bq, q2h, 0);
    copy_lolast_kernel<<<NB, blk, 0, stream>>>(cat2, lo_last);

    // ---- phase 3: query-side Wk projection ----
    qtil_kernel<<<320, blk, 0, stream>>>(qh_s, q2h, s_Wk, o_Wk, qtil_s, qtil_o);

    // ---- phase 4: merged gate-independent attention scan (both branches) ----
    sc_ctx_main_kernel<<<2048, blk, 0, stream>>>(qtil_s, qtil_o, lnbb, lnbb2,
        pms, pls, pctx_s, pmo, plo, pctx_o);

    // ---- phase 5: state-branch combine + slot MLP + gate ----
    combproj_kernel<4, 16><<<256, blk, 0, stream>>>(pms, pls, pctx_s,
        s_Wv, s_bv, attn_s);
    small_gemm_kernel<16><<<256, blk, 0, stream>>>(attn_s, s_Wo, s_bo, lat1, state0, 0);
    small_ln_gemm_kernel<16><<<256, blk, 0, stream>>>(lat1, 0, 1,
        s_lnffn_g, s_lnffn_b, s_fc1_W, s_fc1_b, g1, 1);
    small_gemm_kernel<16><<<256, blk, 0, stream>>>(g1, s_fc2_W, s_fc2_b, lat2, lat1, 0);
    gate_fused_kernel<<<NB, blk, 0, stream>>>(lat2, s_lnslot_g, s_lnslot_b,
        slot_ctx, state0, stateNew, out);

    // ---- phase 6: gate-dependent tail (4 keys) + out-branch combine + head ----
    lnst_kernel<<<16, blk, 0, stream>>>(stateNew, lnst, o_lnkv_g, o_lnkv_b);
    sc_tail_kernel<<<64, blk, 0, stream>>>(qtil_o, lnst, pmo, plo, pctx_o);
    combproj_kernel<1, 17><<<64, blk, 0, stream>>>(pmo, plo, pctx_o,
        o_Wv, o_bv, attn2);
    small_gemm_kernel<4><<<256, blk, 0, stream>>>(attn2, o_Wo, o_bo, lo1, lo_last, 0);
    small_ln_gemm_kernel<4><<<256, blk, 0, stream>>>(lo1, 0, 1,
        o_lnffn_g, o_lnffn_b, o_fc1_W, o_fc1_b, g2, 1);
    small_gemm_kernel<4><<<256, blk, 0, stream>>>(g2, o_fc2_W, o_fc2_b, lo2, lo1, 0);
    small_gemm_kernel<4><<<256, blk, 0, stream>>>(lo2, op_W, op_b, out, nullptr, 0);
}

// Round 18
// 206.630 us; speedup vs baseline: 1.6074x; 1.0013x over previous
//
#include <hip/hip_runtime.h>
#include <hip/hip_bf16.h>

#define DD 1024
#define NB 4
#define TT 1024
#define NH 16
#define NS 4
#define LKV 1028   // NS + TT

typedef __hip_bfloat16 bf16;
typedef __attribute__((ext_vector_type(8))) short short8;
typedef __attribute__((ext_vector_type(4))) float f32x4;

#define GLD16(gp, lp) __builtin_amdgcn_global_load_lds( \
    (const __attribute__((address_space(1))) unsigned int*)(const void*)(gp), \
    (__attribute__((address_space(3))) unsigned int*)(void*)(lp), 16, 0, 0)

__device__ __forceinline__ float warp_sum(float v) {
#pragma unroll
    for (int o = 32; o > 0; o >>= 1) v += __shfl_xor(v, o);
    return v;
}

__device__ __forceinline__ float b2f(unsigned short u) {
    union { unsigned int i; float f; } x; x.i = ((unsigned)u) << 16; return x.f;
}

// ================= prep: cvt x + 2 embed weights, PE table, state copy ========
struct PrepArgs {
    const float* x;
    const float* seW;
    const float* oeW;
    bf16 *xb, *seWb, *oeWb;
    const float* state0;
    float* cat;
    float* pe;
};

__global__ __launch_bounds__(256) void prep_kernel(PrepArgs a) {
    int bid = blockIdx.x;
    int tid = threadIdx.x;
    if (bid < 6144) {
        const float* in; bf16* out; size_t off;
        if (bid < 4096)      { in = a.x;   out = a.xb;   off = (size_t)bid * 1024; }
        else if (bid < 5120) { in = a.seW; out = a.seWb; off = (size_t)(bid - 4096) * 1024; }
        else                 { in = a.oeW; out = a.oeWb; off = (size_t)(bid - 5120) * 1024; }
        size_t i = off + tid * 4;
        float4 v = *(const float4*)(in + i);
        out[i + 0] = __float2bfloat16(v.x);
        out[i + 1] = __float2bfloat16(v.y);
        out[i + 2] = __float2bfloat16(v.z);
        out[i + 3] = __float2bfloat16(v.w);
    } else if (bid < 7168) {
        int t = bid - 6144;
#pragma unroll
        for (int i = 0; i < 2; ++i) {
            int j = i * 256 + tid;                       // 0..511
            float ang = (float)t * exp2f(-(float)j * (1.0f / 256.0f));
            a.pe[(size_t)t * DD + j]       = sinf(ang);
            a.pe[(size_t)t * DD + 512 + j] = cosf(ang);
        }
    } else {
        int r = bid - 7168;        // 0..15
        int b = r >> 2, s = r & 3;
#pragma unroll
        for (int i = 0; i < 4; ++i)
            a.cat[(size_t)(b * LKV + s) * DD + i * 256 + tid] =
                a.state0[(size_t)r * DD + i * 256 + tid];
    }
}

// ================= fused LayerNorm -> bf16 (state-kv rows + out token rows) ===
__global__ __launch_bounds__(256) void ln_fused_kernel(
    const float* __restrict__ cat, const float* __restrict__ cat2,
    bf16* __restrict__ lnbb, bf16* __restrict__ lnbb2,
    const float* __restrict__ sg, const float* __restrict__ sb,
    const float* __restrict__ og, const float* __restrict__ ob)
{
    int bid = blockIdx.x;
    int tid = threadIdx.x;
    const float* in; bf16* out; const float* g; const float* b;
    if (bid < 4112) {
        in = cat + (size_t)bid * DD; out = lnbb + (size_t)bid * DD; g = sg; b = sb;
    } else {
        int r = bid - 4112;
        int row = (r >> 10) * LKV + (r & 1023);
        in = cat2 + (size_t)row * DD; out = lnbb2 + (size_t)r * DD; g = og; b = ob;
    }
    float v[4];
    float s1 = 0.f, s2 = 0.f;
#pragma unroll
    for (int i = 0; i < 4; ++i) {
        v[i] = in[i * 256 + tid];
        s1 += v[i]; s2 += v[i] * v[i];
    }
    s1 = warp_sum(s1); s2 = warp_sum(s2);
    __shared__ float a1[4], a2[4];
    int w = tid >> 6;
    if ((tid & 63) == 0) { a1[w] = s1; a2[w] = s2; }
    __syncthreads();
    s1 = a1[0] + a1[1] + a1[2] + a1[3];
    s2 = a2[0] + a2[1] + a2[2] + a2[3];
    float mu  = s1 * (1.0f / DD);
    float var = s2 * (1.0f / DD) - mu * mu;
    var = var < 0.f ? 0.f : var;
    float rs = rsqrtf(var + 1e-5f);
#pragma unroll
    for (int i = 0; i < 4; ++i) {
        int c = i * 256 + tid;
        out[c] = __float2bfloat16((v[i] - mu) * rs * g[c] + b[c]);
    }
}

// ================= MFMA tile body (128x128, BK=32, 4 waves) ===================
__device__ __forceinline__ void mfma_tile(
    const bf16* __restrict__ A, const bf16* __restrict__ W,
    const float* __restrict__ bias,
    float* __restrict__ outf,
    int obs, int oro, const float* __restrict__ pe,
    bf16* As, bf16* Ws, int m0, int n0)
{
    int tid  = threadIdx.x;
    int lane = tid & 63;
    int wave = tid >> 6;
    int wm = (wave >> 1) << 6;
    int wn = (wave & 1) << 6;

    f32x4 acc[4][4] = {};

    int soff  = wave * 1024 + lane * 16;
    int srow  = soff >> 6;
    int scol  = (soff & 63) >> 1;
    char* lA0 = (char*)As + wave * 1024;
    char* lA1 = (char*)As + 4096 + wave * 1024;
    char* lW0 = (char*)Ws + wave * 1024;
    char* lW1 = (char*)Ws + 4096 + wave * 1024;

    int fRow = lane & 15;
    int kOff = (lane >> 4) << 3;

    for (int k0 = 0; k0 < DD; k0 += 32) {
        GLD16(A + (size_t)(m0 + srow) * DD + k0 + scol,      lA0);
        GLD16(A + (size_t)(m0 + 64 + srow) * DD + k0 + scol, lA1);
        GLD16(W + (size_t)(n0 + srow) * DD + k0 + scol,      lW0);
        GLD16(W + (size_t)(n0 + 64 + srow) * DD + k0 + scol, lW1);
        __syncthreads();
        short8 a[4], b[4];
#pragma unroll
        for (int mi = 0; mi < 4; ++mi)
            a[mi] = *(const short8*)(As + (wm + mi * 16 + fRow) * 32 + kOff);
#pragma unroll
        for (int ni = 0; ni < 4; ++ni)
            b[ni] = *(const short8*)(Ws + (wn + ni * 16 + fRow) * 32 + kOff);
#pragma unroll
        for (int mi = 0; mi < 4; ++mi)
#pragma unroll
            for (int ni = 0; ni < 4; ++ni)
                acc[mi][ni] = __builtin_amdgcn_mfma_f32_16x16x32_bf16(
                    a[mi], b[ni], acc[mi][ni], 0, 0, 0);
        __syncthreads();
    }

    int cCol  = lane & 15;
    int cRow4 = (lane >> 4) << 2;
#pragma unroll
    for (int mi = 0; mi < 4; ++mi) {
#pragma unroll
        for (int ni = 0; ni < 4; ++ni) {
#pragma unroll
            for (int r = 0; r < 4; ++r) {
                int row = m0 + wm + mi * 16 + cRow4 + r;
                int col = n0 + wn + ni * 16 + cCol;
                float v = acc[mi][ni][r] + bias[col] + pe[(size_t)(row & 1023) * DD + col];
                int orow = (row >> 10) * obs + oro + (row & 1023);
                outf[(size_t)orow * DD + col] = v;
            }
        }
    }
}

// ================= fused embeds, XCD-swizzled linear grid (512 blocks) ========
__global__ __launch_bounds__(256) void embed_fused_kernel(
    const bf16* __restrict__ xb,
    const bf16* __restrict__ seW, const bf16* __restrict__ oeW,
    const float* __restrict__ seb, const float* __restrict__ oeb,
    float* __restrict__ cat, float* __restrict__ cat2,
    const float* __restrict__ pe)
{
    __shared__ bf16 As[128 * 32];
    __shared__ bf16 Ws[128 * 32];
    int bid = blockIdx.x;
    int t = (bid & 7) * 64 + (bid >> 3);   // bijective XCD swizzle (512 = 8*64)
    int x = t & 7;
    int q = t >> 3;
    int z = q & 1;
    int y = q >> 1;
    const bf16* W = z ? oeW : seW;
    const float* bias = z ? oeb : seb;
    float* outf = z ? cat2 : cat;
    int oro = z ? 0 : NS;
    mfma_tile(xb, W, bias, outf, LKV, oro, pe, As, Ws, y * 128, x * 128);
}

// ================= copy lo[:, -1] =============================================
__global__ __launch_bounds__(256) void copy_lolast_kernel(
    const float* __restrict__ cat2, float* __restrict__ dst)
{
    int b = blockIdx.x;
    int tid = threadIdx.x;
#pragma unroll
    for (int i = 0; i < 4; ++i)
        dst[(size_t)b * DD + i * 256 + tid] =
            cat2[(size_t)(b * LKV + (TT - 1)) * DD + i * 256 + tid];
}

// ================= small GEMM (M<=16), f32 LDS staging =========================
template<int M>
__global__ __launch_bounds__(256) void small_gemm_kernel(
    const float* __restrict__ A, const float* __restrict__ W,
    const float* __restrict__ bias, float* __restrict__ out,
    const float* __restrict__ res, int gelu)
{
    __shared__ float As[M * DD];
    int tid = threadIdx.x;
#pragma unroll
    for (int i = 0; i < M; ++i) {
        int idx = (i * 256 + tid) * 4;
        *(float4*)(As + idx) = *(const float4*)(A + idx);
    }
    __syncthreads();
    int lane = tid & 63;
    int w = tid >> 6;
    int n = blockIdx.x * 4 + w;
    const float* Wr = W + (size_t)n * DD;
    float acc[M] = {};
#pragma unroll
    for (int j = 0; j < 4; ++j) {
        float4 wv = *(const float4*)(Wr + j * 256 + lane * 4);
#pragma unroll
        for (int m = 0; m < M; ++m) {
            float4 av = *(const float4*)(As + m * DD + j * 256 + lane * 4);
            acc[m] += av.x * wv.x + av.y * wv.y + av.z * wv.z + av.w * wv.w;
        }
    }
#pragma unroll
    for (int m = 0; m < M; ++m) acc[m] = warp_sum(acc[m]);
    if (lane == 0) {
#pragma unroll
        for (int m = 0; m < M; ++m) {
            float v = acc[m] + bias[n];
            if (gelu) v = 0.5f * v * (1.0f + erff(v * 0.70710678118654752f));
            if (res)  v += res[(size_t)m * DD + n];
            out[(size_t)m * DD + n] = v;
        }
    }
}

// ============ small GEMM with fused input LayerNorm ===========================
template<int M>
__global__ __launch_bounds__(256) void small_ln_gemm_kernel(
    const float* __restrict__ A, int row0, int rstride,
    const float* __restrict__ lng, const float* __restrict__ lnb,
    const float* __restrict__ W, const float* __restrict__ bias,
    float* __restrict__ outf, int gelu)
{
    __shared__ float As[M * DD];
    __shared__ float smu[M], srs[M];
    int tid = threadIdx.x;
    int lane = tid & 63;
    int w = tid >> 6;
#pragma unroll
    for (int i = 0; i < M; ++i) {
        int row = row0 + i * rstride;
        *(float4*)(As + i * DD + tid * 4) =
            *(const float4*)(A + (size_t)row * DD + tid * 4);
    }
    __syncthreads();
    constexpr int RPW = (M + 3) / 4;
#pragma unroll
    for (int i = 0; i < RPW; ++i) {
        int r = w * RPW + i;
        if (r < M) {
            float s1 = 0.f, s2 = 0.f;
#pragma unroll
            for (int j = 0; j < 4; ++j) {
                float4 v = *(const float4*)(As + r * DD + (j * 64 + lane) * 4);
                s1 += v.x + v.y + v.z + v.w;
                s2 += v.x*v.x + v.y*v.y + v.z*v.z + v.w*v.w;
            }
            s1 = warp_sum(s1); s2 = warp_sum(s2);
            if (lane == 0) {
                float mu = s1 * (1.0f / DD);
                float var = s2 * (1.0f / DD) - mu * mu;
                var = var < 0.f ? 0.f : var;
                smu[r] = mu; srs[r] = rsqrtf(var + 1e-5f);
            }
        }
    }
    __syncthreads();
    float4 gv = *(const float4*)(lng + tid * 4);
    float4 bv = *(const float4*)(lnb + tid * 4);
#pragma unroll
    for (int i = 0; i < M; ++i) {
        float mu = smu[i], rs = srs[i];
        float4 v = *(const float4*)(As + i * DD + tid * 4);
        v.x = (v.x - mu) * rs * gv.x + bv.x;
        v.y = (v.y - mu) * rs * gv.y + bv.y;
        v.z = (v.z - mu) * rs * gv.z + bv.z;
        v.w = (v.w - mu) * rs * gv.w + bv.w;
        *(float4*)(As + i * DD + tid * 4) = v;
    }
    __syncthreads();
    int n = blockIdx.x * 4 + w;
    const float* Wr = W + (size_t)n * DD;
    float acc[M] = {};
#pragma unroll
    for (int j = 0; j < 4; ++j) {
        float4 wv = *(const float4*)(Wr + j * 256 + lane * 4);
#pragma unroll
        for (int m = 0; m < M; ++m) {
            float4 av = *(const float4*)(As + m * DD + j * 256 + lane * 4);
            acc[m] += av.x * wv.x + av.y * wv.y + av.z * wv.z + av.w * wv.w;
        }
    }
#pragma unroll
    for (int m = 0; m < M; ++m) acc[m] = warp_sum(acc[m]);
    if (lane == 0) {
#pragma unroll
        for (int m = 0; m < M; ++m) {
            float v = acc[m] + bias[n];
            if (gelu) v = 0.5f * v * (1.0f + erff(v * 0.70710678118654752f));
            outf[(size_t)m * DD + n] = v;
        }
    }
}

// ============ qtil: project queries through Wk (low-rank attention trick) =====
__global__ __launch_bounds__(256) void qtil_kernel(
    const float* __restrict__ qh_s, const float* __restrict__ q2h,
    const float* __restrict__ sWk, const float* __restrict__ oWk,
    float* __restrict__ qtil_s, float* __restrict__ qtil_o)
{
    int blk = blockIdx.x;
    int tid = threadIdx.x;
    const float* src; const float* W; float* dst; int h;
    if (blk < 256) {
        int bq = blk >> 4;          // b*4+q
        h = blk & 15;
        src = qh_s + (size_t)bq * DD;
        W = sWk; dst = qtil_s + (size_t)blk * DD;
    } else {
        int o = blk - 256;
        int b = o >> 4;
        h = o & 15;
        src = q2h + (size_t)b * DD;
        W = oWk; dst = qtil_o + (size_t)o * DD;
    }
    __shared__ float qv[64];
    if (tid < 64) qv[tid] = src[h * 64 + tid];
    __syncthreads();
    int i = tid * 4;
    float4 acc = {0.f, 0.f, 0.f, 0.f};
#pragma unroll 4
    for (int o = 0; o < 64; ++o) {
        float4 wr = *(const float4*)(W + (size_t)(h * 64 + o) * DD + i);
        float s = qv[o];
        acc.x += s * wr.x; acc.y += s * wr.y; acc.z += s * wr.z; acc.w += s * wr.w;
    }
    acc.x *= 0.125f; acc.y *= 0.125f; acc.z *= 0.125f; acc.w *= 0.125f;
    *(float4*)(dst + i) = acc;
}

// ============ sc_ctx body: scores + softmax-partial + ctx for one chunk =======
// Register/shuffle pass 1; nchs = chunk-slot stride in pm/pl/pctx.
template<int LQ, int CHSv>
__device__ void sc_ctx_body(int c, int bh,
    const float* __restrict__ qtil, const bf16* __restrict__ keys,
    int keyStride, int nkey, int nchs,
    float* __restrict__ pm, float* __restrict__ pl, float* __restrict__ pctx,
    float* sc, float* redm, float* redl)
{
    int b = bh >> 4, h = bh & 15;
    int tid = threadIdx.x;
    int lane = tid & 63, w = tid >> 6;

    float qreg[LQ][16];
#pragma unroll
    for (int q = 0; q < LQ; ++q) {
        const float* qrow = qtil + (size_t)((b * LQ + q) * 16 + h) * DD + lane * 16;
#pragma unroll
        for (int j = 0; j < 4; ++j) {
            float4 v = *(const float4*)(qrow + j * 4);
            qreg[q][j*4+0] = v.x; qreg[q][j*4+1] = v.y;
            qreg[q][j*4+2] = v.z; qreg[q][j*4+3] = v.w;
        }
    }

    int kbeg = c * CHSv;
    int kcnt = nkey - kbeg; if (kcnt > CHSv) kcnt = CHSv;

    // pass 1: wave-per-key, coalesced 32B/lane key reads, shfl reduce
    for (int t = w; t < kcnt; t += 4) {
        const unsigned short* row = (const unsigned short*)keys
            + (size_t)(b * keyStride + kbeg + t) * DD + lane * 16;
        float kf[16];
#pragma unroll
        for (int j = 0; j < 4; ++j) {
            ushort4 v = *(const ushort4*)(row + j * 4);
            kf[j*4+0] = b2f(v.x); kf[j*4+1] = b2f(v.y);
            kf[j*4+2] = b2f(v.z); kf[j*4+3] = b2f(v.w);
        }
        float acc[LQ];
#pragma unroll
        for (int q = 0; q < LQ; ++q) acc[q] = 0.f;
#pragma unroll
        for (int j = 0; j < 16; ++j)
#pragma unroll
            for (int q = 0; q < LQ; ++q)
                acc[q] += kf[j] * qreg[q][j];
#pragma unroll
        for (int q = 0; q < LQ; ++q) acc[q] = warp_sum(acc[q]);
        if (lane == 0) {
#pragma unroll
            for (int q = 0; q < LQ; ++q) sc[q * CHSv + t] = acc[q];
        }
    }
    __syncthreads();

    float M[LQ], L[LQ];
#pragma unroll
    for (int q = 0; q < LQ; ++q) {
        float lm = -1e30f;
        for (int t = tid; t < kcnt; t += 256) lm = fmaxf(lm, sc[q * CHSv + t]);
#pragma unroll
        for (int o = 32; o > 0; o >>= 1) lm = fmaxf(lm, __shfl_xor(lm, o));
        if (lane == 0) redm[w * LQ + q] = lm;
    }
    __syncthreads();
#pragma unroll
    for (int q = 0; q < LQ; ++q)
        M[q] = fmaxf(fmaxf(redm[q], redm[LQ + q]),
                     fmaxf(redm[2 * LQ + q], redm[3 * LQ + q]));
#pragma unroll
    for (int q = 0; q < LQ; ++q) {
        float ls = 0.f;
        for (int t = tid; t < kcnt; t += 256) {
            float e = expf(sc[q * CHSv + t] - M[q]);
            sc[q * CHSv + t] = e;
            ls += e;
        }
        ls = warp_sum(ls);
        if (lane == 0) redl[w * LQ + q] = ls;
    }
    __syncthreads();
#pragma unroll
    for (int q = 0; q < LQ; ++q)
        L[q] = redl[q] + redl[LQ + q] + redl[2 * LQ + q] + redl[3 * LQ + q];

    // pass 2: thread-per-dim ctx accumulation (coalesced key reads)
    int i4 = tid * 4;
    float cx[LQ][4];
#pragma unroll
    for (int q = 0; q < LQ; ++q) { cx[q][0]=0; cx[q][1]=0; cx[q][2]=0; cx[q][3]=0; }
    for (int t = 0; t < kcnt; ++t) {
        const unsigned short* row = (const unsigned short*)keys
            + (size_t)(b * keyStride + kbeg + t) * DD;
        ushort4 v = *(const ushort4*)(row + i4);
        float f0 = b2f(v.x), f1 = b2f(v.y), f2 = b2f(v.z), f3 = b2f(v.w);
#pragma unroll
        for (int q = 0; q < LQ; ++q) {
            float p = sc[q * CHSv + t];
            cx[q][0] += p * f0; cx[q][1] += p * f1;
            cx[q][2] += p * f2; cx[q][3] += p * f3;
        }
    }
#pragma unroll
    for (int q = 0; q < LQ; ++q) {
        float4 o4 = {cx[q][0], cx[q][1], cx[q][2], cx[q][3]};
        *(float4*)(pctx + (size_t)((bh * nchs + c) * LQ + q) * DD + i4) = o4;
    }
    if (tid < LQ) {
        pm[(bh * LQ + tid) * nchs + c] = M[tid];
        pl[(bh * LQ + tid) * nchs + c] = L[tid];
    }
}

// ======= merged sc_ctx: blocks 0-1023 state branch; 1024-2047 out tokens ======
__global__ __launch_bounds__(256) void sc_ctx_main_kernel(
    const float* __restrict__ qtil_s, const float* __restrict__ qtil_o,
    const bf16* __restrict__ lnbb, const bf16* __restrict__ lnbb2,
    float* __restrict__ pms, float* __restrict__ pls, float* __restrict__ pctx_s,
    float* __restrict__ pmo, float* __restrict__ plo, float* __restrict__ pctx_o)
{
    __shared__ float sc[4 * 65];
    __shared__ float redm[16], redl[16];
    int bid = blockIdx.x;
    if (bid < 1024) {
        int c = bid & 15, bh = bid >> 4;
        sc_ctx_body<4, 65>(c, bh, qtil_s, lnbb, LKV, 1028, 16,
                           pms, pls, pctx_s, sc, redm, redl);
    } else {
        bid -= 1024;
        int c = bid & 15, bh = bid >> 4;
        sc_ctx_body<1, 64>(c, bh, qtil_o, lnbb2, TT, 1024, 17,
                           pmo, plo, pctx_o, sc, redm, redl);
    }
}

// ======= gate-dependent tail: 4 new-state keys as chunk 16 of out branch ======
__global__ __launch_bounds__(256) void sc_tail_kernel(
    const float* __restrict__ qtil_o, const bf16* __restrict__ lnst,
    float* __restrict__ pmo, float* __restrict__ plo, float* __restrict__ pctx_o)
{
    __shared__ float sc4[4];
    int bh = blockIdx.x;
    int b = bh >> 4, h = bh & 15;
    int tid = threadIdx.x;
    int lane = tid & 63, w = tid >> 6;

    {
        const unsigned short* row = (const unsigned short*)lnst
            + (size_t)(b * 4 + w) * DD + lane * 16;
        const float* qrow = qtil_o + (size_t)bh * DD + lane * 16;
        float s = 0.f;
#pragma unroll
        for (int j = 0; j < 4; ++j) {
            ushort4 v = *(const ushort4*)(row + j * 4);
            float4 qv = *(const float4*)(qrow + j * 4);
            s += b2f(v.x)*qv.x + b2f(v.y)*qv.y + b2f(v.z)*qv.z + b2f(v.w)*qv.w;
        }
        s = warp_sum(s);
        if (lane == 0) sc4[w] = s;
    }
    __syncthreads();
    float m = fmaxf(fmaxf(sc4[0], sc4[1]), fmaxf(sc4[2], sc4[3]));
    float e0 = expf(sc4[0] - m), e1 = expf(sc4[1] - m);
    float e2 = expf(sc4[2] - m), e3 = expf(sc4[3] - m);
    float l = e0 + e1 + e2 + e3;
    int i4 = tid * 4;
    const unsigned short* k0 = (const unsigned short*)lnst + (size_t)(b*4+0)*DD + i4;
    const unsigned short* k1 = (const unsigned short*)lnst + (size_t)(b*4+1)*DD + i4;
    const unsigned short* k2 = (const unsigned short*)lnst + (size_t)(b*4+2)*DD + i4;
    const unsigned short* k3 = (const unsigned short*)lnst + (size_t)(b*4+3)*DD + i4;
    ushort4 v0 = *(const ushort4*)k0, v1 = *(const ushort4*)k1;
    ushort4 v2 = *(const ushort4*)k2, v3 = *(const ushort4*)k3;
    float4 o4;
    o4.x = e0*b2f(v0.x) + e1*b2f(v1.x) + e2*b2f(v2.x) + e3*b2f(v3.x);
    o4.y = e0*b2f(v0.y) + e1*b2f(v1.y) + e2*b2f(v2.y) + e3*b2f(v3.y);
    o4.z = e0*b2f(v0.z) + e1*b2f(v1.z) + e2*b2f(v2.z) + e3*b2f(v3.z);
    o4.w = e0*b2f(v0.w) + e1*b2f(v1.w) + e2*b2f(v2.w) + e3*b2f(v3.w);
    *(float4*)(pctx_o + (size_t)(bh * 17 + 16) * DD + i4) = o4;
    if (tid == 0) {
        pmo[bh * 17 + 16] = m;
        plo[bh * 17 + 16] = l;
    }
}

// ============ combproj: combine NCHT chunk ctx + project through Wv + bv ======
template<int LQ, int NCHT>
__global__ __launch_bounds__(256) void combproj_kernel(
    const float* __restrict__ pm, const float* __restrict__ pl,
    const float* __restrict__ pctx,
    const float* __restrict__ Wv, const float* __restrict__ bv,
    float* __restrict__ attn)
{
    __shared__ float ctxf[DD];
    int blk = blockIdx.x;
    int h = blk & 15;
    int bq = blk >> 4;               // b*LQ+q
    int b = bq / LQ, q = bq - b * LQ;
    int bh = b * 16 + h;
    int tid = threadIdx.x;
    int lane = tid & 63, w = tid >> 6;

    int base = (bh * LQ + q) * NCHT;
    float Mx = -1e30f;
#pragma unroll
    for (int c = 0; c < NCHT; ++c) Mx = fmaxf(Mx, pm[base + c]);
    float wc[NCHT];
    float L = 0.f;
#pragma unroll
    for (int c = 0; c < NCHT; ++c) {
        wc[c] = expf(pm[base + c] - Mx);
        L += pl[base + c] * wc[c];
    }
    float inv = 1.f / L;
    int i4 = tid * 4;
    float4 s4 = {0.f, 0.f, 0.f, 0.f};
#pragma unroll
    for (int c = 0; c < NCHT; ++c) {
        float4 a = *(const float4*)(pctx + (size_t)((bh * NCHT + c) * LQ + q) * DD + i4);
        s4.x += a.x * wc[c]; s4.y += a.y * wc[c];
        s4.z += a.z * wc[c]; s4.w += a.w * wc[c];
    }
    ctxf[i4+0] = s4.x * inv;
    ctxf[i4+1] = s4.y * inv;
    ctxf[i4+2] = s4.z * inv;
    ctxf[i4+3] = s4.w * inv;
    __syncthreads();

#pragma unroll 1
    for (int rr = 0; rr < 16; ++rr) {
        int o = h * 64 + w * 16 + rr;
        const float* Wr = Wv + (size_t)o * DD + lane * 16;
        const float* cf = ctxf + lane * 16;
        float s = 0.f;
#pragma unroll
        for (int j = 0; j < 4; ++j) {
            float4 wv4 = *(const float4*)(Wr + j * 4);
            s += wv4.x * cf[j*4+0] + wv4.y * cf[j*4+1]
               + wv4.z * cf[j*4+2] + wv4.w * cf[j*4+3];
        }
        s = warp_sum(s);
        if (lane == 0)
            attn[(size_t)bq * DD + o] = s + bv[o];
    }
}

// ================= LN of stateNew rows -> bf16 (out-branch keys) ==============
__global__ __launch_bounds__(256) void lnst_kernel(
    const float* __restrict__ stateNew, bf16* __restrict__ lnst,
    const float* __restrict__ g, const float* __restrict__ b)
{
    int r = blockIdx.x;
    int tid = threadIdx.x;
    size_t base = (size_t)r * DD;
    float v[4];
    float s1 = 0.f, s2 = 0.f;
#pragma unroll
    for (int i = 0; i < 4; ++i) {
        v[i] = stateNew[base + i * 256 + tid];
        s1 += v[i]; s2 += v[i] * v[i];
    }
    s1 = warp_sum(s1); s2 = warp_sum(s2);
    __shared__ float a1[4], a2[4];
    int w = tid >> 6;
    if ((tid & 63) == 0) { a1[w] = s1; a2[w] = s2; }
    __syncthreads();
    s1 = a1[0] + a1[1] + a1[2] + a1[3];
    s2 = a2[0] + a2[1] + a2[2] + a2[3];
    float mu  = s1 * (1.0f / DD);
    float var = s2 * (1.0f / DD) - mu * mu;
    var = var < 0.f ? 0.f : var;
    float rs = rsqrtf(var + 1e-5f);
#pragma unroll
    for (int i = 0; i < 4; ++i) {
        int c = i * 256 + tid;
        lnst[base + c] = __float2bfloat16((v[i] - mu) * rs * g[c] + b[c]);
    }
}

// ========== fused gate: LN(lat2) -> logits -> top2 -> state update ============
__global__ __launch_bounds__(256) void gate_fused_kernel(
    const float* __restrict__ lat2,
    const float* __restrict__ lng, const float* __restrict__ lnb,
    const float* __restrict__ ctx,
    const float* __restrict__ state_old, float* __restrict__ stateNew,
    float* __restrict__ dout)
{
    int b = blockIdx.x;
    int tid = threadIdx.x;
    int lane = tid & 63, w = tid >> 6;
    __shared__ float logit[NS];
    __shared__ float alpha[NS];

    {
        const float* row = lat2 + (size_t)(b * NS + w) * DD;
        float4 v[4];
        float s1 = 0.f, s2 = 0.f;
#pragma unroll
        for (int j = 0; j < 4; ++j) {
            v[j] = *(const float4*)(row + (j * 64 + lane) * 4);
            s1 += v[j].x + v[j].y + v[j].z + v[j].w;
            s2 += v[j].x*v[j].x + v[j].y*v[j].y + v[j].z*v[j].z + v[j].w*v[j].w;
        }
        s1 = warp_sum(s1); s2 = warp_sum(s2);
        float mu = s1 * (1.0f / DD);
        float var = s2 * (1.0f / DD) - mu * mu;
        var = var < 0.f ? 0.f : var;
        float rs = rsqrtf(var + 1e-5f);
        float dot = 0.f;
#pragma unroll
        for (int j = 0; j < 4; ++j) {
            int c = (j * 64 + lane) * 4;
            float4 gv = *(const float4*)(lng + c);
            float4 bv = *(const float4*)(lnb + c);
            float4 cv = *(const float4*)(ctx + c);
            dot += ((v[j].x - mu) * rs * gv.x + bv.x) * cv.x
                 + ((v[j].y - mu) * rs * gv.y + bv.y) * cv.y
                 + ((v[j].z - mu) * rs * gv.z + bv.z) * cv.z
                 + ((v[j].w - mu) * rs * gv.w + bv.w) * cv.w;
        }
        dot = warp_sum(dot);
        if (lane == 0) logit[w] = dot;
    }
    __syncthreads();
    if (tid == 0) {
        float l[NS];
        for (int s = 0; s < NS; ++s) l[s] = logit[s];
        int i0 = 0;
        for (int s = 1; s < NS; ++s) if (l[s] > l[i0]) i0 = s;
        int i1 = (i0 == 0) ? 1 : 0;
        for (int s = 0; s < NS; ++s) if (s != i0 && l[s] > l[i1]) i1 = s;
        float mx = fmaxf(l[i0], l[i1]);
        float e0 = expf(l[i0] - mx), e1 = expf(l[i1] - mx);
        float inv = 1.f / (e0 + e1);
        for (int s = 0; s < NS; ++s) alpha[s] = 0.f;
        alpha[i0] = e0 * inv;
        alpha[i1] += e1 * inv;
        dout[4096 + b * 2 + 0] = (float)i0;
        dout[4096 + b * 2 + 1] = (float)i1;
    }
    __syncthreads();
    for (int idx = tid; idx < NS * DD; idx += 256) {
        int s = idx >> 10;
        float so = state_old[(size_t)b * NS * DD + idx];
        float lt = lat2[(size_t)b * NS * DD + idx];
        float ns = 0.6f * so + 0.4f * alpha[s] * tanhf(lt);
        stateNew[(size_t)b * NS * DD + idx] = ns;
        dout[4104 + b * NS * DD + idx] = ns;
    }
}

extern "C" void kernel_launch(void* const* d_in, const int* in_sizes, int n_in,
                              void* d_out, int out_size, void* d_ws, size_t ws_size,
                              hipStream_t stream)
{
    const float* x        = (const float*)d_in[0];
    const float* state0   = (const float*)d_in[1];
    const float* se_W     = (const float*)d_in[2];
    const float* se_b     = (const float*)d_in[3];
    const float* s_Wq     = (const float*)d_in[4];
    const float* s_bq     = (const float*)d_in[5];
    const float* s_Wk     = (const float*)d_in[6];
    const float* s_bk     = (const float*)d_in[7];   (void)s_bk;  // drops out of softmax
    const float* s_Wv     = (const float*)d_in[8];
    const float* s_bv     = (const float*)d_in[9];
    const float* s_Wo     = (const float*)d_in[10];
    const float* s_bo     = (const float*)d_in[11];
    const float* s_lnq_g  = (const float*)d_in[12];
    const float* s_lnq_b  = (const float*)d_in[13];
    const float* s_lnkv_g = (const float*)d_in[14];
    const float* s_lnkv_b = (const float*)d_in[15];
    const float* s_fc1_W  = (const float*)d_in[16];
    const float* s_fc1_b  = (const float*)d_in[17];
    const float* s_fc2_W  = (const float*)d_in[18];
    const float* s_fc2_b  = (const float*)d_in[19];
    const float* s_lnffn_g= (const float*)d_in[20];
    const float* s_lnffn_b= (const float*)d_in[21];
    const float* s_lnslot_g=(const float*)d_in[22];
    const float* s_lnslot_b=(const float*)d_in[23];
    const float* slot_ctx = (const float*)d_in[24];
    const float* oe_W     = (const float*)d_in[25];
    const float* oe_b     = (const float*)d_in[26];
    const float* o_Wq     = (const float*)d_in[27];
    const float* o_bq     = (const float*)d_in[28];
    const float* o_Wk     = (const float*)d_in[29];
    const float* o_bk     = (const float*)d_in[30];  (void)o_bk;  // drops out of softmax
    const float* o_Wv     = (const float*)d_in[31];
    const float* o_bv     = (const float*)d_in[32];
    const float* o_Wo     = (const float*)d_in[33];
    const float* o_bo     = (const float*)d_in[34];
    const float* o_lnq_g  = (const float*)d_in[35];
    const float* o_lnq_b  = (const float*)d_in[36];
    const float* o_lnkv_g = (const float*)d_in[37];
    const float* o_lnkv_b = (const float*)d_in[38];
    const float* o_fc1_W  = (const float*)d_in[39];
    const float* o_fc1_b  = (const float*)d_in[40];
    const float* o_fc2_W  = (const float*)d_in[41];
    const float* o_fc2_b  = (const float*)d_in[42];
    const float* o_lnffn_g= (const float*)d_in[43];
    const float* o_lnffn_b= (const float*)d_in[44];
    const float* op_W     = (const float*)d_in[45];
    const float* op_b     = (const float*)d_in[46];

    float* ws = (float*)d_ws;
    float* pe    = ws;
    float* cat   = ws + 1048576;                 // consumed by ln_fused, then reused:
    float* qtil_s= ws + 1048576;                 //   256 x 1024
    float* qtil_o= ws + 1310720;                 //   64 x 1024
    float* pctx_o= ws + 1376256;                 //   64*17 x 1024 = 1,114,112
    float* pms   = ws + 2490368;                 //   64*4*16 = 4096
    float* pls   = ws + 2494464;                 //   4096
    float* pmo   = ws + 2498560;                 //   64*17 = 1088 (pad 2048)
    float* plo   = ws + 2500608;                 //   1088
    bf16*  lnbb  = (bf16*)(ws + 5259264);        // 4112 rows bf16
    float* cat2  = ws + 7421952;                 // consumed in phase 2, then:
    float* pctx_s= ws + 7421952;                 //   64*16*4 x 1024 = 4,194,304
    bf16*  xb    = (bf16*)(ws + 11632640);       // xb early, lnbb2 late (alias)
    bf16*  lnbb2 = (bf16*)(ws + 11632640);
    bf16*  seWb  = (bf16*)(ws + 13729792);
    bf16*  oeWb  = seWb + 1048576;
    float* sm    = ws + 16875520;
    float* qh_s    = sm + 16384;
    float* attn_s  = sm + 32768;
    float* lat1    = sm + 49152;
    float* g1      = sm + 81920;
    float* lat2    = sm + 98304;
    float* q2h     = sm + 135232;
    float* attn2   = sm + 139328;
    float* lo_last = sm + 143424;
    float* lo1     = sm + 147520;
    float* g2      = sm + 155712;
    float* lo2     = sm + 159808;
    float* stateNew= sm + 231488;
    bf16*  lnst    = (bf16*)(sm + 247872);       // 16 x 1024 bf16
    float* out = (float*)d_out;

    dim3 blk(256);

    // ---- phase 0: conversions (x, seW, oeW only) + PE + state-row copy ----
    PrepArgs pa;
    pa.x = x; pa.seW = se_W; pa.oeW = oe_W;
    pa.xb = xb; pa.seWb = seWb; pa.oeWb = oeWb;
    pa.state0 = state0; pa.cat = cat; pa.pe = pe;
    prep_kernel<<<7184, blk, 0, stream>>>(pa);

    // ---- phase 1: both embeds (MFMA), XCD-swizzled ----
    embed_fused_kernel<<<512, blk, 0, stream>>>(
        xb, seWb, oeWb, se_b, oe_b, cat, cat2, pe);

    // ---- phase 2: big LNs + q projections + lo_last ----
    ln_fused_kernel<<<8208, blk, 0, stream>>>(cat, cat2, lnbb, lnbb2,
        s_lnkv_g, s_lnkv_b, o_lnkv_g, o_lnkv_b);
    small_ln_gemm_kernel<16><<<256, blk, 0, stream>>>(state0, 0, 1,
        s_lnq_g, s_lnq_b, s_Wq, s_bq, qh_s, 0);
    small_ln_gemm_kernel<4><<<256, blk, 0, stream>>>(cat2, TT - 1, LKV,
        o_lnq_g, o_lnq_b, o_Wq, o_bq, q2h, 0);
    copy_lolast_kernel<<<NB, blk, 0, stream>>>(cat2, lo_last);

    // ---- phase 3: query-side Wk projection ----
    qtil_kernel<<<320, blk, 0, stream>>>(qh_s, q2h, s_Wk, o_Wk, qtil_s, qtil_o);

    // ---- phase 4: merged gate-independent attention scan (both branches) ----
    sc_ctx_main_kernel<<<2048, blk, 0, stream>>>(qtil_s, qtil_o, lnbb, lnbb2,
        pms, pls, pctx_s, pmo, plo, pctx_o);

    // ---- phase 5: state-branch combine + slot MLP + gate ----
    combproj_kernel<4, 16><<<256, blk, 0, stream>>>(pms, pls, pctx_s,
        s_Wv, s_bv, attn_s);
    small_gemm_kernel<16><<<256, blk, 0, stream>>>(attn_s, s_Wo, s_bo, lat1, state0, 0);
    small_ln_gemm_kernel<16><<<256, blk, 0, stream>>>(lat1, 0, 1,
        s_lnffn_g, s_lnffn_b, s_fc1_W, s_fc1_b, g1, 1);
    small_gemm_kernel<16><<<256, blk, 0, stream>>>(g1, s_fc2_W, s_fc2_b, lat2, lat1, 0);
    gate_fused_kernel<<<NB, blk, 0, stream>>>(lat2, s_lnslot_g, s_lnslot_b,
        slot_ctx, state0, stateNew, out);

    // ---- phase 6: gate-dependent tail (4 keys) + out-branch combine + head ----
    lnst_kernel<<<16, blk, 0, stream>>>(stateNew, lnst, o_lnkv_g, o_lnkv_b);
    sc_tail_kernel<<<64, blk, 0, stream>>>(qtil_o, lnst, pmo, plo, pctx_o);
    combproj_kernel<1, 17><<<64, blk, 0, stream>>>(pmo, plo, pctx_o,
        o_Wv, o_bv, attn2);
    small_gemm_kernel<4><<<256, blk, 0, stream>>>(attn2, o_Wo, o_bo, lo1, lo_last, 0);
    small_ln_gemm_kernel<4><<<256, blk, 0, stream>>>(lo1, 0, 1,
        o_lnffn_g, o_lnffn_b, o_fc1_W, o_fc1_b, g2, 1);
    small_gemm_kernel<4><<<256, blk, 0, stream>>>(g2, o_fc2_W, o_fc2_b, lo2, lo1, 0);
    small_gemm_kernel<4><<<256, blk, 0, stream>>>(lo2, op_W, op_b, out, nullptr, 0);
}

// Round 19
// 206.516 us; speedup vs baseline: 1.6083x; 1.0005x over previous
//
#include <hip/hip_runtime.h>
#include <hip/hip_bf16.h>

#define DD 1024
#define NB 4
#define TT 1024
#define NH 16
#define NS 4
#define LKV 1028   // NS + TT

typedef __hip_bfloat16 bf16;
typedef __attribute__((ext_vector_type(8))) short short8;
typedef __attribute__((ext_vector_type(4))) float f32x4;

#define GLD16(gp, lp) __builtin_amdgcn_global_load_lds( \
    (const __attribute__((address_space(1))) unsigned int*)(const void*)(gp), \
    (__attribute__((address_space(3))) unsigned int*)(void*)(lp), 16, 0, 0)

__device__ __forceinline__ float warp_sum(float v) {
#pragma unroll
    for (int o = 32; o > 0; o >>= 1) v += __shfl_xor(v, o);
    return v;
}

__device__ __forceinline__ float b2f(unsigned short u) {
    union { unsigned int i; float f; } x; x.i = ((unsigned)u) << 16; return x.f;
}

// ================= prep: cvt x + 2 embed weights, PE table, state copy ========
struct PrepArgs {
    const float* x;
    const float* seW;
    const float* oeW;
    bf16 *xb, *seWb, *oeWb;
    const float* state0;
    float* cat;
    float* pe;
};

__global__ __launch_bounds__(256) void prep_kernel(PrepArgs a) {
    int bid = blockIdx.x;
    int tid = threadIdx.x;
    if (bid < 6144) {
        const float* in; bf16* out; size_t off;
        if (bid < 4096)      { in = a.x;   out = a.xb;   off = (size_t)bid * 1024; }
        else if (bid < 5120) { in = a.seW; out = a.seWb; off = (size_t)(bid - 4096) * 1024; }
        else                 { in = a.oeW; out = a.oeWb; off = (size_t)(bid - 5120) * 1024; }
        size_t i = off + tid * 4;
        float4 v = *(const float4*)(in + i);
        out[i + 0] = __float2bfloat16(v.x);
        out[i + 1] = __float2bfloat16(v.y);
        out[i + 2] = __float2bfloat16(v.z);
        out[i + 3] = __float2bfloat16(v.w);
    } else if (bid < 7168) {
        int t = bid - 6144;
#pragma unroll
        for (int i = 0; i < 2; ++i) {
            int j = i * 256 + tid;                       // 0..511
            float ang = (float)t * exp2f(-(float)j * (1.0f / 256.0f));
            a.pe[(size_t)t * DD + j]       = sinf(ang);
            a.pe[(size_t)t * DD + 512 + j] = cosf(ang);
        }
    } else {
        int r = bid - 7168;        // 0..15
        int b = r >> 2, s = r & 3;
#pragma unroll
        for (int i = 0; i < 4; ++i)
            a.cat[(size_t)(b * LKV + s) * DD + i * 256 + tid] =
                a.state0[(size_t)r * DD + i * 256 + tid];
    }
}

// ================= fused LayerNorm -> bf16 (state-kv rows + out token rows) ===
__global__ __launch_bounds__(256) void ln_fused_kernel(
    const float* __restrict__ cat, const float* __restrict__ cat2,
    bf16* __restrict__ lnbb, bf16* __restrict__ lnbb2,
    const float* __restrict__ sg, const float* __restrict__ sb,
    const float* __restrict__ og, const float* __restrict__ ob)
{
    int bid = blockIdx.x;
    int tid = threadIdx.x;
    const float* in; bf16* out; const float* g; const float* b;
    if (bid < 4112) {
        in = cat + (size_t)bid * DD; out = lnbb + (size_t)bid * DD; g = sg; b = sb;
    } else {
        int r = bid - 4112;
        int row = (r >> 10) * LKV + (r & 1023);
        in = cat2 + (size_t)row * DD; out = lnbb2 + (size_t)r * DD; g = og; b = ob;
    }
    float v[4];
    float s1 = 0.f, s2 = 0.f;
#pragma unroll
    for (int i = 0; i < 4; ++i) {
        v[i] = in[i * 256 + tid];
        s1 += v[i]; s2 += v[i] * v[i];
    }
    s1 = warp_sum(s1); s2 = warp_sum(s2);
    __shared__ float a1[4], a2[4];
    int w = tid >> 6;
    if ((tid & 63) == 0) { a1[w] = s1; a2[w] = s2; }
    __syncthreads();
    s1 = a1[0] + a1[1] + a1[2] + a1[3];
    s2 = a2[0] + a2[1] + a2[2] + a2[3];
    float mu  = s1 * (1.0f / DD);
    float var = s2 * (1.0f / DD) - mu * mu;
    var = var < 0.f ? 0.f : var;
    float rs = rsqrtf(var + 1e-5f);
#pragma unroll
    for (int i = 0; i < 4; ++i) {
        int c = i * 256 + tid;
        out[c] = __float2bfloat16((v[i] - mu) * rs * g[c] + b[c]);
    }
}

// ================= MFMA tile body (128x128, BK=32, 4 waves) ===================
__device__ __forceinline__ void mfma_tile(
    const bf16* __restrict__ A, const bf16* __restrict__ W,
    const float* __restrict__ bias,
    float* __restrict__ outf,
    int obs, int oro, const float* __restrict__ pe,
    bf16* As, bf16* Ws, int m0, int n0)
{
    int tid  = threadIdx.x;
    int lane = tid & 63;
    int wave = tid >> 6;
    int wm = (wave >> 1) << 6;
    int wn = (wave & 1) << 6;

    f32x4 acc[4][4] = {};

    int soff  = wave * 1024 + lane * 16;
    int srow  = soff >> 6;
    int scol  = (soff & 63) >> 1;
    char* lA0 = (char*)As + wave * 1024;
    char* lA1 = (char*)As + 4096 + wave * 1024;
    char* lW0 = (char*)Ws + wave * 1024;
    char* lW1 = (char*)Ws + 4096 + wave * 1024;

    int fRow = lane & 15;
    int kOff = (lane >> 4) << 3;

    for (int k0 = 0; k0 < DD; k0 += 32) {
        GLD16(A + (size_t)(m0 + srow) * DD + k0 + scol,      lA0);
        GLD16(A + (size_t)(m0 + 64 + srow) * DD + k0 + scol, lA1);
        GLD16(W + (size_t)(n0 + srow) * DD + k0 + scol,      lW0);
        GLD16(W + (size_t)(n0 + 64 + srow) * DD + k0 + scol, lW1);
        __syncthreads();
        short8 a[4], b[4];
#pragma unroll
        for (int mi = 0; mi < 4; ++mi)
            a[mi] = *(const short8*)(As + (wm + mi * 16 + fRow) * 32 + kOff);
#pragma unroll
        for (int ni = 0; ni < 4; ++ni)
            b[ni] = *(const short8*)(Ws + (wn + ni * 16 + fRow) * 32 + kOff);
#pragma unroll
        for (int mi = 0; mi < 4; ++mi)
#pragma unroll
            for (int ni = 0; ni < 4; ++ni)
                acc[mi][ni] = __builtin_amdgcn_mfma_f32_16x16x32_bf16(
                    a[mi], b[ni], acc[mi][ni], 0, 0, 0);
        __syncthreads();
    }

    int cCol  = lane & 15;
    int cRow4 = (lane >> 4) << 2;
#pragma unroll
    for (int mi = 0; mi < 4; ++mi) {
#pragma unroll
        for (int ni = 0; ni < 4; ++ni) {
#pragma unroll
            for (int r = 0; r < 4; ++r) {
                int row = m0 + wm + mi * 16 + cRow4 + r;
                int col = n0 + wn + ni * 16 + cCol;
                float v = acc[mi][ni][r] + bias[col] + pe[(size_t)(row & 1023) * DD + col];
                int orow = (row >> 10) * obs + oro + (row & 1023);
                outf[(size_t)orow * DD + col] = v;
            }
        }
    }
}

// ================= fused embeds, XCD-swizzled linear grid (512 blocks) ========
__global__ __launch_bounds__(256) void embed_fused_kernel(
    const bf16* __restrict__ xb,
    const bf16* __restrict__ seW, const bf16* __restrict__ oeW,
    const float* __restrict__ seb, const float* __restrict__ oeb,
    float* __restrict__ cat, float* __restrict__ cat2,
    const float* __restrict__ pe)
{
    __shared__ bf16 As[128 * 32];
    __shared__ bf16 Ws[128 * 32];
    int bid = blockIdx.x;
    int t = (bid & 7) * 64 + (bid >> 3);   // bijective XCD swizzle (512 = 8*64)
    int x = t & 7;
    int q = t >> 3;
    int z = q & 1;
    int y = q >> 1;
    const bf16* W = z ? oeW : seW;
    const float* bias = z ? oeb : seb;
    float* outf = z ? cat2 : cat;
    int oro = z ? 0 : NS;
    mfma_tile(xb, W, bias, outf, LKV, oro, pe, As, Ws, y * 128, x * 128);
}

// ================= copy lo[:, -1] =============================================
__global__ __launch_bounds__(256) void copy_lolast_kernel(
    const float* __restrict__ cat2, float* __restrict__ dst)
{
    int b = blockIdx.x;
    int tid = threadIdx.x;
#pragma unroll
    for (int i = 0; i < 4; ++i)
        dst[(size_t)b * DD + i * 256 + tid] =
            cat2[(size_t)(b * LKV + (TT - 1)) * DD + i * 256 + tid];
}

// ================= small GEMM (M<=16), f32 LDS staging =========================
template<int M>
__global__ __launch_bounds__(256) void small_gemm_kernel(
    const float* __restrict__ A, const float* __restrict__ W,
    const float* __restrict__ bias, float* __restrict__ out,
    const float* __restrict__ res, int gelu)
{
    __shared__ float As[M * DD];
    int tid = threadIdx.x;
#pragma unroll
    for (int i = 0; i < M; ++i) {
        int idx = (i * 256 + tid) * 4;
        *(float4*)(As + idx) = *(const float4*)(A + idx);
    }
    __syncthreads();
    int lane = tid & 63;
    int w = tid >> 6;
    int n = blockIdx.x * 4 + w;
    const float* Wr = W + (size_t)n * DD;
    float acc[M] = {};
#pragma unroll
    for (int j = 0; j < 4; ++j) {
        float4 wv = *(const float4*)(Wr + j * 256 + lane * 4);
#pragma unroll
        for (int m = 0; m < M; ++m) {
            float4 av = *(const float4*)(As + m * DD + j * 256 + lane * 4);
            acc[m] += av.x * wv.x + av.y * wv.y + av.z * wv.z + av.w * wv.w;
        }
    }
#pragma unroll
    for (int m = 0; m < M; ++m) acc[m] = warp_sum(acc[m]);
    if (lane == 0) {
#pragma unroll
        for (int m = 0; m < M; ++m) {
            float v = acc[m] + bias[n];
            if (gelu) v = 0.5f * v * (1.0f + erff(v * 0.70710678118654752f));
            if (res)  v += res[(size_t)m * DD + n];
            out[(size_t)m * DD + n] = v;
        }
    }
}

// ============ small GEMM with fused input LayerNorm ===========================
template<int M>
__global__ __launch_bounds__(256) void small_ln_gemm_kernel(
    const float* __restrict__ A, int row0, int rstride,
    const float* __restrict__ lng, const float* __restrict__ lnb,
    const float* __restrict__ W, const float* __restrict__ bias,
    float* __restrict__ outf, int gelu)
{
    __shared__ float As[M * DD];
    __shared__ float smu[M], srs[M];
    int tid = threadIdx.x;
    int lane = tid & 63;
    int w = tid >> 6;
#pragma unroll
    for (int i = 0; i < M; ++i) {
        int row = row0 + i * rstride;
        *(float4*)(As + i * DD + tid * 4) =
            *(const float4*)(A + (size_t)row * DD + tid * 4);
    }
    __syncthreads();
    constexpr int RPW = (M + 3) / 4;
#pragma unroll
    for (int i = 0; i < RPW; ++i) {
        int r = w * RPW + i;
        if (r < M) {
            float s1 = 0.f, s2 = 0.f;
#pragma unroll
            for (int j = 0; j < 4; ++j) {
                float4 v = *(const float4*)(As + r * DD + (j * 64 + lane) * 4);
                s1 += v.x + v.y + v.z + v.w;
                s2 += v.x*v.x + v.y*v.y + v.z*v.z + v.w*v.w;
            }
            s1 = warp_sum(s1); s2 = warp_sum(s2);
            if (lane == 0) {
                float mu = s1 * (1.0f / DD);
                float var = s2 * (1.0f / DD) - mu * mu;
                var = var < 0.f ? 0.f : var;
                smu[r] = mu; srs[r] = rsqrtf(var + 1e-5f);
            }
        }
    }
    __syncthreads();
    float4 gv = *(const float4*)(lng + tid * 4);
    float4 bv = *(const float4*)(lnb + tid * 4);
#pragma unroll
    for (int i = 0; i < M; ++i) {
        float mu = smu[i], rs = srs[i];
        float4 v = *(const float4*)(As + i * DD + tid * 4);
        v.x = (v.x - mu) * rs * gv.x + bv.x;
        v.y = (v.y - mu) * rs * gv.y + bv.y;
        v.z = (v.z - mu) * rs * gv.z + bv.z;
        v.w = (v.w - mu) * rs * gv.w + bv.w;
        *(float4*)(As + i * DD + tid * 4) = v;
    }
    __syncthreads();
    int n = blockIdx.x * 4 + w;
    const float* Wr = W + (size_t)n * DD;
    float acc[M] = {};
#pragma unroll
    for (int j = 0; j < 4; ++j) {
        float4 wv = *(const float4*)(Wr + j * 256 + lane * 4);
#pragma unroll
        for (int m = 0; m < M; ++m) {
            float4 av = *(const float4*)(As + m * DD + j * 256 + lane * 4);
            acc[m] += av.x * wv.x + av.y * wv.y + av.z * wv.z + av.w * wv.w;
        }
    }
#pragma unroll
    for (int m = 0; m < M; ++m) acc[m] = warp_sum(acc[m]);
    if (lane == 0) {
#pragma unroll
        for (int m = 0; m < M; ++m) {
            float v = acc[m] + bias[n];
            if (gelu) v = 0.5f * v * (1.0f + erff(v * 0.70710678118654752f));
            outf[(size_t)m * DD + n] = v;
        }
    }
}

// ============ qtil: project queries through Wk (low-rank attention trick) =====
__global__ __launch_bounds__(256) void qtil_kernel(
    const float* __restrict__ qh_s, const float* __restrict__ q2h,
    const float* __restrict__ sWk, const float* __restrict__ oWk,
    float* __restrict__ qtil_s, float* __restrict__ qtil_o)
{
    int blk = blockIdx.x;
    int tid = threadIdx.x;
    const float* src; const float* W; float* dst; int h;
    if (blk < 256) {
        int bq = blk >> 4;          // b*4+q
        h = blk & 15;
        src = qh_s + (size_t)bq * DD;
        W = sWk; dst = qtil_s + (size_t)blk * DD;
    } else {
        int o = blk - 256;
        int b = o >> 4;
        h = o & 15;
        src = q2h + (size_t)b * DD;
        W = oWk; dst = qtil_o + (size_t)o * DD;
    }
    __shared__ float qv[64];
    if (tid < 64) qv[tid] = src[h * 64 + tid];
    __syncthreads();
    int i = tid * 4;
    float4 acc = {0.f, 0.f, 0.f, 0.f};
#pragma unroll 4
    for (int o = 0; o < 64; ++o) {
        float4 wr = *(const float4*)(W + (size_t)(h * 64 + o) * DD + i);
        float s = qv[o];
        acc.x += s * wr.x; acc.y += s * wr.y; acc.z += s * wr.z; acc.w += s * wr.w;
    }
    acc.x *= 0.125f; acc.y *= 0.125f; acc.z *= 0.125f; acc.w *= 0.125f;
    *(float4*)(dst + i) = acc;
}

// ============ sc_ctx body: scores + softmax-partial + ctx for one chunk =======
// Register/shuffle pass 1; nchs = chunk-slot stride in pm/pl/pctx.
template<int LQ, int CHSv>
__device__ void sc_ctx_body(int c, int bh,
    const float* __restrict__ qtil, const bf16* __restrict__ keys,
    int keyStride, int nkey, int nchs,
    float* __restrict__ pm, float* __restrict__ pl, float* __restrict__ pctx,
    float* sc, float* redm, float* redl)
{
    int b = bh >> 4, h = bh & 15;
    int tid = threadIdx.x;
    int lane = tid & 63, w = tid >> 6;

    float qreg[LQ][16];
#pragma unroll
    for (int q = 0; q < LQ; ++q) {
        const float* qrow = qtil + (size_t)((b * LQ + q) * 16 + h) * DD + lane * 16;
#pragma unroll
        for (int j = 0; j < 4; ++j) {
            float4 v = *(const float4*)(qrow + j * 4);
            qreg[q][j*4+0] = v.x; qreg[q][j*4+1] = v.y;
            qreg[q][j*4+2] = v.z; qreg[q][j*4+3] = v.w;
        }
    }

    int kbeg = c * CHSv;
    int kcnt = nkey - kbeg; if (kcnt > CHSv) kcnt = CHSv;

    // pass 1: wave-per-key, coalesced 32B/lane key reads, shfl reduce
    for (int t = w; t < kcnt; t += 4) {
        const unsigned short* row = (const unsigned short*)keys
            + (size_t)(b * keyStride + kbeg + t) * DD + lane * 16;
        float kf[16];
#pragma unroll
        for (int j = 0; j < 4; ++j) {
            ushort4 v = *(const ushort4*)(row + j * 4);
            kf[j*4+0] = b2f(v.x); kf[j*4+1] = b2f(v.y);
            kf[j*4+2] = b2f(v.z); kf[j*4+3] = b2f(v.w);
        }
        float acc[LQ];
#pragma unroll
        for (int q = 0; q < LQ; ++q) acc[q] = 0.f;
#pragma unroll
        for (int j = 0; j < 16; ++j)
#pragma unroll
            for (int q = 0; q < LQ; ++q)
                acc[q] += kf[j] * qreg[q][j];
#pragma unroll
        for (int q = 0; q < LQ; ++q) acc[q] = warp_sum(acc[q]);
        if (lane == 0) {
#pragma unroll
            for (int q = 0; q < LQ; ++q) sc[q * CHSv + t] = acc[q];
        }
    }
    __syncthreads();

    float M[LQ], L[LQ];
#pragma unroll
    for (int q = 0; q < LQ; ++q) {
        float lm = -1e30f;
        for (int t = tid; t < kcnt; t += 256) lm = fmaxf(lm, sc[q * CHSv + t]);
#pragma unroll
        for (int o = 32; o > 0; o >>= 1) lm = fmaxf(lm, __shfl_xor(lm, o));
        if (lane == 0) redm[w * LQ + q] = lm;
    }
    __syncthreads();
#pragma unroll
    for (int q = 0; q < LQ; ++q)
        M[q] = fmaxf(fmaxf(redm[q], redm[LQ + q]),
                     fmaxf(redm[2 * LQ + q], redm[3 * LQ + q]));
#pragma unroll
    for (int q = 0; q < LQ; ++q) {
        float ls = 0.f;
        for (int t = tid; t < kcnt; t += 256) {
            float e = expf(sc[q * CHSv + t] - M[q]);
            sc[q * CHSv + t] = e;
            ls += e;
        }
        ls = warp_sum(ls);
        if (lane == 0) redl[w * LQ + q] = ls;
    }
    __syncthreads();
#pragma unroll
    for (int q = 0; q < LQ; ++q)
        L[q] = redl[q] + redl[LQ + q] + redl[2 * LQ + q] + redl[3 * LQ + q];

    // pass 2: thread-per-dim ctx accumulation (coalesced key reads)
    int i4 = tid * 4;
    float cx[LQ][4];
#pragma unroll
    for (int q = 0; q < LQ; ++q) { cx[q][0]=0; cx[q][1]=0; cx[q][2]=0; cx[q][3]=0; }
    for (int t = 0; t < kcnt; ++t) {
        const unsigned short* row = (const unsigned short*)keys
            + (size_t)(b * keyStride + kbeg + t) * DD;
        ushort4 v = *(const ushort4*)(row + i4);
        float f0 = b2f(v.x), f1 = b2f(v.y), f2 = b2f(v.z), f3 = b2f(v.w);
#pragma unroll
        for (int q = 0; q < LQ; ++q) {
            float p = sc[q * CHSv + t];
            cx[q][0] += p * f0; cx[q][1] += p * f1;
            cx[q][2] += p * f2; cx[q][3] += p * f3;
        }
    }
#pragma unroll
    for (int q = 0; q < LQ; ++q) {
        float4 o4 = {cx[q][0], cx[q][1], cx[q][2], cx[q][3]};
        *(float4*)(pctx + (size_t)((bh * nchs + c) * LQ + q) * DD + i4) = o4;
    }
    if (tid < LQ) {
        pm[(bh * LQ + tid) * nchs + c] = M[tid];
        pl[(bh * LQ + tid) * nchs + c] = L[tid];
    }
}

// ======= merged sc_ctx: blocks 0-1023 state branch; 1024-2047 out tokens ======
__global__ __launch_bounds__(256) void sc_ctx_main_kernel(
    const float* __restrict__ qtil_s, const float* __restrict__ qtil_o,
    const bf16* __restrict__ lnbb, const bf16* __restrict__ lnbb2,
    float* __restrict__ pms, float* __restrict__ pls, float* __restrict__ pctx_s,
    float* __restrict__ pmo, float* __restrict__ plo, float* __restrict__ pctx_o)
{
    __shared__ float sc[4 * 65];
    __shared__ float redm[16], redl[16];
    int bid = blockIdx.x;
    if (bid < 1024) {
        int c = bid & 15, bh = bid >> 4;
        sc_ctx_body<4, 65>(c, bh, qtil_s, lnbb, LKV, 1028, 16,
                           pms, pls, pctx_s, sc, redm, redl);
    } else {
        bid -= 1024;
        int c = bid & 15, bh = bid >> 4;
        sc_ctx_body<1, 64>(c, bh, qtil_o, lnbb2, TT, 1024, 17,
                           pmo, plo, pctx_o, sc, redm, redl);
    }
}

// ======= gate-dependent tail: 4 new-state keys as chunk 16 of out branch ======
__global__ __launch_bounds__(256) void sc_tail_kernel(
    const float* __restrict__ qtil_o, const bf16* __restrict__ lnst,
    float* __restrict__ pmo, float* __restrict__ plo, float* __restrict__ pctx_o)
{
    __shared__ float sc4[4];
    int bh = blockIdx.x;
    int b = bh >> 4, h = bh & 15;
    int tid = threadIdx.x;
    int lane = tid & 63, w = tid >> 6;

    {
        const unsigned short* row = (const unsigned short*)lnst
            + (size_t)(b * 4 + w) * DD + lane * 16;
        const float* qrow = qtil_o + (size_t)bh * DD + lane * 16;
        float s = 0.f;
#pragma unroll
        for (int j = 0; j < 4; ++j) {
            ushort4 v = *(const ushort4*)(row + j * 4);
            float4 qv = *(const float4*)(qrow + j * 4);
            s += b2f(v.x)*qv.x + b2f(v.y)*qv.y + b2f(v.z)*qv.z + b2f(v.w)*qv.w;
        }
        s = warp_sum(s);
        if (lane == 0) sc4[w] = s;
    }
    __syncthreads();
    float m = fmaxf(fmaxf(sc4[0], sc4[1]), fmaxf(sc4[2], sc4[3]));
    float e0 = expf(sc4[0] - m), e1 = expf(sc4[1] - m);
    float e2 = expf(sc4[2] - m), e3 = expf(sc4[3] - m);
    float l = e0 + e1 + e2 + e3;
    int i4 = tid * 4;
    const unsigned short* k0 = (const unsigned short*)lnst + (size_t)(b*4+0)*DD + i4;
    const unsigned short* k1 = (const unsigned short*)lnst + (size_t)(b*4+1)*DD + i4;
    const unsigned short* k2 = (const unsigned short*)lnst + (size_t)(b*4+2)*DD + i4;
    const unsigned short* k3 = (const unsigned short*)lnst + (size_t)(b*4+3)*DD + i4;
    ushort4 v0 = *(const ushort4*)k0, v1 = *(const ushort4*)k1;
    ushort4 v2 = *(const ushort4*)k2, v3 = *(const ushort4*)k3;
    float4 o4;
    o4.x = e0*b2f(v0.x) + e1*b2f(v1.x) + e2*b2f(v2.x) + e3*b2f(v3.x);
    o4.y = e0*b2f(v0.y) + e1*b2f(v1.y) + e2*b2f(v2.y) + e3*b2f(v3.y);
    o4.z = e0*b2f(v0.z) + e1*b2f(v1.z) + e2*b2f(v2.z) + e3*b2f(v3.z);
    o4.w = e0*b2f(v0.w) + e1*b2f(v1.w) + e2*b2f(v2.w) + e3*b2f(v3.w);
    *(float4*)(pctx_o + (size_t)(bh * 17 + 16) * DD + i4) = o4;
    if (tid == 0) {
        pmo[bh * 17 + 16] = m;
        plo[bh * 17 + 16] = l;
    }
}

// ============ combproj: combine NCHT chunk ctx + project through Wv + bv ======
template<int LQ, int NCHT>
__global__ __launch_bounds__(256) void combproj_kernel(
    const float* __restrict__ pm, const float* __restrict__ pl,
    const float* __restrict__ pctx,
    const float* __restrict__ Wv, const float* __restrict__ bv,
    float* __restrict__ attn)
{
    __shared__ float ctxf[DD];
    int blk = blockIdx.x;
    int h = blk & 15;
    int bq = blk >> 4;               // b*LQ+q
    int b = bq / LQ, q = bq - b * LQ;
    int bh = b * 16 + h;
    int tid = threadIdx.x;
    int lane = tid & 63, w = tid >> 6;

    int base = (bh * LQ + q) * NCHT;
    float Mx = -1e30f;
#pragma unroll
    for (int c = 0; c < NCHT; ++c) Mx = fmaxf(Mx, pm[base + c]);
    float wc[NCHT];
    float L = 0.f;
#pragma unroll
    for (int c = 0; c < NCHT; ++c) {
        wc[c] = expf(pm[base + c] - Mx);
        L += pl[base + c] * wc[c];
    }
    float inv = 1.f / L;
    int i4 = tid * 4;
    float4 s4 = {0.f, 0.f, 0.f, 0.f};
#pragma unroll
    for (int c = 0; c < NCHT; ++c) {
        float4 a = *(const float4*)(pctx + (size_t)((bh * NCHT + c) * LQ + q) * DD + i4);
        s4.x += a.x * wc[c]; s4.y += a.y * wc[c];
        s4.z += a.z * wc[c]; s4.w += a.w * wc[c];
    }
    ctxf[i4+0] = s4.x * inv;
    ctxf[i4+1] = s4.y * inv;
    ctxf[i4+2] = s4.z * inv;
    ctxf[i4+3] = s4.w * inv;
    __syncthreads();

#pragma unroll 1
    for (int rr = 0; rr < 16; ++rr) {
        int o = h * 64 + w * 16 + rr;
        const float* Wr = Wv + (size_t)o * DD + lane * 16;
        const float* cf = ctxf + lane * 16;
        float s = 0.f;
#pragma unroll
        for (int j = 0; j < 4; ++j) {
            float4 wv4 = *(const float4*)(Wr + j * 4);
            s += wv4.x * cf[j*4+0] + wv4.y * cf[j*4+1]
               + wv4.z * cf[j*4+2] + wv4.w * cf[j*4+3];
        }
        s = warp_sum(s);
        if (lane == 0)
            attn[(size_t)bq * DD + o] = s + bv[o];
    }
}

// ================= LN of stateNew rows -> bf16 (out-branch keys) ==============
__global__ __launch_bounds__(256) void lnst_kernel(
    const float* __restrict__ stateNew, bf16* __restrict__ lnst,
    const float* __restrict__ g, const float* __restrict__ b)
{
    int r = blockIdx.x;
    int tid = threadIdx.x;
    size_t base = (size_t)r * DD;
    float v[4];
    float s1 = 0.f, s2 = 0.f;
#pragma unroll
    for (int i = 0; i < 4; ++i) {
        v[i] = stateNew[base + i * 256 + tid];
        s1 += v[i]; s2 += v[i] * v[i];
    }
    s1 = warp_sum(s1); s2 = warp_sum(s2);
    __shared__ float a1[4], a2[4];
    int w = tid >> 6;
    if ((tid & 63) == 0) { a1[w] = s1; a2[w] = s2; }
    __syncthreads();
    s1 = a1[0] + a1[1] + a1[2] + a1[3];
    s2 = a2[0] + a2[1] + a2[2] + a2[3];
    float mu  = s1 * (1.0f / DD);
    float var = s2 * (1.0f / DD) - mu * mu;
    var = var < 0.f ? 0.f : var;
    float rs = rsqrtf(var + 1e-5f);
#pragma unroll
    for (int i = 0; i < 4; ++i) {
        int c = i * 256 + tid;
        lnst[base + c] = __float2bfloat16((v[i] - mu) * rs * g[c] + b[c]);
    }
}

// ========== fused gate: LN(lat2) -> logits -> top2 -> state update ============
__global__ __launch_bounds__(256) void gate_fused_kernel(
    const float* __restrict__ lat2,
    const float* __restrict__ lng, const float* __restrict__ lnb,
    const float* __restrict__ ctx,
    const float* __restrict__ state_old, float* __restrict__ stateNew,
    float* __restrict__ dout)
{
    int b = blockIdx.x;
    int tid = threadIdx.x;
    int lane = tid & 63, w = tid >> 6;
    __shared__ float logit[NS];
    __shared__ float alpha[NS];

    {
        const float* row = lat2 + (size_t)(b * NS + w) * DD;
        float4 v[4];
        float s1 = 0.f, s2 = 0.f;
#pragma unroll
        for (int j = 0; j < 4; ++j) {
            v[j] = *(const float4*)(row + (j * 64 + lane) * 4);
            s1 += v[j].x + v[j].y + v[j].z + v[j].w;
            s2 += v[j].x*v[j].x + v[j].y*v[j].y + v[j].z*v[j].z + v[j].w*v[j].w;
        }
        s1 = warp_sum(s1); s2 = warp_sum(s2);
        float mu = s1 * (1.0f / DD);
        float var = s2 * (1.0f / DD) - mu * mu;
        var = var < 0.f ? 0.f : var;
        float rs = rsqrtf(var + 1e-5f);
        float dot = 0.f;
#pragma unroll
        for (int j = 0; j < 4; ++j) {
            int c = (j * 64 + lane) * 4;
            float4 gv = *(const float4*)(lng + c);
            float4 bv = *(const float4*)(lnb + c);
            float4 cv = *(const float4*)(ctx + c);
            dot += ((v[j].x - mu) * rs * gv.x + bv.x) * cv.x
                 + ((v[j].y - mu) * rs * gv.y + bv.y) * cv.y
                 + ((v[j].z - mu) * rs * gv.z + bv.z) * cv.z
                 + ((v[j].w - mu) * rs * gv.w + bv.w) * cv.w;
        }
        dot = warp_sum(dot);
        if (lane == 0) logit[w] = dot;
    }
    __syncthreads();
    if (tid == 0) {
        float l[NS];
        for (int s = 0; s < NS; ++s) l[s] = logit[s];
        int i0 = 0;
        for (int s = 1; s < NS; ++s) if (l[s] > l[i0]) i0 = s;
        int i1 = (i0 == 0) ? 1 : 0;
        for (int s = 0; s < NS; ++s) if (s != i0 && l[s] > l[i1]) i1 = s;
        float mx = fmaxf(l[i0], l[i1]);
        float e0 = expf(l[i0] - mx), e1 = expf(l[i1] - mx);
        float inv = 1.f / (e0 + e1);
        for (int s = 0; s < NS; ++s) alpha[s] = 0.f;
        alpha[i0] = e0 * inv;
        alpha[i1] += e1 * inv;
        dout[4096 + b * 2 + 0] = (float)i0;
        dout[4096 + b * 2 + 1] = (float)i1;
    }
    __syncthreads();
    for (int idx = tid; idx < NS * DD; idx += 256) {
        int s = idx >> 10;
        float so = state_old[(size_t)b * NS * DD + idx];
        float lt = lat2[(size_t)b * NS * DD + idx];
        float ns = 0.6f * so + 0.4f * alpha[s] * tanhf(lt);
        stateNew[(size_t)b * NS * DD + idx] = ns;
        dout[4104 + b * NS * DD + idx] = ns;
    }
}

extern "C" void kernel_launch(void* const* d_in, const int* in_sizes, int n_in,
                              void* d_out, int out_size, void* d_ws, size_t ws_size,
                              hipStream_t stream)
{
    const float* x        = (const float*)d_in[0];
    const float* state0   = (const float*)d_in[1];
    const float* se_W     = (const float*)d_in[2];
    const float* se_b     = (const float*)d_in[3];
    const float* s_Wq     = (const float*)d_in[4];
    const float* s_bq     = (const float*)d_in[5];
    const float* s_Wk     = (const float*)d_in[6];
    const float* s_bk     = (const float*)d_in[7];   (void)s_bk;  // drops out of softmax
    const float* s_Wv     = (const float*)d_in[8];
    const float* s_bv     = (const float*)d_in[9];
    const float* s_Wo     = (const float*)d_in[10];
    const float* s_bo     = (const float*)d_in[11];
    const float* s_lnq_g  = (const float*)d_in[12];
    const float* s_lnq_b  = (const float*)d_in[13];
    const float* s_lnkv_g = (const float*)d_in[14];
    const float* s_lnkv_b = (const float*)d_in[15];
    const float* s_fc1_W  = (const float*)d_in[16];
    const float* s_fc1_b  = (const float*)d_in[17];
    const float* s_fc2_W  = (const float*)d_in[18];
    const float* s_fc2_b  = (const float*)d_in[19];
    const float* s_lnffn_g= (const float*)d_in[20];
    const float* s_lnffn_b= (const float*)d_in[21];
    const float* s_lnslot_g=(const float*)d_in[22];
    const float* s_lnslot_b=(const float*)d_in[23];
    const float* slot_ctx = (const float*)d_in[24];
    const float* oe_W     = (const float*)d_in[25];
    const float* oe_b     = (const float*)d_in[26];
    const float* o_Wq     = (const float*)d_in[27];
    const float* o_bq     = (const float*)d_in[28];
    const float* o_Wk     = (const float*)d_in[29];
    const float* o_bk     = (const float*)d_in[30];  (void)o_bk;  // drops out of softmax
    const float* o_Wv     = (const float*)d_in[31];
    const float* o_bv     = (const float*)d_in[32];
    const float* o_Wo     = (const float*)d_in[33];
    const float* o_bo     = (const float*)d_in[34];
    const float* o_lnq_g  = (const float*)d_in[35];
    const float* o_lnq_b  = (const float*)d_in[36];
    const float* o_lnkv_g = (const float*)d_in[37];
    const float* o_lnkv_b = (const float*)d_in[38];
    const float* o_fc1_W  = (const float*)d_in[39];
    const float* o_fc1_b  = (const float*)d_in[40];
    const float* o_fc2_W  = (const float*)d_in[41];
    const float* o_fc2_b  = (const float*)d_in[42];
    const float* o_lnffn_g= (const float*)d_in[43];
    const float* o_lnffn_b= (const float*)d_in[44];
    const float* op_W     = (const float*)d_in[45];
    const float* op_b     = (const float*)d_in[46];

    float* ws = (float*)d_ws;
    float* pe    = ws;
    float* cat   = ws + 1048576;                 // consumed by ln_fused, then reused:
    float* qtil_s= ws + 1048576;                 //   256 x 1024
    float* qtil_o= ws + 1310720;                 //   64 x 1024
    float* pctx_o= ws + 1376256;                 //   64*17 x 1024 = 1,114,112
    float* pms   = ws + 2490368;                 //   64*4*16 = 4096
    float* pls   = ws + 2494464;                 //   4096
    float* pmo   = ws + 2498560;                 //   64*17 = 1088 (pad 2048)
    float* plo   = ws + 2500608;                 //   1088
    bf16*  lnbb  = (bf16*)(ws + 5259264);        // 4112 rows bf16
    float* cat2  = ws + 7421952;                 // consumed in phase 2, then:
    float* pctx_s= ws + 7421952;                 //   64*16*4 x 1024 = 4,194,304
    bf16*  xb    = (bf16*)(ws + 11632640);       // xb early, lnbb2 late (alias)
    bf16*  lnbb2 = (bf16*)(ws + 11632640);
    bf16*  seWb  = (bf16*)(ws + 13729792);
    bf16*  oeWb  = seWb + 1048576;
    float* sm    = ws + 16875520;
    float* qh_s    = sm + 16384;
    float* attn_s  = sm + 32768;
    float* lat1    = sm + 49152;
    float* g1      = sm + 81920;
    float* lat2    = sm + 98304;
    float* q2h     = sm + 135232;
    float* attn2   = sm + 139328;
    float* lo_last = sm + 143424;
    float* lo1     = sm + 147520;
    float* g2      = sm + 155712;
    float* lo2     = sm + 159808;
    float* stateNew= sm + 231488;
    bf16*  lnst    = (bf16*)(sm + 247872);       // 16 x 1024 bf16
    float* out = (float*)d_out;

    dim3 blk(256);

    // ---- phase 0: conversions (x, seW, oeW only) + PE + state-row copy ----
    PrepArgs pa;
    pa.x = x; pa.seW = se_W; pa.oeW = oe_W;
    pa.xb = xb; pa.seWb = seWb; pa.oeWb = oeWb;
    pa.state0 = state0; pa.cat = cat; pa.pe = pe;
    prep_kernel<<<7184, blk, 0, stream>>>(pa);

    // ---- phase 1: both embeds (MFMA), XCD-swizzled ----
    embed_fused_kernel<<<512, blk, 0, stream>>>(
        xb, seWb, oeWb, se_b, oe_b, cat, cat2, pe);

    // ---- phase 2: big LNs + q projections + lo_last ----
    ln_fused_kernel<<<8208, blk, 0, stream>>>(cat, cat2, lnbb, lnbb2,
        s_lnkv_g, s_lnkv_b, o_lnkv_g, o_lnkv_b);
    small_ln_gemm_kernel<16><<<256, blk, 0, stream>>>(state0, 0, 1,
        s_lnq_g, s_lnq_b, s_Wq, s_bq, qh_s, 0);
    small_ln_gemm_kernel<4><<<256, blk, 0, stream>>>(cat2, TT - 1, LKV,
        o_lnq_g, o_lnq_b, o_Wq, o_bq, q2h, 0);
    copy_lolast_kernel<<<NB, blk, 0, stream>>>(cat2, lo_last);

    // ---- phase 3: query-side Wk projection ----
    qtil_kernel<<<320, blk, 0, stream>>>(qh_s, q2h, s_Wk, o_Wk, qtil_s, qtil_o);

    // ---- phase 4: merged gate-independent attention scan (both branches) ----
    sc_ctx_main_kernel<<<2048, blk, 0, stream>>>(qtil_s, qtil_o, lnbb, lnbb2,
        pms, pls, pctx_s, pmo, plo, pctx_o);

    // ---- phase 5: state-branch combine + slot MLP + gate ----
    combproj_kernel<4, 16><<<256, blk, 0, stream>>>(pms, pls, pctx_s,
        s_Wv, s_bv, attn_s);
    small_gemm_kernel<16><<<256, blk, 0, stream>>>(attn_s, s_Wo, s_bo, lat1, state0, 0);
    small_ln_gemm_kernel<16><<<256, blk, 0, stream>>>(lat1, 0, 1,
        s_lnffn_g, s_lnffn_b, s_fc1_W, s_fc1_b, g1, 1);
    small_gemm_kernel<16><<<256, blk, 0, stream>>>(g1, s_fc2_W, s_fc2_b, lat2, lat1, 0);
    gate_fused_kernel<<<NB, blk, 0, stream>>>(lat2, s_lnslot_g, s_lnslot_b,
        slot_ctx, state0, stateNew, out);

    // ---- phase 6: gate-dependent tail (4 keys) + out-branch combine + head ----
    lnst_kernel<<<16, blk, 0, stream>>>(stateNew, lnst, o_lnkv_g, o_lnkv_b);
    sc_tail_kernel<<<64, blk, 0, stream>>>(qtil_o, lnst, pmo, plo, pctx_o);
    combproj_kernel<1, 17><<<64, blk, 0, stream>>>(pmo, plo, pctx_o,
        o_Wv, o_bv, attn2);
    small_gemm_kernel<4><<<256, blk, 0, stream>>>(attn2, o_Wo, o_bo, lo1, lo_last, 0);
    small_ln_gemm_kernel<4><<<256, blk, 0, stream>>>(lo1, 0, 1,
        o_lnffn_g, o_lnffn_b, o_fc1_W, o_fc1_b, g2, 1);
    small_gemm_kernel<4><<<256, blk, 0, stream>>>(g2, o_fc2_W, o_fc2_b, lo2, lo1, 0);
    small_gemm_kernel<4><<<256, blk, 0, stream>>>(lo2, op_W, op_b, out, nullptr, 0);
}